// Round 8
// baseline (232.616 us; speedup 1.0000x reference)
//
#include <hip/hip_runtime.h>
#include <math.h>

// SALAD head. B=64, C=1536, N=256, HID=512, L=128, M=64, G=256. BNT = B*N.
#define BNT 16384

using f32x4 = __attribute__((ext_vector_type(4))) float;
using s16x8 = __attribute__((ext_vector_type(8))) short;

__device__ __forceinline__ unsigned short f32_to_bf16_rne(float f) {
  unsigned int u = __float_as_uint(f);
  u += 0x7FFFu + ((u >> 16) & 1u);
  return (unsigned short)(u >> 16);
}
__device__ __forceinline__ unsigned pack_bf16x2(float a, float b) {
  return (unsigned)f32_to_bf16_rne(a) | ((unsigned)f32_to_bf16_rne(b) << 16);
}

__device__ __forceinline__ void gload_lds16(const ushort* g, ushort* lds) {
  __builtin_amdgcn_global_load_lds(
      (const __attribute__((address_space(1))) unsigned int*)g,
      (__attribute__((address_space(3))) unsigned int*)lds, 16, 0, 0);
}

// ---- fused prep: bf16 converts of t,Wt1,Wt2,Wc1,Ws1 + b1 stack + A2 stack --
__global__ __launch_bounds__(256) void prep_all(
    const float* __restrict__ t, const float* __restrict__ Wt1,
    const float* __restrict__ Wt2, const float* __restrict__ Wc1,
    const float* __restrict__ Ws1, const float* __restrict__ bc1,
    const float* __restrict__ bs1, const float* __restrict__ Wc2,
    const float* __restrict__ Ws2, const float* __restrict__ bc2,
    const float* __restrict__ bs2, ushort* __restrict__ Tb,
    ushort* __restrict__ Wt1b, ushort* __restrict__ Wt2b,
    ushort* __restrict__ Wc1b, ushort* __restrict__ Ws1b,
    float* __restrict__ b1, ushort* __restrict__ A2, float* __restrict__ b2) {
  const int bid = blockIdx.x, tid = threadIdx.x;
  const float* src = nullptr;
  ushort* dst = nullptr;
  int i = 0;
  if (bid < 96) {
    src = t; dst = Tb; i = bid * 256 + tid;
  } else if (bid < 864) {
    src = Wt1; dst = Wt1b; i = (bid - 96) * 256 + tid;
  } else if (bid < 992) {
    src = Wt2; dst = Wt2b; i = (bid - 864) * 256 + tid;
  } else if (bid < 1760) {
    src = Wc1; dst = Wc1b; i = (bid - 992) * 256 + tid;
  } else if (bid < 2528) {
    src = Ws1; dst = Ws1b; i = (bid - 1760) * 256 + tid;
  } else if (bid < 2532) {
    const int j = (bid - 2528) * 256 + tid;
    b1[j] = j < 512 ? bc1[j] : bs1[j - 512];
    return;
  } else {
    const int r = bid - 2532;
    const int c = tid * 4;
    float v[4] = {0.f, 0.f, 0.f, 0.f};
    if (r < 128) {
      if (c < 512) {
#pragma unroll
        for (int j = 0; j < 4; ++j) v[j] = Wc2[r * 512 + c + j];
      }
    } else if (r < 192) {
      if (c >= 512) {
#pragma unroll
        for (int j = 0; j < 4; ++j) v[j] = Ws2[(r - 128) * 512 + (c - 512) + j];
      }
    }
    uint2 o;
    o.x = pack_bf16x2(v[0], v[1]);
    o.y = pack_bf16x2(v[2], v[3]);
    *(uint2*)(A2 + r * 1024 + c) = o;
    if (tid == 0) b2[r] = r < 128 ? bc2[r] : (r < 192 ? bs2[r - 128] : 0.f);
    return;
  }
  const float4 v = ((const float4*)src)[i];
  uint2 o;
  o.x = pack_bf16x2(v.x, v.y);
  o.y = pack_bf16x2(v.z, v.w);
  ((uint2*)dst)[i] = o;
}

// ---- token layer 1 (MFMA, no LDS, split-K) ---------------------------------
__global__ __launch_bounds__(256) void token1_mfma(
    const ushort* __restrict__ Tb, const ushort* __restrict__ Wt1b,
    float* __restrict__ Pt) {
  const int ct = blockIdx.x, kc = blockIdx.y;
  const int tid = threadIdx.x, l = tid & 63, wv = tid >> 6;
  const int lr = l & 15, ko = l >> 4;
  const int col = ct * 64 + wv * 16 + lr;
  f32x4 acc[4];
#pragma unroll
  for (int r = 0; r < 4; ++r) acc[r] = (f32x4){0.f, 0.f, 0.f, 0.f};
  const int k0 = kc * 384;
#pragma unroll 4
  for (int ks = 0; ks < 12; ++ks) {
    const int k = k0 + ks * 32 + ko * 8;
    const s16x8 bf = *(const s16x8*)(Wt1b + (size_t)col * 1536 + k);
#pragma unroll
    for (int rf = 0; rf < 4; ++rf) {
      const s16x8 af = *(const s16x8*)(Tb + (size_t)(rf * 16 + lr) * 1536 + k);
      acc[rf] =
          __builtin_amdgcn_mfma_f32_16x16x32_bf16(af, bf, acc[rf], 0, 0, 0);
    }
  }
#pragma unroll
  for (int rf = 0; rf < 4; ++rf)
#pragma unroll
    for (int j = 0; j < 4; ++j) {
      const int row = rf * 16 + ko * 4 + j;
      Pt[((kc * 64 + row) << 9) + col] = acc[rf][j];
    }
}

// ---- token layer-1 reduce --------------------------------------------------
__global__ __launch_bounds__(256) void token1_reduce(
    const float* __restrict__ Pt, const float* __restrict__ bt1,
    ushort* __restrict__ Hb) {
  const int i = blockIdx.x * 256 + threadIdx.x;
  const int row = i >> 8, c2 = (i & 255) * 2;
  float v0 = bt1[c2], v1 = bt1[c2 + 1];
#pragma unroll
  for (int kc = 0; kc < 4; ++kc) {
    v0 += Pt[((kc * 64 + row) << 9) + c2];
    v1 += Pt[((kc * 64 + row) << 9) + c2 + 1];
  }
  v0 = fmaxf(v0, 0.f);
  v1 = fmaxf(v1, 0.f);
  ((unsigned*)Hb)[i] = pack_bf16x2(v0, v1);
}

// ---- token layer 2 (MFMA, no LDS) ------------------------------------------
__global__ __launch_bounds__(256) void token2_mfma(
    const ushort* __restrict__ Hb, const ushort* __restrict__ Wt2b,
    const float* __restrict__ bt2, float* __restrict__ TK) {
  const int ct = blockIdx.x;
  const int tid = threadIdx.x, l = tid & 63, wv = tid >> 6;
  const int lr = l & 15, ko = l >> 4;
  const int col = ct * 64 + wv * 16 + lr;
  f32x4 acc[4];
#pragma unroll
  for (int r = 0; r < 4; ++r) acc[r] = (f32x4){0.f, 0.f, 0.f, 0.f};
#pragma unroll 4
  for (int ks = 0; ks < 16; ++ks) {
    const int k = ks * 32 + ko * 8;
    const s16x8 bf = *(const s16x8*)(Wt2b + (size_t)col * 512 + k);
#pragma unroll
    for (int rf = 0; rf < 4; ++rf) {
      const s16x8 af = *(const s16x8*)(Hb + (size_t)(rf * 16 + lr) * 512 + k);
      acc[rf] =
          __builtin_amdgcn_mfma_f32_16x16x32_bf16(af, bf, acc[rf], 0, 0, 0);
    }
  }
  const float bb = bt2[col];
#pragma unroll
  for (int rf = 0; rf < 4; ++rf)
#pragma unroll
    for (int j = 0; j < 4; ++j)
      TK[(rf * 16 + ko * 4 + j) * 256 + col] = acc[rf][j] + bb;
}

// ------- x [64][1536][256] fp32 -> XT [16384][1536] bf16 (transpose) --------
__global__ __launch_bounds__(256) void transpose_x_bf16(
    const float* __restrict__ x, ushort* __restrict__ XT) {
  __shared__ ushort lds[16384];
  const int cc = blockIdx.x * 64, b = blockIdx.y;
  const int t = threadIdx.x;
  const float* xb = x + b * 393216 + cc * 256;
#pragma unroll
  for (int i = 0; i < 16; ++i) {
    const int c0 = i * 4;
    const float v0 = xb[(c0 + 0) * 256 + t];
    const float v1 = xb[(c0 + 1) * 256 + t];
    const float v2 = xb[(c0 + 2) * 256 + t];
    const float v3 = xb[(c0 + 3) * 256 + t];
    uint2 o;
    o.x = pack_bf16x2(v0, v1);
    o.y = pack_bf16x2(v2, v3);
    const int g = c0 >> 3;
    const int waddr = t * 128 + (((g ^ (t & 7)) << 4) | ((c0 & 7) << 1));
    *(uint2*)((char*)lds + waddr) = o;
  }
  __syncthreads();
#pragma unroll
  for (int r = 0; r < 8; ++r) {
    const int j = r * 32 + (t >> 3), q = t & 7;
    const uint4 o =
        *(const uint4*)((const char*)lds + j * 128 + ((q ^ (j & 7)) << 4));
    *(uint4*)(XT + (size_t)(b * 256 + j) * 1536 + cc + q * 8) = o;
  }
}

// ---- layer-1 GEMM: 256x256 tile, BK=32 ring-4, counted vmcnt (T2+T3+T4+T5) -
// HT[j][h] = bf16(relu(A1[h]·XT[j] + b1[h])), A1 [1024][1536] stacked.
// 512 thr = 8 waves (2M x 4N), per-wave C 128x64. Grid 256 = 1 block/CU.
// LDS: 4 slots x (A 16KB + B 16KB) = 128 KiB.
// Slot granule layout (T2, via permuted global source; linear LDS dest):
//   gi(row,g) = g*256 + (row & 0xF8) + ((row + 2*g) & 7)   [bijective]
// -> ds_read_b128 quarter-waves hit each bank-slot exactly 2x (conflict-min).
__global__ __launch_bounds__(512) void gemm1_mfma8(
    const ushort* __restrict__ A1, const ushort* __restrict__ Bt,
    const float* __restrict__ b1, ushort* __restrict__ HT) {
  __shared__ ushort lds[65536];  // 128 KiB
  const int tid = threadIdx.x, l = tid & 63, w = tid >> 6;
  const int bid = blockIdx.x;
  const int newid = (bid & 7) * 32 + (bid >> 3);  // XCD-bijective (256%8==0)
  const int m0 = (newid & 3) * 256, n0 = (newid >> 2) * 256;
  const int wr = w >> 2, wc = w & 3;  // 2x4 wave grid
  const int lr = l & 15, kq = l >> 4;

  f32x4 acc[8][4];
#pragma unroll
  for (int mi = 0; mi < 8; ++mi)
#pragma unroll
    for (int ni = 0; ni < 4; ++ni) acc[mi][ni] = (f32x4){0.f, 0.f, 0.f, 0.f};

  // staged-source permutation (inverse of gi): thread's two granules u, u+512
  const int u0 = tid, u1 = tid + 512;
  const int gA0 = u0 >> 8, gA1 = u1 >> 8;
  const int row0 = (u0 & 0xF8) | (((u0 & 7) - 2 * gA0) & 7);
  const int row1 = (u1 & 0xF8) | (((u1 & 7) - 2 * gA1) & 7);
  const ushort* srcA0 = A1 + (size_t)(m0 + row0) * 1536 + gA0 * 8;
  const ushort* srcA1 = A1 + (size_t)(m0 + row1) * 1536 + gA1 * 8;
  const ushort* srcB0 = Bt + (size_t)(n0 + row0) * 1536 + gA0 * 8;
  const ushort* srcB1 = Bt + (size_t)(n0 + row1) * 1536 + gA1 * 8;
  const int wofs = w * 512;  // wave's contiguous 64-granule LDS window (ushorts)

  // per-thread ds_read offsets (ushort units) into a slot
  int offA[8], offB[4];
#pragma unroll
  for (int mi = 0; mi < 8; ++mi) {
    const int row = wr * 128 + mi * 16 + lr;
    offA[mi] = (kq * 256 + (row & 0xF8) + ((row + 2 * kq) & 7)) * 8;
  }
#pragma unroll
  for (int ni = 0; ni < 4; ++ni) {
    const int row = wc * 64 + ni * 16 + lr;
    offB[ni] = (kq * 256 + (row & 0xF8) + ((row + 2 * kq) & 7)) * 8;
  }

#define STAGE1(kk, s)                                   \
  do {                                                  \
    ushort* As_ = &lds[(s)*8192 + wofs];                \
    ushort* Bs_ = &lds[32768 + (s)*8192 + wofs];        \
    gload_lds16(srcA0 + (kk)*32, As_);                  \
    gload_lds16(srcA1 + (kk)*32, As_ + 4096);           \
    gload_lds16(srcB0 + (kk)*32, Bs_);                  \
    gload_lds16(srcB1 + (kk)*32, Bs_ + 4096);           \
  } while (0)

  // prologue: stage sub-tiles 0,1; wait tile 0 (4 newest stay in flight)
  STAGE1(0, 0);
  STAGE1(1, 1);
  asm volatile("s_waitcnt vmcnt(4)" ::: "memory");
  __builtin_amdgcn_s_barrier();

  for (int u = 0; u < 48; ++u) {
    if (u + 2 < 48) STAGE1(u + 2, (u + 2) & 3);
    const ushort* Ab = &lds[(u & 3) * 8192];
    const ushort* Bb = &lds[32768 + (u & 3) * 8192];
    s16x8 af[8], bfr[4];
#pragma unroll
    for (int mi = 0; mi < 8; ++mi) af[mi] = *(const s16x8*)(Ab + offA[mi]);
#pragma unroll
    for (int ni = 0; ni < 4; ++ni) bfr[ni] = *(const s16x8*)(Bb + offB[ni]);
    __builtin_amdgcn_s_setprio(1);
#pragma unroll
    for (int mi = 0; mi < 8; ++mi)
#pragma unroll
      for (int ni = 0; ni < 4; ++ni)
        acc[mi][ni] = __builtin_amdgcn_mfma_f32_16x16x32_bf16(
            af[mi], bfr[ni], acc[mi][ni], 0, 0, 0);
    __builtin_amdgcn_s_setprio(0);
    if (u + 2 < 48) {
      asm volatile("s_waitcnt vmcnt(4)" ::: "memory");  // next tile landed;
                                                        // newest 4 in flight
    } else if (u + 1 < 48) {
      asm volatile("s_waitcnt vmcnt(0)" ::: "memory");  // drain final tile
    }
    if (u + 1 < 48) __builtin_amdgcn_s_barrier();
  }
#undef STAGE1

  // epilogue: h = m0+wr*128+mi*16+kq*4+j, token col = n0+wc*64+ni*16+lr
#pragma unroll
  for (int mi = 0; mi < 8; ++mi) {
    const int rbase = m0 + wr * 128 + mi * 16 + kq * 4;
    float b4[4];
#pragma unroll
    for (int j = 0; j < 4; ++j) b4[j] = b1[rbase + j];
#pragma unroll
    for (int ni = 0; ni < 4; ++ni) {
      const int col = n0 + wc * 64 + ni * 16 + lr;
      const float v0 = fmaxf(acc[mi][ni][0] + b4[0], 0.f);
      const float v1 = fmaxf(acc[mi][ni][1] + b4[1], 0.f);
      const float v2 = fmaxf(acc[mi][ni][2] + b4[2], 0.f);
      const float v3 = fmaxf(acc[mi][ni][3] + b4[3], 0.f);
      uint2 o;
      o.x = pack_bf16x2(v0, v1);
      o.y = pack_bf16x2(v2, v3);
      *(uint2*)(HT + (size_t)col * 1024 + rbase) = o;
    }
  }
}

// ---- layer-2 MFMA GEMM, 2-phase dbuf (unchanged from passing r7) -----------
__global__ __launch_bounds__(256) void gemm2_mfma(
    const ushort* __restrict__ A2, const ushort* __restrict__ HT,
    const float* __restrict__ b2, float* __restrict__ C2,
    ushort* __restrict__ Fb) {
  constexpr int K = 1024;
  __shared__ ushort As[2 * 128 * 32];
  __shared__ ushort Bs[2 * 128 * 32];
  const int tid = threadIdx.x;
  const int l = tid & 63, w = tid >> 6;
  const int bid = blockIdx.x;
  const int newid = (bid & 7) * 32 + (bid >> 3);
  const int m0 = (newid & 1) * 128, n0 = (newid >> 1) * 128;
  const int wr = w >> 1, wc = w & 1;
  const int lr = l & 15, kq = l >> 4;

  f32x4 acc[4][4];
#pragma unroll
  for (int mi = 0; mi < 4; ++mi)
#pragma unroll
    for (int ni = 0; ni < 4; ++ni) acc[mi][ni] = (f32x4){0.f, 0.f, 0.f, 0.f};

  const int rA0 = tid >> 2;
  const int q8 = (tid & 3) * 8;
  ushort* AsW0 = As + (w * 64) * 8;
  ushort* AsW1 = As + (256 + w * 64) * 8;
  ushort* BsW0 = Bs + (w * 64) * 8;
  ushort* BsW1 = Bs + (256 + w * 64) * 8;
  const ushort* Arow0 = A2 + (size_t)(m0 + rA0) * K + q8;
  const ushort* Arow1 = A2 + (size_t)(m0 + rA0 + 64) * K + q8;
  const ushort* Brow0 = HT + (size_t)(n0 + rA0) * K + q8;
  const ushort* Brow1 = HT + (size_t)(n0 + rA0 + 64) * K + q8;

  gload_lds16(Arow0, AsW0);
  gload_lds16(Arow1, AsW1);
  gload_lds16(Brow0, BsW0);
  gload_lds16(Brow1, BsW1);
  __syncthreads();

  int cur = 0;
  for (int k0 = 0; k0 < K; k0 += 32) {
    const int nxt = cur ^ 1;
    if (k0 + 32 < K) {
      gload_lds16(Arow0 + k0 + 32, AsW0 + nxt * 4096);
      gload_lds16(Arow1 + k0 + 32, AsW1 + nxt * 4096);
      gload_lds16(Brow0 + k0 + 32, BsW0 + nxt * 4096);
      gload_lds16(Brow1 + k0 + 32, BsW1 + nxt * 4096);
    }
    const ushort* Ab = As + cur * 4096;
    const ushort* Bb = Bs + cur * 4096;
    s16x8 af[4], bfr[4];
#pragma unroll
    for (int mi = 0; mi < 4; ++mi)
      af[mi] = *(const s16x8*)(Ab + (wr * 64 + mi * 16 + lr) * 32 + kq * 8);
#pragma unroll
    for (int ni = 0; ni < 4; ++ni)
      bfr[ni] = *(const s16x8*)(Bb + (wc * 64 + ni * 16 + lr) * 32 + kq * 8);
#pragma unroll
    for (int mi = 0; mi < 4; ++mi)
#pragma unroll
      for (int ni = 0; ni < 4; ++ni)
        acc[mi][ni] = __builtin_amdgcn_mfma_f32_16x16x32_bf16(
            af[mi], bfr[ni], acc[mi][ni], 0, 0, 0);
    __syncthreads();
    cur = nxt;
  }

#pragma unroll
  for (int mi = 0; mi < 4; ++mi) {
    const int rbase = m0 + wr * 64 + mi * 16 + kq * 4;
    if (rbase < 192) {
      float b4[4];
#pragma unroll
      for (int j = 0; j < 4; ++j) b4[j] = b2[rbase + j];
      if (rbase < 128) {
#pragma unroll
        for (int ni = 0; ni < 4; ++ni) {
          const int col = n0 + wc * 64 + ni * 16 + lr;
#pragma unroll
          for (int j = 0; j < 4; ++j)
            Fb[(size_t)(rbase + j) * BNT + col] =
                f32_to_bf16_rne(acc[mi][ni][j] + b4[j]);
        }
      } else {
#pragma unroll
        for (int ni = 0; ni < 4; ++ni) {
          const int col = n0 + wc * 64 + ni * 16 + lr;
          float* cr = C2 + (size_t)rbase * BNT + col;
#pragma unroll
          for (int j = 0; j < 4; ++j)
            cr[(size_t)j * BNT] = acc[mi][ni][j] + b4[j];
        }
      }
    }
  }
}

// ---------------- Sinkhorn -> P bf16 ----------------------------------------
__global__ __launch_bounds__(256) void sinkhorn_b16(
    const float* __restrict__ S, const float* __restrict__ dustp,
    ushort* __restrict__ Pb) {
  const int b = blockIdx.x, tid = threadIdx.x;
  const int lane = tid & 63, wave = tid >> 6;
  __shared__ float Ms[65][256];
  __shared__ float u[65];
  __shared__ float v[256];
  const float dust = dustp[0];
  for (int idx = tid; idx < 16384; idx += 256) {
    const int m = idx >> 8, n = idx & 255;
    Ms[m][n] = S[m * BNT + b * 256 + n];
  }
  Ms[64][tid] = dust;
  v[tid] = 0.f;
  if (tid < 65) u[tid] = 0.f;
  const float norm = -logf(320.f);
  const float la_dust = norm + logf(192.f);
  __syncthreads();
  for (int it = 0; it < 3; ++it) {
    for (int i = wave; i < 65; i += 4) {
      const float x0 = Ms[i][lane] + v[lane];
      const float x1 = Ms[i][lane + 64] + v[lane + 64];
      const float x2 = Ms[i][lane + 128] + v[lane + 128];
      const float x3 = Ms[i][lane + 192] + v[lane + 192];
      float mm = fmaxf(fmaxf(x0, x1), fmaxf(x2, x3));
#pragma unroll
      for (int off = 32; off; off >>= 1) mm = fmaxf(mm, __shfl_xor(mm, off));
      float s = expf(x0 - mm) + expf(x1 - mm) + expf(x2 - mm) + expf(x3 - mm);
#pragma unroll
      for (int off = 32; off; off >>= 1) s += __shfl_xor(s, off);
      if (lane == 0) u[i] = (i == 64 ? la_dust : norm) - (logf(s) + mm);
    }
    __syncthreads();
    {
      const int n = tid;
      float mm = -1e30f;
      for (int i = 0; i < 65; ++i) mm = fmaxf(mm, Ms[i][n] + u[i]);
      float s = 0.f;
      for (int i = 0; i < 65; ++i) s += expf(Ms[i][n] + u[i] - mm);
      v[n] = norm - (logf(s) + mm);
    }
    __syncthreads();
  }
  for (int idx = tid; idx < 16384; idx += 256) {
    const int m = idx >> 8, n = idx & 255;
    Pb[b * 16384 + idx] =
        f32_to_bf16_rne(expf(Ms[m][n] + u[m] + v[n] - norm));
  }
}

// ---- VLAD via MFMA, direct from global -------------------------------------
__global__ __launch_bounds__(256) void vlad_mfma(const ushort* __restrict__ Fb,
                                                 const ushort* __restrict__ Pb,
                                                 float* __restrict__ VL) {
  const int b = blockIdx.x;
  const int tid = threadIdx.x, l = tid & 63, w = tid >> 6;
  const int lr = l & 15, ko = l >> 4;
  f32x4 acc[2][4];
#pragma unroll
  for (int li = 0; li < 2; ++li)
#pragma unroll
    for (int ni = 0; ni < 4; ++ni) acc[li][ni] = (f32x4){0.f, 0.f, 0.f, 0.f};
  const ushort* Fbase = Fb + b * 256;
  const ushort* Pbase = Pb + b * 16384;
#pragma unroll
  for (int ks = 0; ks < 8; ++ks) {
    const int k = ks * 32 + ko * 8;
    s16x8 bfr[4];
#pragma unroll
    for (int ni = 0; ni < 4; ++ni)
      bfr[ni] = *(const s16x8*)(Pbase + (ni * 16 + lr) * 256 + k);
#pragma unroll
    for (int li = 0; li < 2; ++li) {
      const s16x8 af =
          *(const s16x8*)(Fbase + (size_t)(w * 32 + li * 16 + lr) * BNT + k);
#pragma unroll
      for (int ni = 0; ni < 4; ++ni)
        acc[li][ni] = __builtin_amdgcn_mfma_f32_16x16x32_bf16(
            af, bfr[ni], acc[li][ni], 0, 0, 0);
    }
  }
#pragma unroll
  for (int li = 0; li < 2; ++li)
#pragma unroll
    for (int ni = 0; ni < 4; ++ni)
#pragma unroll
      for (int j = 0; j < 4; ++j) {
        const int ll = w * 32 + li * 16 + ko * 4 + j;
        const int m = ni * 16 + lr;
        VL[b * 8192 + ll * 64 + m] = acc[li][ni][j];
      }
}

// ---------------- finalize ---------------------------------------------------
__global__ __launch_bounds__(256) void finalize_kernel(
    const float* __restrict__ TK, const float* __restrict__ VL,
    float* __restrict__ out) {
  const int b = blockIdx.x, tid = threadIdx.x;
  const int lane = tid & 63, wave = tid >> 6;
  __shared__ float sred[4];
  __shared__ float ssm_part[4][64];
  __shared__ float invm_s[64];
  __shared__ float totals[1];
  const float* vl = &VL[b * 8192];
  float accv = 0.f;
  for (int k = 0; k < 32; ++k) {
    const float xv = vl[tid + 256 * k];
    accv = fmaf(xv, xv, accv);
  }
  ssm_part[wave][lane] = accv;
  const float tv = TK[b * 256 + tid];
  float ss = tv * tv;
#pragma unroll
  for (int off = 32; off; off >>= 1) ss += __shfl_down(ss, off);
  if (lane == 0) sred[wave] = ss;
  __syncthreads();
  const float sstok = sred[0] + sred[1] + sred[2] + sred[3];
  const float invtok = 1.f / fmaxf(sqrtf(sstok), 1e-12f);
  float tpart = 0.f;
  if (wave == 0) {
    const float s4 = ssm_part[0][tid] + ssm_part[1][tid] + ssm_part[2][tid] +
                     ssm_part[3][tid];
    const float inv = 1.f / fmaxf(sqrtf(s4), 1e-12f);
    invm_s[tid] = inv;
    tpart = s4 * inv * inv;
#pragma unroll
    for (int off = 32; off; off >>= 1) tpart += __shfl_down(tpart, off);
    if (lane == 0) totals[0] = tpart;
  }
  __syncthreads();
  const float total = totals[0] + sstok * invtok * invtok;
  const float invT = 1.f / fmaxf(sqrtf(total), 1e-12f);
  float* ob = &out[b * 8448];
  ob[tid] = tv * invtok * invT;
  for (int k = 0; k < 32; ++k) {
    const int idx = tid + 256 * k;
    ob[256 + idx] = vl[idx] * invm_s[idx & 63] * invT;
  }
}

// ================= fp32 fallback path kernels ===============================
template <bool RELU>
__global__ __launch_bounds__(256) void gemm_tt(
    const float* __restrict__ A, const float* __restrict__ Bw,
    const float* __restrict__ bias, float* __restrict__ C, int K, int Nn) {
  __shared__ float As[16][68];
  __shared__ float Bs[16][68];
  const int tid = threadIdx.x;
  const int tx = tid & 15, ty = tid >> 4;
  const int n0 = blockIdx.x * 64;
  const int lrow = tid >> 2, lkq = (tid & 3) << 2;
  float acc[4][4];
#pragma unroll
  for (int r = 0; r < 4; ++r)
#pragma unroll
    for (int c = 0; c < 4; ++c) acc[r][c] = 0.f;
  for (int k0 = 0; k0 < K; k0 += 16) {
    const float4 av = *(const float4*)&A[lrow * K + k0 + lkq];
    const float4 bv = *(const float4*)&Bw[(n0 + lrow) * K + k0 + lkq];
    As[lkq + 0][lrow] = av.x;
    As[lkq + 1][lrow] = av.y;
    As[lkq + 2][lrow] = av.z;
    As[lkq + 3][lrow] = av.w;
    Bs[lkq + 0][lrow] = bv.x;
    Bs[lkq + 1][lrow] = bv.y;
    Bs[lkq + 2][lrow] = bv.z;
    Bs[lkq + 3][lrow] = bv.w;
    __syncthreads();
#pragma unroll
    for (int kk = 0; kk < 16; ++kk) {
      const float4 a4 = *(const float4*)&As[kk][ty << 2];
      const float4 b4 = *(const float4*)&Bs[kk][tx << 2];
      acc[0][0] = fmaf(a4.x, b4.x, acc[0][0]);
      acc[0][1] = fmaf(a4.x, b4.y, acc[0][1]);
      acc[0][2] = fmaf(a4.x, b4.z, acc[0][2]);
      acc[0][3] = fmaf(a4.x, b4.w, acc[0][3]);
      acc[1][0] = fmaf(a4.y, b4.x, acc[1][0]);
      acc[1][1] = fmaf(a4.y, b4.y, acc[1][1]);
      acc[1][2] = fmaf(a4.y, b4.z, acc[1][2]);
      acc[1][3] = fmaf(a4.y, b4.w, acc[1][3]);
      acc[2][0] = fmaf(a4.z, b4.x, acc[2][0]);
      acc[2][1] = fmaf(a4.z, b4.y, acc[2][1]);
      acc[2][2] = fmaf(a4.z, b4.z, acc[2][2]);
      acc[2][3] = fmaf(a4.z, b4.w, acc[2][3]);
      acc[3][0] = fmaf(a4.w, b4.x, acc[3][0]);
      acc[3][1] = fmaf(a4.w, b4.y, acc[3][1]);
      acc[3][2] = fmaf(a4.w, b4.z, acc[3][2]);
      acc[3][3] = fmaf(a4.w, b4.w, acc[3][3]);
    }
    __syncthreads();
  }
#pragma unroll
  for (int r = 0; r < 4; ++r) {
    const int row = (ty << 2) + r;
    float4 o;
    o.x = acc[r][0] + bias[n0 + (tx << 2) + 0];
    o.y = acc[r][1] + bias[n0 + (tx << 2) + 1];
    o.z = acc[r][2] + bias[n0 + (tx << 2) + 2];
    o.w = acc[r][3] + bias[n0 + (tx << 2) + 3];
    if (RELU) {
      o.x = fmaxf(o.x, 0.f);
      o.y = fmaxf(o.y, 0.f);
      o.z = fmaxf(o.z, 0.f);
      o.w = fmaxf(o.w, 0.f);
    }
    *(float4*)&C[row * Nn + n0 + (tx << 2)] = o;
  }
}

template <bool XVIEW, bool RELU>
__global__ __launch_bounds__(256) void gemm_tile(
    const float* __restrict__ A, const float* __restrict__ Bsrc,
    const float* __restrict__ bias, float* __restrict__ Cout, int K) {
  __shared__ float As[16][68];
  __shared__ float Bsh[16][68];
  const int tid = threadIdx.x;
  const int tx = tid & 15, ty = tid >> 4;
  const int rowBase = blockIdx.y * 64;
  const int colBase = blockIdx.x * 64;
  const int bb = colBase >> 8, n0 = colBase & 255;
  const int boff = XVIEW ? (bb * 393216 + n0) : colBase;
  const int la_row = tid >> 2, la_kq = (tid & 3) << 2;
  const int lb_k = tid >> 4, lb_c = (tid & 15) << 2;
  float acc[4][4];
#pragma unroll
  for (int r = 0; r < 4; ++r)
#pragma unroll
    for (int c = 0; c < 4; ++c) acc[r][c] = 0.f;
  for (int k0 = 0; k0 < K; k0 += 16) {
    const float4 av = *(const float4*)&A[(rowBase + la_row) * K + k0 + la_kq];
    float4 bv;
    if (XVIEW)
      bv = *(const float4*)&Bsrc[boff + (k0 + lb_k) * 256 + lb_c];
    else
      bv = *(const float4*)&Bsrc[(k0 + lb_k) * BNT + boff + lb_c];
    As[la_kq + 0][la_row] = av.x;
    As[la_kq + 1][la_row] = av.y;
    As[la_kq + 2][la_row] = av.z;
    As[la_kq + 3][la_row] = av.w;
    *(float4*)&Bsh[lb_k][lb_c] = bv;
    __syncthreads();
#pragma unroll
    for (int kk = 0; kk < 16; ++kk) {
      const float4 a4 = *(const float4*)&As[kk][ty << 2];
      const float4 b4 = *(const float4*)&Bsh[kk][tx << 2];
      acc[0][0] = fmaf(a4.x, b4.x, acc[0][0]);
      acc[0][1] = fmaf(a4.x, b4.y, acc[0][1]);
      acc[0][2] = fmaf(a4.x, b4.z, acc[0][2]);
      acc[0][3] = fmaf(a4.x, b4.w, acc[0][3]);
      acc[1][0] = fmaf(a4.y, b4.x, acc[1][0]);
      acc[1][1] = fmaf(a4.y, b4.y, acc[1][1]);
      acc[1][2] = fmaf(a4.y, b4.z, acc[1][2]);
      acc[1][3] = fmaf(a4.y, b4.w, acc[1][3]);
      acc[2][0] = fmaf(a4.z, b4.x, acc[2][0]);
      acc[2][1] = fmaf(a4.z, b4.y, acc[2][1]);
      acc[2][2] = fmaf(a4.z, b4.z, acc[2][2]);
      acc[2][3] = fmaf(a4.z, b4.w, acc[2][3]);
      acc[3][0] = fmaf(a4.w, b4.x, acc[3][0]);
      acc[3][1] = fmaf(a4.w, b4.y, acc[3][1]);
      acc[3][2] = fmaf(a4.w, b4.z, acc[3][2]);
      acc[3][3] = fmaf(a4.w, b4.w, acc[3][3]);
    }
    __syncthreads();
  }
#pragma unroll
  for (int r = 0; r < 4; ++r) {
    const int row = rowBase + (ty << 2) + r;
    const float bsv = bias[row];
    float4 o;
    o.x = acc[r][0] + bsv;
    o.y = acc[r][1] + bsv;
    o.z = acc[r][2] + bsv;
    o.w = acc[r][3] + bsv;
    if (RELU) {
      o.x = fmaxf(o.x, 0.f);
      o.y = fmaxf(o.y, 0.f);
      o.z = fmaxf(o.z, 0.f);
      o.w = fmaxf(o.w, 0.f);
    }
    *(float4*)&Cout[row * BNT + colBase + (tx << 2)] = o;
  }
}

__global__ __launch_bounds__(256) void sinkhorn_kernel(
    const float* __restrict__ S, const float* __restrict__ dustp,
    float* __restrict__ P) {
  const int b = blockIdx.x, tid = threadIdx.x;
  const int lane = tid & 63, wave = tid >> 6;
  __shared__ float Ms[65][256];
  __shared__ float u[65];
  __shared__ float v[256];
  const float dust = dustp[0];
  for (int idx = tid; idx < 16384; idx += 256) {
    const int m = idx >> 8, n = idx & 255;
    Ms[m][n] = S[m * BNT + b * 256 + n];
  }
  Ms[64][tid] = dust;
  v[tid] = 0.f;
  if (tid < 65) u[tid] = 0.f;
  const float norm = -logf(320.f);
  const float la_dust = norm + logf(192.f);
  __syncthreads();
  for (int it = 0; it < 3; ++it) {
    for (int i = wave; i < 65; i += 4) {
      const float x0 = Ms[i][lane] + v[lane];
      const float x1 = Ms[i][lane + 64] + v[lane + 64];
      const float x2 = Ms[i][lane + 128] + v[lane + 128];
      const float x3 = Ms[i][lane + 192] + v[lane + 192];
      float mm = fmaxf(fmaxf(x0, x1), fmaxf(x2, x3));
#pragma unroll
      for (int off = 32; off; off >>= 1) mm = fmaxf(mm, __shfl_xor(mm, off));
      float s = expf(x0 - mm) + expf(x1 - mm) + expf(x2 - mm) + expf(x3 - mm);
#pragma unroll
      for (int off = 32; off; off >>= 1) s += __shfl_xor(s, off);
      if (lane == 0) u[i] = (i == 64 ? la_dust : norm) - (logf(s) + mm);
    }
    __syncthreads();
    {
      const int n = tid;
      float mm = -1e30f;
      for (int i = 0; i < 65; ++i) mm = fmaxf(mm, Ms[i][n] + u[i]);
      float s = 0.f;
      for (int i = 0; i < 65; ++i) s += expf(Ms[i][n] + u[i] - mm);
      v[n] = norm - (logf(s) + mm);
    }
    __syncthreads();
  }
  for (int idx = tid; idx < 16384; idx += 256) {
    const int m = idx >> 8, n = idx & 255;
    P[b * 16384 + idx] = expf(Ms[m][n] + u[m] + v[n] - norm);
  }
}

__device__ __forceinline__ int ps_idx(int m, int n) {
  return m * 256 + ((((n >> 2) ^ (m & 7)) << 2) | (n & 3));
}
__global__ __launch_bounds__(256) void vlad_kernel(const float* __restrict__ F,
                                                   const float* __restrict__ P,
                                                   float* __restrict__ VL) {
  const int b = blockIdx.x, half = blockIdx.y;
  const int tid = threadIdx.x;
  const int m = tid & 63, lg = tid >> 6;
  __shared__ float ps[64 * 256];
  for (int idx = tid; idx < 16384; idx += 256) {
    const int mm = idx >> 8, n = idx & 255;
    ps[ps_idx(mm, n)] = P[b * 16384 + idx];
  }
  __syncthreads();
  float acc[16];
#pragma unroll
  for (int i = 0; i < 16; ++i) acc[i] = 0.f;
  for (int i = 0; i < 16; ++i) {
    const int ll = half * 64 + lg + 4 * i;
    const float* frow = &F[(size_t)ll * BNT + b * 256];
    float a = 0.f;
#pragma unroll 8
    for (int nq = 0; nq < 64; ++nq) {
      const float4 f4 = *(const float4*)&frow[nq << 2];
      const float4 p4 = *(const float4*)&ps[m * 256 + ((nq ^ (m & 7)) << 2)];
      a = fmaf(f4.x, p4.x, a);
      a = fmaf(f4.y, p4.y, a);
      a = fmaf(f4.z, p4.z, a);
      a = fmaf(f4.w, p4.w, a);
    }
    acc[i] = a;
  }
#pragma unroll
  for (int i = 0; i < 16; ++i) {
    const int ll = half * 64 + lg + 4 * i;
    VL[b * 8192 + ll * 64 + m] = acc[i];
  }
}

extern "C" void kernel_launch(void* const* d_in, const int* in_sizes, int n_in,
                              void* d_out, int out_size, void* d_ws,
                              size_t ws_size, hipStream_t stream) {
  const float* x = (const float*)d_in[0];
  const float* t = (const float*)d_in[1];
  const float* Wt1 = (const float*)d_in[2];
  const float* bt1 = (const float*)d_in[3];
  const float* Wt2 = (const float*)d_in[4];
  const float* bt2 = (const float*)d_in[5];
  const float* Wc1 = (const float*)d_in[6];
  const float* bc1 = (const float*)d_in[7];
  const float* Wc2 = (const float*)d_in[8];
  const float* bc2 = (const float*)d_in[9];
  const float* Ws1 = (const float*)d_in[10];
  const float* bs1 = (const float*)d_in[11];
  const float* Ws2 = (const float*)d_in[12];
  const float* bs2 = (const float*)d_in[13];
  const float* dust = (const float*)d_in[14];
  float* out = (float*)d_out;

  if (ws_size >= 97714176ull) {
    char* base = (char*)d_ws;
    ushort* Tb = (ushort*)base;
    ushort* Wt1b = (ushort*)(base + 196608);
    ushort* Wt2b = (ushort*)(base + 1769472);
    float* Pt = (float*)(base + 2031616);
    ushort* Hb = (ushort*)(base + 2555904);
    ushort* XT = (ushort*)base;
    ushort* Pb = (ushort*)base;
    float* VL = (float*)(base + 4194304);
    ushort* Fb = (ushort*)(base + 8388608);
    ushort* HT = (ushort*)(base + 50331648);
    float* C2 = (float*)(base + 83886080);
    ushort* A1 = (ushort*)(base + 83886080);
    ushort* Wc1b = A1;
    ushort* Ws1b = (ushort*)(base + 85458944);
    ushort* A2 = (ushort*)(base + 96468992);
    float* b2 = (float*)(base + 96993280);
    float* TK = (float*)(base + 96994304);
    float* b1 = (float*)(base + 97059840);
    float* Sb = C2 + (size_t)128 * BNT;

    prep_all<<<2788, 256, 0, stream>>>(t, Wt1, Wt2, Wc1, Ws1, bc1, bs1, Wc2,
                                       Ws2, bc2, bs2, Tb, Wt1b, Wt2b, Wc1b,
                                       Ws1b, b1, A2, b2);
    token1_mfma<<<dim3(8, 4), 256, 0, stream>>>(Tb, Wt1b, Pt);
    token1_reduce<<<64, 256, 0, stream>>>(Pt, bt1, Hb);
    token2_mfma<<<4, 256, 0, stream>>>(Hb, Wt2b, bt2, TK);
    transpose_x_bf16<<<dim3(24, 64), 256, 0, stream>>>(x, XT);
    gemm1_mfma8<<<256, 512, 0, stream>>>(A1, XT, b1, HT);
    gemm2_mfma<<<256, 256, 0, stream>>>(A2, HT, b2, C2, Fb);
    sinkhorn_b16<<<64, 256, 0, stream>>>(Sb, dust, Pb);
    vlad_mfma<<<64, 256, 0, stream>>>(Fb, Pb, VL);
    finalize_kernel<<<64, 256, 0, stream>>>(TK, VL, out);
  } else {
    float* ws = (float*)d_ws;
    float* H = ws;
    float* F = H + 512 * BNT;
    float* Sb = F + 128 * BNT;
    float* P = Sb + 64 * BNT;
    float* VL = P + 64 * BNT;
    float* TK = VL + 64 * 8192;
    float* Hh = P;

    gemm_tt<true><<<dim3(8, 1), 256, 0, stream>>>(t, Wt1, bt1, Hh, 1536, 512);
    gemm_tt<false><<<dim3(4, 1), 256, 0, stream>>>(Hh, Wt2, bt2, TK, 512, 256);
    gemm_tile<true, true><<<dim3(256, 8), 256, 0, stream>>>(Wc1, x, bc1, H, 1536);
    gemm_tile<false, false><<<dim3(256, 2), 256, 0, stream>>>(Wc2, H, bc2, F, 512);
    gemm_tile<true, true><<<dim3(256, 8), 256, 0, stream>>>(Ws1, x, bs1, H, 1536);
    gemm_tile<false, false><<<dim3(256, 1), 256, 0, stream>>>(Ws2, H, bs2, Sb, 512);
    sinkhorn_kernel<<<64, 256, 0, stream>>>(Sb, dust, P);
    vlad_kernel<<<dim3(64, 2), 256, 0, stream>>>(F, P, VL);
    finalize_kernel<<<64, 256, 0, stream>>>(TK, VL, out);
  }
}

// Round 9
// 191.227 us; speedup vs baseline: 1.2164x; 1.2164x over previous
//
#include <hip/hip_runtime.h>
#include <math.h>

// SALAD head. B=64, C=1536, N=256, HID=512, L=128, M=64, G=256. BNT = B*N.
#define BNT 16384

using f32x4 = __attribute__((ext_vector_type(4))) float;
using s16x8 = __attribute__((ext_vector_type(8))) short;

__device__ __forceinline__ unsigned short f32_to_bf16_rne(float f) {
  unsigned int u = __float_as_uint(f);
  u += 0x7FFFu + ((u >> 16) & 1u);
  return (unsigned short)(u >> 16);
}
__device__ __forceinline__ unsigned pack_bf16x2(float a, float b) {
  return (unsigned)f32_to_bf16_rne(a) | ((unsigned)f32_to_bf16_rne(b) << 16);
}

__device__ __forceinline__ void gload_lds16(const ushort* g, ushort* lds) {
  __builtin_amdgcn_global_load_lds(
      (const __attribute__((address_space(1))) unsigned int*)g,
      (__attribute__((address_space(3))) unsigned int*)lds, 16, 0, 0);
}

// ---- fused prep: bf16 converts of t,Wt1,Wt2,Wc1,Ws1 + b1 stack + A2 stack --
__global__ __launch_bounds__(256) void prep_all(
    const float* __restrict__ t, const float* __restrict__ Wt1,
    const float* __restrict__ Wt2, const float* __restrict__ Wc1,
    const float* __restrict__ Ws1, const float* __restrict__ bc1,
    const float* __restrict__ bs1, const float* __restrict__ Wc2,
    const float* __restrict__ Ws2, const float* __restrict__ bc2,
    const float* __restrict__ bs2, ushort* __restrict__ Tb,
    ushort* __restrict__ Wt1b, ushort* __restrict__ Wt2b,
    ushort* __restrict__ Wc1b, ushort* __restrict__ Ws1b,
    float* __restrict__ b1, ushort* __restrict__ A2, float* __restrict__ b2) {
  const int bid = blockIdx.x, tid = threadIdx.x;
  const float* src = nullptr;
  ushort* dst = nullptr;
  int i = 0;
  if (bid < 96) {
    src = t; dst = Tb; i = bid * 256 + tid;
  } else if (bid < 864) {
    src = Wt1; dst = Wt1b; i = (bid - 96) * 256 + tid;
  } else if (bid < 992) {
    src = Wt2; dst = Wt2b; i = (bid - 864) * 256 + tid;
  } else if (bid < 1760) {
    src = Wc1; dst = Wc1b; i = (bid - 992) * 256 + tid;
  } else if (bid < 2528) {
    src = Ws1; dst = Ws1b; i = (bid - 1760) * 256 + tid;
  } else if (bid < 2532) {
    const int j = (bid - 2528) * 256 + tid;
    b1[j] = j < 512 ? bc1[j] : bs1[j - 512];
    return;
  } else {
    const int r = bid - 2532;
    const int c = tid * 4;
    float v[4] = {0.f, 0.f, 0.f, 0.f};
    if (r < 128) {
      if (c < 512) {
#pragma unroll
        for (int j = 0; j < 4; ++j) v[j] = Wc2[r * 512 + c + j];
      }
    } else if (r < 192) {
      if (c >= 512) {
#pragma unroll
        for (int j = 0; j < 4; ++j) v[j] = Ws2[(r - 128) * 512 + (c - 512) + j];
      }
    }
    uint2 o;
    o.x = pack_bf16x2(v[0], v[1]);
    o.y = pack_bf16x2(v[2], v[3]);
    *(uint2*)(A2 + r * 1024 + c) = o;
    if (tid == 0) b2[r] = r < 128 ? bc2[r] : (r < 192 ? bs2[r - 128] : 0.f);
    return;
  }
  const float4 v = ((const float4*)src)[i];
  uint2 o;
  o.x = pack_bf16x2(v.x, v.y);
  o.y = pack_bf16x2(v.z, v.w);
  ((uint2*)dst)[i] = o;
}

// ---- token layer 1 (MFMA, no LDS, split-K) ---------------------------------
__global__ __launch_bounds__(256) void token1_mfma(
    const ushort* __restrict__ Tb, const ushort* __restrict__ Wt1b,
    float* __restrict__ Pt) {
  const int ct = blockIdx.x, kc = blockIdx.y;
  const int tid = threadIdx.x, l = tid & 63, wv = tid >> 6;
  const int lr = l & 15, ko = l >> 4;
  const int col = ct * 64 + wv * 16 + lr;
  f32x4 acc[4];
#pragma unroll
  for (int r = 0; r < 4; ++r) acc[r] = (f32x4){0.f, 0.f, 0.f, 0.f};
  const int k0 = kc * 384;
#pragma unroll 4
  for (int ks = 0; ks < 12; ++ks) {
    const int k = k0 + ks * 32 + ko * 8;
    const s16x8 bf = *(const s16x8*)(Wt1b + (size_t)col * 1536 + k);
#pragma unroll
    for (int rf = 0; rf < 4; ++rf) {
      const s16x8 af = *(const s16x8*)(Tb + (size_t)(rf * 16 + lr) * 1536 + k);
      acc[rf] =
          __builtin_amdgcn_mfma_f32_16x16x32_bf16(af, bf, acc[rf], 0, 0, 0);
    }
  }
#pragma unroll
  for (int rf = 0; rf < 4; ++rf)
#pragma unroll
    for (int j = 0; j < 4; ++j) {
      const int row = rf * 16 + ko * 4 + j;
      Pt[((kc * 64 + row) << 9) + col] = acc[rf][j];
    }
}

// ---- token layer-1 reduce --------------------------------------------------
__global__ __launch_bounds__(256) void token1_reduce(
    const float* __restrict__ Pt, const float* __restrict__ bt1,
    ushort* __restrict__ Hb) {
  const int i = blockIdx.x * 256 + threadIdx.x;
  const int row = i >> 8, c2 = (i & 255) * 2;
  float v0 = bt1[c2], v1 = bt1[c2 + 1];
#pragma unroll
  for (int kc = 0; kc < 4; ++kc) {
    v0 += Pt[((kc * 64 + row) << 9) + c2];
    v1 += Pt[((kc * 64 + row) << 9) + c2 + 1];
  }
  v0 = fmaxf(v0, 0.f);
  v1 = fmaxf(v1, 0.f);
  ((unsigned*)Hb)[i] = pack_bf16x2(v0, v1);
}

// ---- token layer 2 (MFMA, no LDS) ------------------------------------------
__global__ __launch_bounds__(256) void token2_mfma(
    const ushort* __restrict__ Hb, const ushort* __restrict__ Wt2b,
    const float* __restrict__ bt2, float* __restrict__ TK) {
  const int ct = blockIdx.x;
  const int tid = threadIdx.x, l = tid & 63, wv = tid >> 6;
  const int lr = l & 15, ko = l >> 4;
  const int col = ct * 64 + wv * 16 + lr;
  f32x4 acc[4];
#pragma unroll
  for (int r = 0; r < 4; ++r) acc[r] = (f32x4){0.f, 0.f, 0.f, 0.f};
#pragma unroll 4
  for (int ks = 0; ks < 16; ++ks) {
    const int k = ks * 32 + ko * 8;
    const s16x8 bf = *(const s16x8*)(Wt2b + (size_t)col * 512 + k);
#pragma unroll
    for (int rf = 0; rf < 4; ++rf) {
      const s16x8 af = *(const s16x8*)(Hb + (size_t)(rf * 16 + lr) * 512 + k);
      acc[rf] =
          __builtin_amdgcn_mfma_f32_16x16x32_bf16(af, bf, acc[rf], 0, 0, 0);
    }
  }
  const float bb = bt2[col];
#pragma unroll
  for (int rf = 0; rf < 4; ++rf)
#pragma unroll
    for (int j = 0; j < 4; ++j)
      TK[(rf * 16 + ko * 4 + j) * 256 + col] = acc[rf][j] + bb;
}

// ------- x [64][1536][256] fp32 -> XT [16384][1536] bf16 (transpose) --------
__global__ __launch_bounds__(256) void transpose_x_bf16(
    const float* __restrict__ x, ushort* __restrict__ XT) {
  __shared__ ushort lds[16384];
  const int cc = blockIdx.x * 64, b = blockIdx.y;
  const int t = threadIdx.x;
  const float* xb = x + b * 393216 + cc * 256;
#pragma unroll
  for (int i = 0; i < 16; ++i) {
    const int c0 = i * 4;
    const float v0 = xb[(c0 + 0) * 256 + t];
    const float v1 = xb[(c0 + 1) * 256 + t];
    const float v2 = xb[(c0 + 2) * 256 + t];
    const float v3 = xb[(c0 + 3) * 256 + t];
    uint2 o;
    o.x = pack_bf16x2(v0, v1);
    o.y = pack_bf16x2(v2, v3);
    const int g = c0 >> 3;
    const int waddr = t * 128 + (((g ^ (t & 7)) << 4) | ((c0 & 7) << 1));
    *(uint2*)((char*)lds + waddr) = o;
  }
  __syncthreads();
#pragma unroll
  for (int r = 0; r < 8; ++r) {
    const int j = r * 32 + (t >> 3), q = t & 7;
    const uint4 o =
        *(const uint4*)((const char*)lds + j * 128 + ((q ^ (j & 7)) << 4));
    *(uint4*)(XT + (size_t)(b * 256 + j) * 1536 + cc + q * 8) = o;
  }
}

// ---- layer-1 GEMM: 256x256, BK=64, 8-phase schedule (T2+T3+T4+T5) ----------
// HT[j][h] = bf16(relu(A1[h]·XT[j] + b1[h])), A1 [1024][1536] stacked.
// 512 thr (8 waves, 2Mx4N), per-wave 128x64. LDS = 2dbuf x 2Khalf x 256x32
// per operand = 128 KiB. Per K-tile window: 4 phases, each {ds_read subtile,
// stage 1 half, barrier, 16 MFMA (setprio), barrier}; counted vmcnt(4) at
// P2 & P4 only. Slot layout: byte = row*64 + ((kq ^ ((row>>1)&3))*16) —
// conflict-free b128 reads; staged via inverse-permuted global source.
__global__ __launch_bounds__(512) void gemm1_8ph(
    const ushort* __restrict__ A1, const ushort* __restrict__ Bt,
    const float* __restrict__ b1, ushort* __restrict__ HT) {
  __shared__ ushort lds[65536];  // A: [0,32768) 4 slots; B: [32768,65536)
  const int tid = threadIdx.x, l = tid & 63, w = tid >> 6;
  const int bid = blockIdx.x;
  const int newid = (bid & 7) * 32 + (bid >> 3);  // XCD-bijective (256%8==0)
  const int m0 = (newid & 3) * 256, n0 = (newid >> 2) * 256;
  const int wr = w >> 2, wc = w & 3;  // 2x4 wave grid
  const int lr = l & 15, kq = l >> 4;
  const int permK8 = (kq ^ ((lr >> 1) & 3)) * 8;  // ushort offset in row
  const int aRow = wr * 128 + lr;                 // + mi*16
  const int bRow = wc * 64 + lr;                  // + ni*16

  f32x4 acc[8][4];
#pragma unroll
  for (int mi = 0; mi < 8; ++mi)
#pragma unroll
    for (int ni = 0; ni < 4; ++ni) acc[mi][ni] = (f32x4){0.f, 0.f, 0.f, 0.f};

  // stage source: thread tid stages LDS granules n=tid and n=tid+512.
  // granule n -> (row=n>>2, slotpos=n&3); source kq = slotpos ^ ((row>>1)&3)
  const int srow = tid >> 2, ssp = tid & 3;
  const int skq = ssp ^ ((srow >> 1) & 3);  // same for row and row+128
  const ushort* sA0 = A1 + (size_t)(m0 + srow) * 1536 + skq * 8;
  const ushort* sA1 = A1 + (size_t)(m0 + srow + 128) * 1536 + skq * 8;
  const ushort* sB0 = Bt + (size_t)(n0 + srow) * 1536 + skq * 8;
  const ushort* sB1 = Bt + (size_t)(n0 + srow + 128) * 1536 + skq * 8;
  const int wofs = w * 512;  // wave-linear granule window (ushorts)

#define STG_A(tau, kh)                                              \
  do {                                                              \
    ushort* d = &lds[((((tau)&1) * 2 + (kh)) * 8192) + wofs];       \
    gload_lds16(sA0 + (tau)*64 + (kh)*32, d);                       \
    gload_lds16(sA1 + (tau)*64 + (kh)*32, d + 4096);                \
  } while (0)
#define STG_B(tau, kh)                                              \
  do {                                                              \
    ushort* d = &lds[32768 + ((((tau)&1) * 2 + (kh)) * 8192) + wofs]; \
    gload_lds16(sB0 + (tau)*64 + (kh)*32, d);                       \
    gload_lds16(sB1 + (tau)*64 + (kh)*32, d + 4096);                \
  } while (0)

  // prologue: K-tile 0 fully staged (one-time drain)
  STG_A(0, 0);
  STG_B(0, 0);
  STG_A(0, 1);
  STG_B(0, 1);
  asm volatile("s_waitcnt vmcnt(0)" ::: "memory");
  __builtin_amdgcn_s_barrier();

  for (int sg = 0; sg < 24; ++sg) {
    const int rho = sg & 1;
    const int As0 = (rho * 2 + 0) * 8192, As1 = (rho * 2 + 1) * 8192;
    const int Bs0 = 32768 + As0, Bs1 = 32768 + As1;
    const bool st = (sg + 1) < 24;
    s16x8 af[4], bfv[4];

    // ---- P1: kh0, mi 0-3 (reads A 4 + B 4)
#pragma unroll
    for (int i = 0; i < 4; ++i)
      af[i] = *(const s16x8*)&lds[As0 + (aRow + i * 16) * 32 + permK8];
#pragma unroll
    for (int ni = 0; ni < 4; ++ni)
      bfv[ni] = *(const s16x8*)&lds[Bs0 + (bRow + ni * 16) * 32 + permK8];
    if (st) STG_A(sg + 1, 0);
    __builtin_amdgcn_s_barrier();
    __builtin_amdgcn_s_setprio(1);
#pragma unroll
    for (int i = 0; i < 4; ++i)
#pragma unroll
      for (int ni = 0; ni < 4; ++ni)
        acc[i][ni] = __builtin_amdgcn_mfma_f32_16x16x32_bf16(af[i], bfv[ni],
                                                             acc[i][ni], 0, 0, 0);
    __builtin_amdgcn_s_setprio(0);
    __builtin_amdgcn_s_barrier();

    // ---- P2: kh0, mi 4-7 (reads A 4, reuses B)
#pragma unroll
    for (int i = 0; i < 4; ++i)
      af[i] = *(const s16x8*)&lds[As0 + (aRow + 64 + i * 16) * 32 + permK8];
    if (st) STG_B(sg + 1, 0);
    if (sg < 23)
      asm volatile("s_waitcnt vmcnt(4)" ::: "memory");
    else
      asm volatile("s_waitcnt vmcnt(0)" ::: "memory");
    __builtin_amdgcn_s_barrier();
    __builtin_amdgcn_s_setprio(1);
#pragma unroll
    for (int i = 0; i < 4; ++i)
#pragma unroll
      for (int ni = 0; ni < 4; ++ni)
        acc[4 + i][ni] = __builtin_amdgcn_mfma_f32_16x16x32_bf16(
            af[i], bfv[ni], acc[4 + i][ni], 0, 0, 0);
    __builtin_amdgcn_s_setprio(0);
    __builtin_amdgcn_s_barrier();

    // ---- P3: kh1, mi 0-3 (reads A 4 + B 4)
#pragma unroll
    for (int i = 0; i < 4; ++i)
      af[i] = *(const s16x8*)&lds[As1 + (aRow + i * 16) * 32 + permK8];
#pragma unroll
    for (int ni = 0; ni < 4; ++ni)
      bfv[ni] = *(const s16x8*)&lds[Bs1 + (bRow + ni * 16) * 32 + permK8];
    if (st) STG_A(sg + 1, 1);
    __builtin_amdgcn_s_barrier();
    __builtin_amdgcn_s_setprio(1);
#pragma unroll
    for (int i = 0; i < 4; ++i)
#pragma unroll
      for (int ni = 0; ni < 4; ++ni)
        acc[i][ni] = __builtin_amdgcn_mfma_f32_16x16x32_bf16(af[i], bfv[ni],
                                                             acc[i][ni], 0, 0, 0);
    __builtin_amdgcn_s_setprio(0);
    __builtin_amdgcn_s_barrier();

    // ---- P4: kh1, mi 4-7 (reads A 4, reuses B)
#pragma unroll
    for (int i = 0; i < 4; ++i)
      af[i] = *(const s16x8*)&lds[As1 + (aRow + 64 + i * 16) * 32 + permK8];
    if (st) STG_B(sg + 1, 1);
    asm volatile("s_waitcnt vmcnt(4)" ::: "memory");
    __builtin_amdgcn_s_barrier();
    __builtin_amdgcn_s_setprio(1);
#pragma unroll
    for (int i = 0; i < 4; ++i)
#pragma unroll
      for (int ni = 0; ni < 4; ++ni)
        acc[4 + i][ni] = __builtin_amdgcn_mfma_f32_16x16x32_bf16(
            af[i], bfv[ni], acc[4 + i][ni], 0, 0, 0);
    __builtin_amdgcn_s_setprio(0);
    __builtin_amdgcn_s_barrier();
  }
#undef STG_A
#undef STG_B

  // epilogue: h = m0+wr*128+mi*16+kq*4+j, token col = n0+wc*64+ni*16+lr
#pragma unroll
  for (int mi = 0; mi < 8; ++mi) {
    const int rbase = m0 + wr * 128 + mi * 16 + kq * 4;
    float b4[4];
#pragma unroll
    for (int j = 0; j < 4; ++j) b4[j] = b1[rbase + j];
#pragma unroll
    for (int ni = 0; ni < 4; ++ni) {
      const int col = n0 + wc * 64 + ni * 16 + lr;
      const float v0 = fmaxf(acc[mi][ni][0] + b4[0], 0.f);
      const float v1 = fmaxf(acc[mi][ni][1] + b4[1], 0.f);
      const float v2 = fmaxf(acc[mi][ni][2] + b4[2], 0.f);
      const float v3 = fmaxf(acc[mi][ni][3] + b4[3], 0.f);
      uint2 o;
      o.x = pack_bf16x2(v0, v1);
      o.y = pack_bf16x2(v2, v3);
      *(uint2*)(HT + (size_t)col * 1024 + rbase) = o;
    }
  }
}

// ---- layer-2 MFMA GEMM, 2-phase dbuf (unchanged, proven) -------------------
__global__ __launch_bounds__(256) void gemm2_mfma(
    const ushort* __restrict__ A2, const ushort* __restrict__ HT,
    const float* __restrict__ b2, float* __restrict__ C2,
    ushort* __restrict__ Fb) {
  constexpr int K = 1024;
  __shared__ ushort As[2 * 128 * 32];
  __shared__ ushort Bs[2 * 128 * 32];
  const int tid = threadIdx.x;
  const int l = tid & 63, w = tid >> 6;
  const int bid = blockIdx.x;
  const int newid = (bid & 7) * 32 + (bid >> 3);
  const int m0 = (newid & 1) * 128, n0 = (newid >> 1) * 128;
  const int wr = w >> 1, wc = w & 1;
  const int lr = l & 15, kq = l >> 4;

  f32x4 acc[4][4];
#pragma unroll
  for (int mi = 0; mi < 4; ++mi)
#pragma unroll
    for (int ni = 0; ni < 4; ++ni) acc[mi][ni] = (f32x4){0.f, 0.f, 0.f, 0.f};

  const int rA0 = tid >> 2;
  const int q8 = (tid & 3) * 8;
  ushort* AsW0 = As + (w * 64) * 8;
  ushort* AsW1 = As + (256 + w * 64) * 8;
  ushort* BsW0 = Bs + (w * 64) * 8;
  ushort* BsW1 = Bs + (256 + w * 64) * 8;
  const ushort* Arow0 = A2 + (size_t)(m0 + rA0) * K + q8;
  const ushort* Arow1 = A2 + (size_t)(m0 + rA0 + 64) * K + q8;
  const ushort* Brow0 = HT + (size_t)(n0 + rA0) * K + q8;
  const ushort* Brow1 = HT + (size_t)(n0 + rA0 + 64) * K + q8;

  gload_lds16(Arow0, AsW0);
  gload_lds16(Arow1, AsW1);
  gload_lds16(Brow0, BsW0);
  gload_lds16(Brow1, BsW1);
  __syncthreads();

  int cur = 0;
  for (int k0 = 0; k0 < K; k0 += 32) {
    const int nxt = cur ^ 1;
    if (k0 + 32 < K) {
      gload_lds16(Arow0 + k0 + 32, AsW0 + nxt * 4096);
      gload_lds16(Arow1 + k0 + 32, AsW1 + nxt * 4096);
      gload_lds16(Brow0 + k0 + 32, BsW0 + nxt * 4096);
      gload_lds16(Brow1 + k0 + 32, BsW1 + nxt * 4096);
    }
    const ushort* Ab = As + cur * 4096;
    const ushort* Bb = Bs + cur * 4096;
    s16x8 af[4], bfr[4];
#pragma unroll
    for (int mi = 0; mi < 4; ++mi)
      af[mi] = *(const s16x8*)(Ab + (wr * 64 + mi * 16 + lr) * 32 + kq * 8);
#pragma unroll
    for (int ni = 0; ni < 4; ++ni)
      bfr[ni] = *(const s16x8*)(Bb + (wc * 64 + ni * 16 + lr) * 32 + kq * 8);
#pragma unroll
    for (int mi = 0; mi < 4; ++mi)
#pragma unroll
      for (int ni = 0; ni < 4; ++ni)
        acc[mi][ni] = __builtin_amdgcn_mfma_f32_16x16x32_bf16(
            af[mi], bfr[ni], acc[mi][ni], 0, 0, 0);
    __syncthreads();
    cur = nxt;
  }

#pragma unroll
  for (int mi = 0; mi < 4; ++mi) {
    const int rbase = m0 + wr * 64 + mi * 16 + kq * 4;
    if (rbase < 192) {
      float b4[4];
#pragma unroll
      for (int j = 0; j < 4; ++j) b4[j] = b2[rbase + j];
      if (rbase < 128) {
#pragma unroll
        for (int ni = 0; ni < 4; ++ni) {
          const int col = n0 + wc * 64 + ni * 16 + lr;
#pragma unroll
          for (int j = 0; j < 4; ++j)
            Fb[(size_t)(rbase + j) * BNT + col] =
                f32_to_bf16_rne(acc[mi][ni][j] + b4[j]);
        }
      } else {
#pragma unroll
        for (int ni = 0; ni < 4; ++ni) {
          const int col = n0 + wc * 64 + ni * 16 + lr;
          float* cr = C2 + (size_t)rbase * BNT + col;
#pragma unroll
          for (int j = 0; j < 4; ++j)
            cr[(size_t)j * BNT] = acc[mi][ni][j] + b4[j];
        }
      }
    }
  }
}

// ---------------- Sinkhorn -> P bf16 ----------------------------------------
__global__ __launch_bounds__(256) void sinkhorn_b16(
    const float* __restrict__ S, const float* __restrict__ dustp,
    ushort* __restrict__ Pb) {
  const int b = blockIdx.x, tid = threadIdx.x;
  const int lane = tid & 63, wave = tid >> 6;
  __shared__ float Ms[65][256];
  __shared__ float u[65];
  __shared__ float v[256];
  const float dust = dustp[0];
  for (int idx = tid; idx < 16384; idx += 256) {
    const int m = idx >> 8, n = idx & 255;
    Ms[m][n] = S[m * BNT + b * 256 + n];
  }
  Ms[64][tid] = dust;
  v[tid] = 0.f;
  if (tid < 65) u[tid] = 0.f;
  const float norm = -logf(320.f);
  const float la_dust = norm + logf(192.f);
  __syncthreads();
  for (int it = 0; it < 3; ++it) {
    for (int i = wave; i < 65; i += 4) {
      const float x0 = Ms[i][lane] + v[lane];
      const float x1 = Ms[i][lane + 64] + v[lane + 64];
      const float x2 = Ms[i][lane + 128] + v[lane + 128];
      const float x3 = Ms[i][lane + 192] + v[lane + 192];
      float mm = fmaxf(fmaxf(x0, x1), fmaxf(x2, x3));
#pragma unroll
      for (int off = 32; off; off >>= 1) mm = fmaxf(mm, __shfl_xor(mm, off));
      float s = expf(x0 - mm) + expf(x1 - mm) + expf(x2 - mm) + expf(x3 - mm);
#pragma unroll
      for (int off = 32; off; off >>= 1) s += __shfl_xor(s, off);
      if (lane == 0) u[i] = (i == 64 ? la_dust : norm) - (logf(s) + mm);
    }
    __syncthreads();
    {
      const int n = tid;
      float mm = -1e30f;
      for (int i = 0; i < 65; ++i) mm = fmaxf(mm, Ms[i][n] + u[i]);
      float s = 0.f;
      for (int i = 0; i < 65; ++i) s += expf(Ms[i][n] + u[i] - mm);
      v[n] = norm - (logf(s) + mm);
    }
    __syncthreads();
  }
  for (int idx = tid; idx < 16384; idx += 256) {
    const int m = idx >> 8, n = idx & 255;
    Pb[b * 16384 + idx] =
        f32_to_bf16_rne(expf(Ms[m][n] + u[m] + v[n] - norm));
  }
}

// ---- VLAD via MFMA, direct from global -------------------------------------
__global__ __launch_bounds__(256) void vlad_mfma(const ushort* __restrict__ Fb,
                                                 const ushort* __restrict__ Pb,
                                                 float* __restrict__ VL) {
  const int b = blockIdx.x;
  const int tid = threadIdx.x, l = tid & 63, w = tid >> 6;
  const int lr = l & 15, ko = l >> 4;
  f32x4 acc[2][4];
#pragma unroll
  for (int li = 0; li < 2; ++li)
#pragma unroll
    for (int ni = 0; ni < 4; ++ni) acc[li][ni] = (f32x4){0.f, 0.f, 0.f, 0.f};
  const ushort* Fbase = Fb + b * 256;
  const ushort* Pbase = Pb + b * 16384;
#pragma unroll
  for (int ks = 0; ks < 8; ++ks) {
    const int k = ks * 32 + ko * 8;
    s16x8 bfr[4];
#pragma unroll
    for (int ni = 0; ni < 4; ++ni)
      bfr[ni] = *(const s16x8*)(Pbase + (ni * 16 + lr) * 256 + k);
#pragma unroll
    for (int li = 0; li < 2; ++li) {
      const s16x8 af =
          *(const s16x8*)(Fbase + (size_t)(w * 32 + li * 16 + lr) * BNT + k);
#pragma unroll
      for (int ni = 0; ni < 4; ++ni)
        acc[li][ni] = __builtin_amdgcn_mfma_f32_16x16x32_bf16(
            af, bfr[ni], acc[li][ni], 0, 0, 0);
    }
  }
#pragma unroll
  for (int li = 0; li < 2; ++li)
#pragma unroll
    for (int ni = 0; ni < 4; ++ni)
#pragma unroll
      for (int j = 0; j < 4; ++j) {
        const int ll = w * 32 + li * 16 + ko * 4 + j;
        const int m = ni * 16 + lr;
        VL[b * 8192 + ll * 64 + m] = acc[li][ni][j];
      }
}

// ---------------- finalize ---------------------------------------------------
__global__ __launch_bounds__(256) void finalize_kernel(
    const float* __restrict__ TK, const float* __restrict__ VL,
    float* __restrict__ out) {
  const int b = blockIdx.x, tid = threadIdx.x;
  const int lane = tid & 63, wave = tid >> 6;
  __shared__ float sred[4];
  __shared__ float ssm_part[4][64];
  __shared__ float invm_s[64];
  __shared__ float totals[1];
  const float* vl = &VL[b * 8192];
  float accv = 0.f;
  for (int k = 0; k < 32; ++k) {
    const float xv = vl[tid + 256 * k];
    accv = fmaf(xv, xv, accv);
  }
  ssm_part[wave][lane] = accv;
  const float tv = TK[b * 256 + tid];
  float ss = tv * tv;
#pragma unroll
  for (int off = 32; off; off >>= 1) ss += __shfl_down(ss, off);
  if (lane == 0) sred[wave] = ss;
  __syncthreads();
  const float sstok = sred[0] + sred[1] + sred[2] + sred[3];
  const float invtok = 1.f / fmaxf(sqrtf(sstok), 1e-12f);
  float tpart = 0.f;
  if (wave == 0) {
    const float s4 = ssm_part[0][tid] + ssm_part[1][tid] + ssm_part[2][tid] +
                     ssm_part[3][tid];
    const float inv = 1.f / fmaxf(sqrtf(s4), 1e-12f);
    invm_s[tid] = inv;
    tpart = s4 * inv * inv;
#pragma unroll
    for (int off = 32; off; off >>= 1) tpart += __shfl_down(tpart, off);
    if (lane == 0) totals[0] = tpart;
  }
  __syncthreads();
  const float total = totals[0] + sstok * invtok * invtok;
  const float invT = 1.f / fmaxf(sqrtf(total), 1e-12f);
  float* ob = &out[b * 8448];
  ob[tid] = tv * invtok * invT;
  for (int k = 0; k < 32; ++k) {
    const int idx = tid + 256 * k;
    ob[256 + idx] = vl[idx] * invm_s[idx & 63] * invT;
  }
}

// ================= fp32 fallback path kernels ===============================
template <bool RELU>
__global__ __launch_bounds__(256) void gemm_tt(
    const float* __restrict__ A, const float* __restrict__ Bw,
    const float* __restrict__ bias, float* __restrict__ C, int K, int Nn) {
  __shared__ float As[16][68];
  __shared__ float Bs[16][68];
  const int tid = threadIdx.x;
  const int tx = tid & 15, ty = tid >> 4;
  const int n0 = blockIdx.x * 64;
  const int lrow = tid >> 2, lkq = (tid & 3) << 2;
  float acc[4][4];
#pragma unroll
  for (int r = 0; r < 4; ++r)
#pragma unroll
    for (int c = 0; c < 4; ++c) acc[r][c] = 0.f;
  for (int k0 = 0; k0 < K; k0 += 16) {
    const float4 av = *(const float4*)&A[lrow * K + k0 + lkq];
    const float4 bv = *(const float4*)&Bw[(n0 + lrow) * K + k0 + lkq];
    As[lkq + 0][lrow] = av.x;
    As[lkq + 1][lrow] = av.y;
    As[lkq + 2][lrow] = av.z;
    As[lkq + 3][lrow] = av.w;
    Bs[lkq + 0][lrow] = bv.x;
    Bs[lkq + 1][lrow] = bv.y;
    Bs[lkq + 2][lrow] = bv.z;
    Bs[lkq + 3][lrow] = bv.w;
    __syncthreads();
#pragma unroll
    for (int kk = 0; kk < 16; ++kk) {
      const float4 a4 = *(const float4*)&As[kk][ty << 2];
      const float4 b4 = *(const float4*)&Bs[kk][tx << 2];
      acc[0][0] = fmaf(a4.x, b4.x, acc[0][0]);
      acc[0][1] = fmaf(a4.x, b4.y, acc[0][1]);
      acc[0][2] = fmaf(a4.x, b4.z, acc[0][2]);
      acc[0][3] = fmaf(a4.x, b4.w, acc[0][3]);
      acc[1][0] = fmaf(a4.y, b4.x, acc[1][0]);
      acc[1][1] = fmaf(a4.y, b4.y, acc[1][1]);
      acc[1][2] = fmaf(a4.y, b4.z, acc[1][2]);
      acc[1][3] = fmaf(a4.y, b4.w, acc[1][3]);
      acc[2][0] = fmaf(a4.z, b4.x, acc[2][0]);
      acc[2][1] = fmaf(a4.z, b4.y, acc[2][1]);
      acc[2][2] = fmaf(a4.z, b4.z, acc[2][2]);
      acc[2][3] = fmaf(a4.z, b4.w, acc[2][3]);
      acc[3][0] = fmaf(a4.w, b4.x, acc[3][0]);
      acc[3][1] = fmaf(a4.w, b4.y, acc[3][1]);
      acc[3][2] = fmaf(a4.w, b4.z, acc[3][2]);
      acc[3][3] = fmaf(a4.w, b4.w, acc[3][3]);
    }
    __syncthreads();
  }
#pragma unroll
  for (int r = 0; r < 4; ++r) {
    const int row = (ty << 2) + r;
    float4 o;
    o.x = acc[r][0] + bias[n0 + (tx << 2) + 0];
    o.y = acc[r][1] + bias[n0 + (tx << 2) + 1];
    o.z = acc[r][2] + bias[n0 + (tx << 2) + 2];
    o.w = acc[r][3] + bias[n0 + (tx << 2) + 3];
    if (RELU) {
      o.x = fmaxf(o.x, 0.f);
      o.y = fmaxf(o.y, 0.f);
      o.z = fmaxf(o.z, 0.f);
      o.w = fmaxf(o.w, 0.f);
    }
    *(float4*)&C[row * Nn + n0 + (tx << 2)] = o;
  }
}

template <bool XVIEW, bool RELU>
__global__ __launch_bounds__(256) void gemm_tile(
    const float* __restrict__ A, const float* __restrict__ Bsrc,
    const float* __restrict__ bias, float* __restrict__ Cout, int K) {
  __shared__ float As[16][68];
  __shared__ float Bsh[16][68];
  const int tid = threadIdx.x;
  const int tx = tid & 15, ty = tid >> 4;
  const int rowBase = blockIdx.y * 64;
  const int colBase = blockIdx.x * 64;
  const int bb = colBase >> 8, n0 = colBase & 255;
  const int boff = XVIEW ? (bb * 393216 + n0) : colBase;
  const int la_row = tid >> 2, la_kq = (tid & 3) << 2;
  const int lb_k = tid >> 4, lb_c = (tid & 15) << 2;
  float acc[4][4];
#pragma unroll
  for (int r = 0; r < 4; ++r)
#pragma unroll
    for (int c = 0; c < 4; ++c) acc[r][c] = 0.f;
  for (int k0 = 0; k0 < K; k0 += 16) {
    const float4 av = *(const float4*)&A[(rowBase + la_row) * K + k0 + la_kq];
    float4 bv;
    if (XVIEW)
      bv = *(const float4*)&Bsrc[boff + (k0 + lb_k) * 256 + lb_c];
    else
      bv = *(const float4*)&Bsrc[(k0 + lb_k) * BNT + boff + lb_c];
    As[la_kq + 0][la_row] = av.x;
    As[la_kq + 1][la_row] = av.y;
    As[la_kq + 2][la_row] = av.z;
    As[la_kq + 3][la_row] = av.w;
    *(float4*)&Bsh[lb_k][lb_c] = bv;
    __syncthreads();
#pragma unroll
    for (int kk = 0; kk < 16; ++kk) {
      const float4 a4 = *(const float4*)&As[kk][ty << 2];
      const float4 b4 = *(const float4*)&Bsh[kk][tx << 2];
      acc[0][0] = fmaf(a4.x, b4.x, acc[0][0]);
      acc[0][1] = fmaf(a4.x, b4.y, acc[0][1]);
      acc[0][2] = fmaf(a4.x, b4.z, acc[0][2]);
      acc[0][3] = fmaf(a4.x, b4.w, acc[0][3]);
      acc[1][0] = fmaf(a4.y, b4.x, acc[1][0]);
      acc[1][1] = fmaf(a4.y, b4.y, acc[1][1]);
      acc[1][2] = fmaf(a4.y, b4.z, acc[1][2]);
      acc[1][3] = fmaf(a4.y, b4.w, acc[1][3]);
      acc[2][0] = fmaf(a4.z, b4.x, acc[2][0]);
      acc[2][1] = fmaf(a4.z, b4.y, acc[2][1]);
      acc[2][2] = fmaf(a4.z, b4.z, acc[2][2]);
      acc[2][3] = fmaf(a4.z, b4.w, acc[2][3]);
      acc[3][0] = fmaf(a4.w, b4.x, acc[3][0]);
      acc[3][1] = fmaf(a4.w, b4.y, acc[3][1]);
      acc[3][2] = fmaf(a4.w, b4.z, acc[3][2]);
      acc[3][3] = fmaf(a4.w, b4.w, acc[3][3]);
    }
    __syncthreads();
  }
#pragma unroll
  for (int r = 0; r < 4; ++r) {
    const int row = rowBase + (ty << 2) + r;
    const float bsv = bias[row];
    float4 o;
    o.x = acc[r][0] + bsv;
    o.y = acc[r][1] + bsv;
    o.z = acc[r][2] + bsv;
    o.w = acc[r][3] + bsv;
    if (RELU) {
      o.x = fmaxf(o.x, 0.f);
      o.y = fmaxf(o.y, 0.f);
      o.z = fmaxf(o.z, 0.f);
      o.w = fmaxf(o.w, 0.f);
    }
    *(float4*)&Cout[row * BNT + colBase + (tx << 2)] = o;
  }
}

__global__ __launch_bounds__(256) void sinkhorn_kernel(
    const float* __restrict__ S, const float* __restrict__ dustp,
    float* __restrict__ P) {
  const int b = blockIdx.x, tid = threadIdx.x;
  const int lane = tid & 63, wave = tid >> 6;
  __shared__ float Ms[65][256];
  __shared__ float u[65];
  __shared__ float v[256];
  const float dust = dustp[0];
  for (int idx = tid; idx < 16384; idx += 256) {
    const int m = idx >> 8, n = idx & 255;
    Ms[m][n] = S[m * BNT + b * 256 + n];
  }
  Ms[64][tid] = dust;
  v[tid] = 0.f;
  if (tid < 65) u[tid] = 0.f;
  const float norm = -logf(320.f);
  const float la_dust = norm + logf(192.f);
  __syncthreads();
  for (int it = 0; it < 3; ++it) {
    for (int i = wave; i < 65; i += 4) {
      const float x0 = Ms[i][lane] + v[lane];
      const float x1 = Ms[i][lane + 64] + v[lane + 64];
      const float x2 = Ms[i][lane + 128] + v[lane + 128];
      const float x3 = Ms[i][lane + 192] + v[lane + 192];
      float mm = fmaxf(fmaxf(x0, x1), fmaxf(x2, x3));
#pragma unroll
      for (int off = 32; off; off >>= 1) mm = fmaxf(mm, __shfl_xor(mm, off));
      float s = expf(x0 - mm) + expf(x1 - mm) + expf(x2 - mm) + expf(x3 - mm);
#pragma unroll
      for (int off = 32; off; off >>= 1) s += __shfl_xor(s, off);
      if (lane == 0) u[i] = (i == 64 ? la_dust : norm) - (logf(s) + mm);
    }
    __syncthreads();
    {
      const int n = tid;
      float mm = -1e30f;
      for (int i = 0; i < 65; ++i) mm = fmaxf(mm, Ms[i][n] + u[i]);
      float s = 0.f;
      for (int i = 0; i < 65; ++i) s += expf(Ms[i][n] + u[i] - mm);
      v[n] = norm - (logf(s) + mm);
    }
    __syncthreads();
  }
  for (int idx = tid; idx < 16384; idx += 256) {
    const int m = idx >> 8, n = idx & 255;
    P[b * 16384 + idx] = expf(Ms[m][n] + u[m] + v[n] - norm);
  }
}

__device__ __forceinline__ int ps_idx(int m, int n) {
  return m * 256 + ((((n >> 2) ^ (m & 7)) << 2) | (n & 3));
}
__global__ __launch_bounds__(256) void vlad_kernel(const float* __restrict__ F,
                                                   const float* __restrict__ P,
                                                   float* __restrict__ VL) {
  const int b = blockIdx.x, half = blockIdx.y;
  const int tid = threadIdx.x;
  const int m = tid & 63, lg = tid >> 6;
  __shared__ float ps[64 * 256];
  for (int idx = tid; idx < 16384; idx += 256) {
    const int mm = idx >> 8, n = idx & 255;
    ps[ps_idx(mm, n)] = P[b * 16384 + idx];
  }
  __syncthreads();
  float acc[16];
#pragma unroll
  for (int i = 0; i < 16; ++i) acc[i] = 0.f;
  for (int i = 0; i < 16; ++i) {
    const int ll = half * 64 + lg + 4 * i;
    const float* frow = &F[(size_t)ll * BNT + b * 256];
    float a = 0.f;
#pragma unroll 8
    for (int nq = 0; nq < 64; ++nq) {
      const float4 f4 = *(const float4*)&frow[nq << 2];
      const float4 p4 = *(const float4*)&ps[m * 256 + ((nq ^ (m & 7)) << 2)];
      a = fmaf(f4.x, p4.x, a);
      a = fmaf(f4.y, p4.y, a);
      a = fmaf(f4.z, p4.z, a);
      a = fmaf(f4.w, p4.w, a);
    }
    acc[i] = a;
  }
#pragma unroll
  for (int i = 0; i < 16; ++i) {
    const int ll = half * 64 + lg + 4 * i;
    VL[b * 8192 + ll * 64 + m] = acc[i];
  }
}

extern "C" void kernel_launch(void* const* d_in, const int* in_sizes, int n_in,
                              void* d_out, int out_size, void* d_ws,
                              size_t ws_size, hipStream_t stream) {
  const float* x = (const float*)d_in[0];
  const float* t = (const float*)d_in[1];
  const float* Wt1 = (const float*)d_in[2];
  const float* bt1 = (const float*)d_in[3];
  const float* Wt2 = (const float*)d_in[4];
  const float* bt2 = (const float*)d_in[5];
  const float* Wc1 = (const float*)d_in[6];
  const float* bc1 = (const float*)d_in[7];
  const float* Wc2 = (const float*)d_in[8];
  const float* bc2 = (const float*)d_in[9];
  const float* Ws1 = (const float*)d_in[10];
  const float* bs1 = (const float*)d_in[11];
  const float* Ws2 = (const float*)d_in[12];
  const float* bs2 = (const float*)d_in[13];
  const float* dust = (const float*)d_in[14];
  float* out = (float*)d_out;

  if (ws_size >= 97714176ull) {
    char* base = (char*)d_ws;
    ushort* Tb = (ushort*)base;
    ushort* Wt1b = (ushort*)(base + 196608);
    ushort* Wt2b = (ushort*)(base + 1769472);
    float* Pt = (float*)(base + 2031616);
    ushort* Hb = (ushort*)(base + 2555904);
    ushort* XT = (ushort*)base;
    ushort* Pb = (ushort*)base;
    float* VL = (float*)(base + 4194304);
    ushort* Fb = (ushort*)(base + 8388608);
    ushort* HT = (ushort*)(base + 50331648);
    float* C2 = (float*)(base + 83886080);
    ushort* A1 = (ushort*)(base + 83886080);
    ushort* Wc1b = A1;
    ushort* Ws1b = (ushort*)(base + 85458944);
    ushort* A2 = (ushort*)(base + 96468992);
    float* b2 = (float*)(base + 96993280);
    float* TK = (float*)(base + 96994304);
    float* b1 = (float*)(base + 97059840);
    float* Sb = C2 + (size_t)128 * BNT;

    prep_all<<<2788, 256, 0, stream>>>(t, Wt1, Wt2, Wc1, Ws1, bc1, bs1, Wc2,
                                       Ws2, bc2, bs2, Tb, Wt1b, Wt2b, Wc1b,
                                       Ws1b, b1, A2, b2);
    token1_mfma<<<dim3(8, 4), 256, 0, stream>>>(Tb, Wt1b, Pt);
    token1_reduce<<<64, 256, 0, stream>>>(Pt, bt1, Hb);
    token2_mfma<<<4, 256, 0, stream>>>(Hb, Wt2b, bt2, TK);
    transpose_x_bf16<<<dim3(24, 64), 256, 0, stream>>>(x, XT);
    gemm1_8ph<<<256, 512, 0, stream>>>(A1, XT, b1, HT);
    gemm2_mfma<<<256, 256, 0, stream>>>(A2, HT, b2, C2, Fb);
    sinkhorn_b16<<<64, 256, 0, stream>>>(Sb, dust, Pb);
    vlad_mfma<<<64, 256, 0, stream>>>(Fb, Pb, VL);
    finalize_kernel<<<64, 256, 0, stream>>>(TK, VL, out);
  } else {
    float* ws = (float*)d_ws;
    float* H = ws;
    float* F = H + 512 * BNT;
    float* Sb = F + 128 * BNT;
    float* P = Sb + 64 * BNT;
    float* VL = P + 64 * BNT;
    float* TK = VL + 64 * 8192;
    float* Hh = P;

    gemm_tt<true><<<dim3(8, 1), 256, 0, stream>>>(t, Wt1, bt1, Hh, 1536, 512);
    gemm_tt<false><<<dim3(4, 1), 256, 0, stream>>>(Hh, Wt2, bt2, TK, 512, 256);
    gemm_tile<true, true><<<dim3(256, 8), 256, 0, stream>>>(Wc1, x, bc1, H, 1536);
    gemm_tile<false, false><<<dim3(256, 2), 256, 0, stream>>>(Wc2, H, bc2, F, 512);
    gemm_tile<true, true><<<dim3(256, 8), 256, 0, stream>>>(Ws1, x, bs1, H, 1536);
    gemm_tile<false, false><<<dim3(256, 1), 256, 0, stream>>>(Ws2, H, bs2, Sb, 512);
    sinkhorn_kernel<<<64, 256, 0, stream>>>(Sb, dust, P);
    vlad_kernel<<<dim3(64, 2), 256, 0, stream>>>(F, P, VL);
    finalize_kernel<<<64, 256, 0, stream>>>(TK, VL, out);
  }
}

// Round 10
// 169.232 us; speedup vs baseline: 1.3745x; 1.1300x over previous
//
#include <hip/hip_runtime.h>
#include <math.h>

// SALAD head. B=64, C=1536, N=256, HID=512, L=128, M=64, G=256. BNT = B*N.
#define BNT 16384

using f32x4 = __attribute__((ext_vector_type(4))) float;
using s16x8 = __attribute__((ext_vector_type(8))) short;

__device__ __forceinline__ unsigned short f32_to_bf16_rne(float f) {
  unsigned int u = __float_as_uint(f);
  u += 0x7FFFu + ((u >> 16) & 1u);
  return (unsigned short)(u >> 16);
}
__device__ __forceinline__ unsigned pack_bf16x2(float a, float b) {
  return (unsigned)f32_to_bf16_rne(a) | ((unsigned)f32_to_bf16_rne(b) << 16);
}

__device__ __forceinline__ void gload_lds16(const ushort* g, ushort* lds) {
  __builtin_amdgcn_global_load_lds(
      (const __attribute__((address_space(1))) unsigned int*)g,
      (__attribute__((address_space(3))) unsigned int*)lds, 16, 0, 0);
}

// ---- fused prep: bf16 converts of t,Wt1,Wt2,Wc1,Ws1 + b1 stack + A2 stack --
__global__ __launch_bounds__(256) void prep_all(
    const float* __restrict__ t, const float* __restrict__ Wt1,
    const float* __restrict__ Wt2, const float* __restrict__ Wc1,
    const float* __restrict__ Ws1, const float* __restrict__ bc1,
    const float* __restrict__ bs1, const float* __restrict__ Wc2,
    const float* __restrict__ Ws2, const float* __restrict__ bc2,
    const float* __restrict__ bs2, ushort* __restrict__ Tb,
    ushort* __restrict__ Wt1b, ushort* __restrict__ Wt2b,
    ushort* __restrict__ Wc1b, ushort* __restrict__ Ws1b,
    float* __restrict__ b1, ushort* __restrict__ A2, float* __restrict__ b2) {
  const int bid = blockIdx.x, tid = threadIdx.x;
  const float* src = nullptr;
  ushort* dst = nullptr;
  int i = 0;
  if (bid < 96) {
    src = t; dst = Tb; i = bid * 256 + tid;
  } else if (bid < 864) {
    src = Wt1; dst = Wt1b; i = (bid - 96) * 256 + tid;
  } else if (bid < 992) {
    src = Wt2; dst = Wt2b; i = (bid - 864) * 256 + tid;
  } else if (bid < 1760) {
    src = Wc1; dst = Wc1b; i = (bid - 992) * 256 + tid;
  } else if (bid < 2528) {
    src = Ws1; dst = Ws1b; i = (bid - 1760) * 256 + tid;
  } else if (bid < 2532) {
    const int j = (bid - 2528) * 256 + tid;
    b1[j] = j < 512 ? bc1[j] : bs1[j - 512];
    return;
  } else {
    const int r = bid - 2532;
    const int c = tid * 4;
    float v[4] = {0.f, 0.f, 0.f, 0.f};
    if (r < 128) {
      if (c < 512) {
#pragma unroll
        for (int j = 0; j < 4; ++j) v[j] = Wc2[r * 512 + c + j];
      }
    } else if (r < 192) {
      if (c >= 512) {
#pragma unroll
        for (int j = 0; j < 4; ++j) v[j] = Ws2[(r - 128) * 512 + (c - 512) + j];
      }
    }
    uint2 o;
    o.x = pack_bf16x2(v[0], v[1]);
    o.y = pack_bf16x2(v[2], v[3]);
    *(uint2*)(A2 + r * 1024 + c) = o;
    if (tid == 0) b2[r] = r < 128 ? bc2[r] : (r < 192 ? bs2[r - 128] : 0.f);
    return;
  }
  const float4 v = ((const float4*)src)[i];
  uint2 o;
  o.x = pack_bf16x2(v.x, v.y);
  o.y = pack_bf16x2(v.z, v.w);
  ((uint2*)dst)[i] = o;
}

// ---- token layer 1 (MFMA, no LDS, split-K) ---------------------------------
__global__ __launch_bounds__(256) void token1_mfma(
    const ushort* __restrict__ Tb, const ushort* __restrict__ Wt1b,
    float* __restrict__ Pt) {
  const int ct = blockIdx.x, kc = blockIdx.y;
  const int tid = threadIdx.x, l = tid & 63, wv = tid >> 6;
  const int lr = l & 15, ko = l >> 4;
  const int col = ct * 64 + wv * 16 + lr;
  f32x4 acc[4];
#pragma unroll
  for (int r = 0; r < 4; ++r) acc[r] = (f32x4){0.f, 0.f, 0.f, 0.f};
  const int k0 = kc * 384;
#pragma unroll 4
  for (int ks = 0; ks < 12; ++ks) {
    const int k = k0 + ks * 32 + ko * 8;
    const s16x8 bf = *(const s16x8*)(Wt1b + (size_t)col * 1536 + k);
#pragma unroll
    for (int rf = 0; rf < 4; ++rf) {
      const s16x8 af = *(const s16x8*)(Tb + (size_t)(rf * 16 + lr) * 1536 + k);
      acc[rf] =
          __builtin_amdgcn_mfma_f32_16x16x32_bf16(af, bf, acc[rf], 0, 0, 0);
    }
  }
#pragma unroll
  for (int rf = 0; rf < 4; ++rf)
#pragma unroll
    for (int j = 0; j < 4; ++j) {
      const int row = rf * 16 + ko * 4 + j;
      Pt[((kc * 64 + row) << 9) + col] = acc[rf][j];
    }
}

// ---- token layer-1 reduce --------------------------------------------------
__global__ __launch_bounds__(256) void token1_reduce(
    const float* __restrict__ Pt, const float* __restrict__ bt1,
    ushort* __restrict__ Hb) {
  const int i = blockIdx.x * 256 + threadIdx.x;
  const int row = i >> 8, c2 = (i & 255) * 2;
  float v0 = bt1[c2], v1 = bt1[c2 + 1];
#pragma unroll
  for (int kc = 0; kc < 4; ++kc) {
    v0 += Pt[((kc * 64 + row) << 9) + c2];
    v1 += Pt[((kc * 64 + row) << 9) + c2 + 1];
  }
  v0 = fmaxf(v0, 0.f);
  v1 = fmaxf(v1, 0.f);
  ((unsigned*)Hb)[i] = pack_bf16x2(v0, v1);
}

// ---- token layer 2 (MFMA, no LDS) ------------------------------------------
__global__ __launch_bounds__(256) void token2_mfma(
    const ushort* __restrict__ Hb, const ushort* __restrict__ Wt2b,
    const float* __restrict__ bt2, float* __restrict__ TK) {
  const int ct = blockIdx.x;
  const int tid = threadIdx.x, l = tid & 63, wv = tid >> 6;
  const int lr = l & 15, ko = l >> 4;
  const int col = ct * 64 + wv * 16 + lr;
  f32x4 acc[4];
#pragma unroll
  for (int r = 0; r < 4; ++r) acc[r] = (f32x4){0.f, 0.f, 0.f, 0.f};
#pragma unroll 4
  for (int ks = 0; ks < 16; ++ks) {
    const int k = ks * 32 + ko * 8;
    const s16x8 bf = *(const s16x8*)(Wt2b + (size_t)col * 512 + k);
#pragma unroll
    for (int rf = 0; rf < 4; ++rf) {
      const s16x8 af = *(const s16x8*)(Hb + (size_t)(rf * 16 + lr) * 512 + k);
      acc[rf] =
          __builtin_amdgcn_mfma_f32_16x16x32_bf16(af, bf, acc[rf], 0, 0, 0);
    }
  }
  const float bb = bt2[col];
#pragma unroll
  for (int rf = 0; rf < 4; ++rf)
#pragma unroll
    for (int j = 0; j < 4; ++j)
      TK[(rf * 16 + ko * 4 + j) * 256 + col] = acc[rf][j] + bb;
}

// ------- x [64][1536][256] fp32 -> XT [16384][1536] bf16 (transpose) --------
__global__ __launch_bounds__(256) void transpose_x_bf16(
    const float* __restrict__ x, ushort* __restrict__ XT) {
  __shared__ ushort lds[16384];
  const int cc = blockIdx.x * 64, b = blockIdx.y;
  const int t = threadIdx.x;
  const float* xb = x + b * 393216 + cc * 256;
#pragma unroll
  for (int i = 0; i < 16; ++i) {
    const int c0 = i * 4;
    const float v0 = xb[(c0 + 0) * 256 + t];
    const float v1 = xb[(c0 + 1) * 256 + t];
    const float v2 = xb[(c0 + 2) * 256 + t];
    const float v3 = xb[(c0 + 3) * 256 + t];
    uint2 o;
    o.x = pack_bf16x2(v0, v1);
    o.y = pack_bf16x2(v2, v3);
    const int g = c0 >> 3;
    const int waddr = t * 128 + (((g ^ (t & 7)) << 4) | ((c0 & 7) << 1));
    *(uint2*)((char*)lds + waddr) = o;
  }
  __syncthreads();
#pragma unroll
  for (int r = 0; r < 8; ++r) {
    const int j = r * 32 + (t >> 3), q = t & 7;
    const uint4 o =
        *(const uint4*)((const char*)lds + j * 128 + ((q ^ (j & 7)) << 4));
    *(uint4*)(XT + (size_t)(b * 256 + j) * 1536 + cc + q * 8) = o;
  }
}

// ---- layer-1 GEMM: 256x256, BK=64, 8-phase schedule (T2+T3+T4+T5) ----------
__global__ __launch_bounds__(512) void gemm1_8ph(
    const ushort* __restrict__ A1, const ushort* __restrict__ Bt,
    const float* __restrict__ b1, ushort* __restrict__ HT) {
  __shared__ ushort lds[65536];  // A: [0,32768) 4 slots; B: [32768,65536)
  const int tid = threadIdx.x, l = tid & 63, w = tid >> 6;
  const int bid = blockIdx.x;
  const int newid = (bid & 7) * 32 + (bid >> 3);  // XCD-bijective (256%8==0)
  const int m0 = (newid & 3) * 256, n0 = (newid >> 2) * 256;
  const int wr = w >> 2, wc = w & 3;  // 2x4 wave grid
  const int lr = l & 15, kq = l >> 4;
  const int permK8 = (kq ^ ((lr >> 1) & 3)) * 8;  // ushort offset in row
  const int aRow = wr * 128 + lr;                 // + mi*16
  const int bRow = wc * 64 + lr;                  // + ni*16

  f32x4 acc[8][4];
#pragma unroll
  for (int mi = 0; mi < 8; ++mi)
#pragma unroll
    for (int ni = 0; ni < 4; ++ni) acc[mi][ni] = (f32x4){0.f, 0.f, 0.f, 0.f};

  const int srow = tid >> 2, ssp = tid & 3;
  const int skq = ssp ^ ((srow >> 1) & 3);
  const ushort* sA0 = A1 + (size_t)(m0 + srow) * 1536 + skq * 8;
  const ushort* sA1 = A1 + (size_t)(m0 + srow + 128) * 1536 + skq * 8;
  const ushort* sB0 = Bt + (size_t)(n0 + srow) * 1536 + skq * 8;
  const ushort* sB1 = Bt + (size_t)(n0 + srow + 128) * 1536 + skq * 8;
  const int wofs = w * 512;

#define STG_A(tau, kh)                                              \
  do {                                                              \
    ushort* d = &lds[((((tau)&1) * 2 + (kh)) * 8192) + wofs];       \
    gload_lds16(sA0 + (tau)*64 + (kh)*32, d);                       \
    gload_lds16(sA1 + (tau)*64 + (kh)*32, d + 4096);                \
  } while (0)
#define STG_B(tau, kh)                                              \
  do {                                                              \
    ushort* d = &lds[32768 + ((((tau)&1) * 2 + (kh)) * 8192) + wofs]; \
    gload_lds16(sB0 + (tau)*64 + (kh)*32, d);                       \
    gload_lds16(sB1 + (tau)*64 + (kh)*32, d + 4096);                \
  } while (0)

  STG_A(0, 0);
  STG_B(0, 0);
  STG_A(0, 1);
  STG_B(0, 1);
  asm volatile("s_waitcnt vmcnt(0)" ::: "memory");
  __builtin_amdgcn_s_barrier();

  for (int sg = 0; sg < 24; ++sg) {
    const int rho = sg & 1;
    const int As0 = (rho * 2 + 0) * 8192, As1 = (rho * 2 + 1) * 8192;
    const int Bs0 = 32768 + As0, Bs1 = 32768 + As1;
    const bool st = (sg + 1) < 24;
    s16x8 af[4], bfv[4];

    // ---- P1: kh0, mi 0-3
#pragma unroll
    for (int i = 0; i < 4; ++i)
      af[i] = *(const s16x8*)&lds[As0 + (aRow + i * 16) * 32 + permK8];
#pragma unroll
    for (int ni = 0; ni < 4; ++ni)
      bfv[ni] = *(const s16x8*)&lds[Bs0 + (bRow + ni * 16) * 32 + permK8];
    if (st) STG_A(sg + 1, 0);
    __builtin_amdgcn_s_barrier();
    __builtin_amdgcn_s_setprio(1);
#pragma unroll
    for (int i = 0; i < 4; ++i)
#pragma unroll
      for (int ni = 0; ni < 4; ++ni)
        acc[i][ni] = __builtin_amdgcn_mfma_f32_16x16x32_bf16(af[i], bfv[ni],
                                                             acc[i][ni], 0, 0, 0);
    __builtin_amdgcn_s_setprio(0);
    __builtin_amdgcn_s_barrier();

    // ---- P2: kh0, mi 4-7
#pragma unroll
    for (int i = 0; i < 4; ++i)
      af[i] = *(const s16x8*)&lds[As0 + (aRow + 64 + i * 16) * 32 + permK8];
    if (st) STG_B(sg + 1, 0);
    if (sg < 23)
      asm volatile("s_waitcnt vmcnt(4)" ::: "memory");
    else
      asm volatile("s_waitcnt vmcnt(0)" ::: "memory");
    __builtin_amdgcn_s_barrier();
    __builtin_amdgcn_s_setprio(1);
#pragma unroll
    for (int i = 0; i < 4; ++i)
#pragma unroll
      for (int ni = 0; ni < 4; ++ni)
        acc[4 + i][ni] = __builtin_amdgcn_mfma_f32_16x16x32_bf16(
            af[i], bfv[ni], acc[4 + i][ni], 0, 0, 0);
    __builtin_amdgcn_s_setprio(0);
    __builtin_amdgcn_s_barrier();

    // ---- P3: kh1, mi 0-3
#pragma unroll
    for (int i = 0; i < 4; ++i)
      af[i] = *(const s16x8*)&lds[As1 + (aRow + i * 16) * 32 + permK8];
#pragma unroll
    for (int ni = 0; ni < 4; ++ni)
      bfv[ni] = *(const s16x8*)&lds[Bs1 + (bRow + ni * 16) * 32 + permK8];
    if (st) STG_A(sg + 1, 1);
    __builtin_amdgcn_s_barrier();
    __builtin_amdgcn_s_setprio(1);
#pragma unroll
    for (int i = 0; i < 4; ++i)
#pragma unroll
      for (int ni = 0; ni < 4; ++ni)
        acc[i][ni] = __builtin_amdgcn_mfma_f32_16x16x32_bf16(af[i], bfv[ni],
                                                             acc[i][ni], 0, 0, 0);
    __builtin_amdgcn_s_setprio(0);
    __builtin_amdgcn_s_barrier();

    // ---- P4: kh1, mi 4-7
#pragma unroll
    for (int i = 0; i < 4; ++i)
      af[i] = *(const s16x8*)&lds[As1 + (aRow + 64 + i * 16) * 32 + permK8];
    if (st) STG_B(sg + 1, 1);
    asm volatile("s_waitcnt vmcnt(4)" ::: "memory");
    __builtin_amdgcn_s_barrier();
    __builtin_amdgcn_s_setprio(1);
#pragma unroll
    for (int i = 0; i < 4; ++i)
#pragma unroll
      for (int ni = 0; ni < 4; ++ni)
        acc[4 + i][ni] = __builtin_amdgcn_mfma_f32_16x16x32_bf16(
            af[i], bfv[ni], acc[4 + i][ni], 0, 0, 0);
    __builtin_amdgcn_s_setprio(0);
    __builtin_amdgcn_s_barrier();
  }
#undef STG_A
#undef STG_B

#pragma unroll
  for (int mi = 0; mi < 8; ++mi) {
    const int rbase = m0 + wr * 128 + mi * 16 + kq * 4;
    float b4[4];
#pragma unroll
    for (int j = 0; j < 4; ++j) b4[j] = b1[rbase + j];
#pragma unroll
    for (int ni = 0; ni < 4; ++ni) {
      const int col = n0 + wc * 64 + ni * 16 + lr;
      const float v0 = fmaxf(acc[mi][ni][0] + b4[0], 0.f);
      const float v1 = fmaxf(acc[mi][ni][1] + b4[1], 0.f);
      const float v2 = fmaxf(acc[mi][ni][2] + b4[2], 0.f);
      const float v3 = fmaxf(acc[mi][ni][3] + b4[3], 0.f);
      uint2 o;
      o.x = pack_bf16x2(v0, v1);
      o.y = pack_bf16x2(v2, v3);
      *(uint2*)(HT + (size_t)col * 1024 + rbase) = o;
    }
  }
}

// ---- layer-2 MFMA GEMM, 2-phase dbuf (unchanged, proven) -------------------
__global__ __launch_bounds__(256) void gemm2_mfma(
    const ushort* __restrict__ A2, const ushort* __restrict__ HT,
    const float* __restrict__ b2, float* __restrict__ C2,
    ushort* __restrict__ Fb) {
  constexpr int K = 1024;
  __shared__ ushort As[2 * 128 * 32];
  __shared__ ushort Bs[2 * 128 * 32];
  const int tid = threadIdx.x;
  const int l = tid & 63, w = tid >> 6;
  const int bid = blockIdx.x;
  const int newid = (bid & 7) * 32 + (bid >> 3);
  const int m0 = (newid & 1) * 128, n0 = (newid >> 1) * 128;
  const int wr = w >> 1, wc = w & 1;
  const int lr = l & 15, kq = l >> 4;

  f32x4 acc[4][4];
#pragma unroll
  for (int mi = 0; mi < 4; ++mi)
#pragma unroll
    for (int ni = 0; ni < 4; ++ni) acc[mi][ni] = (f32x4){0.f, 0.f, 0.f, 0.f};

  const int rA0 = tid >> 2;
  const int q8 = (tid & 3) * 8;
  ushort* AsW0 = As + (w * 64) * 8;
  ushort* AsW1 = As + (256 + w * 64) * 8;
  ushort* BsW0 = Bs + (w * 64) * 8;
  ushort* BsW1 = Bs + (256 + w * 64) * 8;
  const ushort* Arow0 = A2 + (size_t)(m0 + rA0) * K + q8;
  const ushort* Arow1 = A2 + (size_t)(m0 + rA0 + 64) * K + q8;
  const ushort* Brow0 = HT + (size_t)(n0 + rA0) * K + q8;
  const ushort* Brow1 = HT + (size_t)(n0 + rA0 + 64) * K + q8;

  gload_lds16(Arow0, AsW0);
  gload_lds16(Arow1, AsW1);
  gload_lds16(Brow0, BsW0);
  gload_lds16(Brow1, BsW1);
  __syncthreads();

  int cur = 0;
  for (int k0 = 0; k0 < K; k0 += 32) {
    const int nxt = cur ^ 1;
    if (k0 + 32 < K) {
      gload_lds16(Arow0 + k0 + 32, AsW0 + nxt * 4096);
      gload_lds16(Arow1 + k0 + 32, AsW1 + nxt * 4096);
      gload_lds16(Brow0 + k0 + 32, BsW0 + nxt * 4096);
      gload_lds16(Brow1 + k0 + 32, BsW1 + nxt * 4096);
    }
    const ushort* Ab = As + cur * 4096;
    const ushort* Bb = Bs + cur * 4096;
    s16x8 af[4], bfr[4];
#pragma unroll
    for (int mi = 0; mi < 4; ++mi)
      af[mi] = *(const s16x8*)(Ab + (wr * 64 + mi * 16 + lr) * 32 + kq * 8);
#pragma unroll
    for (int ni = 0; ni < 4; ++ni)
      bfr[ni] = *(const s16x8*)(Bb + (wc * 64 + ni * 16 + lr) * 32 + kq * 8);
#pragma unroll
    for (int mi = 0; mi < 4; ++mi)
#pragma unroll
      for (int ni = 0; ni < 4; ++ni)
        acc[mi][ni] = __builtin_amdgcn_mfma_f32_16x16x32_bf16(
            af[mi], bfr[ni], acc[mi][ni], 0, 0, 0);
    __syncthreads();
    cur = nxt;
  }

#pragma unroll
  for (int mi = 0; mi < 4; ++mi) {
    const int rbase = m0 + wr * 64 + mi * 16 + kq * 4;
    if (rbase < 192) {
      float b4[4];
#pragma unroll
      for (int j = 0; j < 4; ++j) b4[j] = b2[rbase + j];
      if (rbase < 128) {
#pragma unroll
        for (int ni = 0; ni < 4; ++ni) {
          const int col = n0 + wc * 64 + ni * 16 + lr;
#pragma unroll
          for (int j = 0; j < 4; ++j)
            Fb[(size_t)(rbase + j) * BNT + col] =
                f32_to_bf16_rne(acc[mi][ni][j] + b4[j]);
        }
      } else {
#pragma unroll
        for (int ni = 0; ni < 4; ++ni) {
          const int col = n0 + wc * 64 + ni * 16 + lr;
          float* cr = C2 + (size_t)rbase * BNT + col;
#pragma unroll
          for (int j = 0; j < 4; ++j)
            cr[(size_t)j * BNT] = acc[mi][ni][j] + b4[j];
        }
      }
    }
  }
}

// ---- Sinkhorn, LINEAR domain (mathematically == log-domain ref) ------------
// E=exp(Ms), U=exp(u), V=exp(v):  U[i]=A[i]/sum_n E[i][n]V[n],
// V[n]=B/sum_i E[i][n]U[i], init V=1; P = E*U*V*320.  Removes ~100K exps
// and all max-tracking serial chains per block (latency-bound kernel).
__global__ __launch_bounds__(256) void sinkhorn_lin(
    const float* __restrict__ S, const float* __restrict__ dustp,
    ushort* __restrict__ Pb) {
  const int b = blockIdx.x, tid = threadIdx.x;
  const int lane = tid & 63, wave = tid >> 6;
  __shared__ float E[65][256];
  __shared__ float U[65];
  __shared__ float V[256];
  for (int idx = tid; idx < 16384; idx += 256) {
    const int m = idx >> 8, n = idx & 255;
    E[m][n] = expf(S[m * BNT + b * 256 + n]);
  }
  E[64][tid] = expf(dustp[0]);
  V[tid] = 1.f;
  const float Ai = 1.f / 320.f;
  const float Adust = 192.f / 320.f;
  const float Bn = 1.f / 320.f;
  __syncthreads();
  for (int it = 0; it < 3; ++it) {
    // U[i] = A[i] / sum_n E[i][n]*V[n]
    for (int i = wave; i < 65; i += 4) {
      float s = E[i][lane] * V[lane];
      s = fmaf(E[i][lane + 64], V[lane + 64], s);
      s = fmaf(E[i][lane + 128], V[lane + 128], s);
      s = fmaf(E[i][lane + 192], V[lane + 192], s);
#pragma unroll
      for (int off = 32; off; off >>= 1) s += __shfl_xor(s, off);
      if (lane == 0) U[i] = (i == 64 ? Adust : Ai) / s;
    }
    __syncthreads();
    // V[n] = B / sum_i E[i][n]*U[i]
    {
      const int n = tid;
      float s = 0.f;
#pragma unroll 13
      for (int i = 0; i < 65; ++i) s = fmaf(E[i][n], U[i], s);
      V[n] = Bn / s;
    }
    __syncthreads();
  }
  for (int idx = tid; idx < 16384; idx += 256) {
    const int m = idx >> 8, n = idx & 255;
    Pb[b * 16384 + idx] = f32_to_bf16_rne(E[m][n] * U[m] * V[n] * 320.f);
  }
}

// ---- VLAD via MFMA, direct from global -------------------------------------
__global__ __launch_bounds__(256) void vlad_mfma(const ushort* __restrict__ Fb,
                                                 const ushort* __restrict__ Pb,
                                                 float* __restrict__ VL) {
  const int b = blockIdx.x;
  const int tid = threadIdx.x, l = tid & 63, w = tid >> 6;
  const int lr = l & 15, ko = l >> 4;
  f32x4 acc[2][4];
#pragma unroll
  for (int li = 0; li < 2; ++li)
#pragma unroll
    for (int ni = 0; ni < 4; ++ni) acc[li][ni] = (f32x4){0.f, 0.f, 0.f, 0.f};
  const ushort* Fbase = Fb + b * 256;
  const ushort* Pbase = Pb + b * 16384;
#pragma unroll
  for (int ks = 0; ks < 8; ++ks) {
    const int k = ks * 32 + ko * 8;
    s16x8 bfr[4];
#pragma unroll
    for (int ni = 0; ni < 4; ++ni)
      bfr[ni] = *(const s16x8*)(Pbase + (ni * 16 + lr) * 256 + k);
#pragma unroll
    for (int li = 0; li < 2; ++li) {
      const s16x8 af =
          *(const s16x8*)(Fbase + (size_t)(w * 32 + li * 16 + lr) * BNT + k);
#pragma unroll
      for (int ni = 0; ni < 4; ++ni)
        acc[li][ni] = __builtin_amdgcn_mfma_f32_16x16x32_bf16(
            af, bfr[ni], acc[li][ni], 0, 0, 0);
    }
  }
#pragma unroll
  for (int li = 0; li < 2; ++li)
#pragma unroll
    for (int ni = 0; ni < 4; ++ni)
#pragma unroll
      for (int j = 0; j < 4; ++j) {
        const int ll = w * 32 + li * 16 + ko * 4 + j;
        const int m = ni * 16 + lr;
        VL[b * 8192 + ll * 64 + m] = acc[li][ni][j];
      }
}

// ---------------- finalize ---------------------------------------------------
__global__ __launch_bounds__(256) void finalize_kernel(
    const float* __restrict__ TK, const float* __restrict__ VL,
    float* __restrict__ out) {
  const int b = blockIdx.x, tid = threadIdx.x;
  const int lane = tid & 63, wave = tid >> 6;
  __shared__ float sred[4];
  __shared__ float ssm_part[4][64];
  __shared__ float invm_s[64];
  __shared__ float totals[1];
  const float* vl = &VL[b * 8192];
  float accv = 0.f;
  for (int k = 0; k < 32; ++k) {
    const float xv = vl[tid + 256 * k];
    accv = fmaf(xv, xv, accv);
  }
  ssm_part[wave][lane] = accv;
  const float tv = TK[b * 256 + tid];
  float ss = tv * tv;
#pragma unroll
  for (int off = 32; off; off >>= 1) ss += __shfl_down(ss, off);
  if (lane == 0) sred[wave] = ss;
  __syncthreads();
  const float sstok = sred[0] + sred[1] + sred[2] + sred[3];
  const float invtok = 1.f / fmaxf(sqrtf(sstok), 1e-12f);
  float tpart = 0.f;
  if (wave == 0) {
    const float s4 = ssm_part[0][tid] + ssm_part[1][tid] + ssm_part[2][tid] +
                     ssm_part[3][tid];
    const float inv = 1.f / fmaxf(sqrtf(s4), 1e-12f);
    invm_s[tid] = inv;
    tpart = s4 * inv * inv;
#pragma unroll
    for (int off = 32; off; off >>= 1) tpart += __shfl_down(tpart, off);
    if (lane == 0) totals[0] = tpart;
  }
  __syncthreads();
  const float total = totals[0] + sstok * invtok * invtok;
  const float invT = 1.f / fmaxf(sqrtf(total), 1e-12f);
  float* ob = &out[b * 8448];
  ob[tid] = tv * invtok * invT;
  for (int k = 0; k < 32; ++k) {
    const int idx = tid + 256 * k;
    ob[256 + idx] = vl[idx] * invm_s[idx & 63] * invT;
  }
}

// ================= fp32 fallback path kernels ===============================
template <bool RELU>
__global__ __launch_bounds__(256) void gemm_tt(
    const float* __restrict__ A, const float* __restrict__ Bw,
    const float* __restrict__ bias, float* __restrict__ C, int K, int Nn) {
  __shared__ float As[16][68];
  __shared__ float Bs[16][68];
  const int tid = threadIdx.x;
  const int tx = tid & 15, ty = tid >> 4;
  const int n0 = blockIdx.x * 64;
  const int lrow = tid >> 2, lkq = (tid & 3) << 2;
  float acc[4][4];
#pragma unroll
  for (int r = 0; r < 4; ++r)
#pragma unroll
    for (int c = 0; c < 4; ++c) acc[r][c] = 0.f;
  for (int k0 = 0; k0 < K; k0 += 16) {
    const float4 av = *(const float4*)&A[lrow * K + k0 + lkq];
    const float4 bv = *(const float4*)&Bw[(n0 + lrow) * K + k0 + lkq];
    As[lkq + 0][lrow] = av.x;
    As[lkq + 1][lrow] = av.y;
    As[lkq + 2][lrow] = av.z;
    As[lkq + 3][lrow] = av.w;
    Bs[lkq + 0][lrow] = bv.x;
    Bs[lkq + 1][lrow] = bv.y;
    Bs[lkq + 2][lrow] = bv.z;
    Bs[lkq + 3][lrow] = bv.w;
    __syncthreads();
#pragma unroll
    for (int kk = 0; kk < 16; ++kk) {
      const float4 a4 = *(const float4*)&As[kk][ty << 2];
      const float4 b4 = *(const float4*)&Bs[kk][tx << 2];
      acc[0][0] = fmaf(a4.x, b4.x, acc[0][0]);
      acc[0][1] = fmaf(a4.x, b4.y, acc[0][1]);
      acc[0][2] = fmaf(a4.x, b4.z, acc[0][2]);
      acc[0][3] = fmaf(a4.x, b4.w, acc[0][3]);
      acc[1][0] = fmaf(a4.y, b4.x, acc[1][0]);
      acc[1][1] = fmaf(a4.y, b4.y, acc[1][1]);
      acc[1][2] = fmaf(a4.y, b4.z, acc[1][2]);
      acc[1][3] = fmaf(a4.y, b4.w, acc[1][3]);
      acc[2][0] = fmaf(a4.z, b4.x, acc[2][0]);
      acc[2][1] = fmaf(a4.z, b4.y, acc[2][1]);
      acc[2][2] = fmaf(a4.z, b4.z, acc[2][2]);
      acc[2][3] = fmaf(a4.z, b4.w, acc[2][3]);
      acc[3][0] = fmaf(a4.w, b4.x, acc[3][0]);
      acc[3][1] = fmaf(a4.w, b4.y, acc[3][1]);
      acc[3][2] = fmaf(a4.w, b4.z, acc[3][2]);
      acc[3][3] = fmaf(a4.w, b4.w, acc[3][3]);
    }
    __syncthreads();
  }
#pragma unroll
  for (int r = 0; r < 4; ++r) {
    const int row = (ty << 2) + r;
    float4 o;
    o.x = acc[r][0] + bias[n0 + (tx << 2) + 0];
    o.y = acc[r][1] + bias[n0 + (tx << 2) + 1];
    o.z = acc[r][2] + bias[n0 + (tx << 2) + 2];
    o.w = acc[r][3] + bias[n0 + (tx << 2) + 3];
    if (RELU) {
      o.x = fmaxf(o.x, 0.f);
      o.y = fmaxf(o.y, 0.f);
      o.z = fmaxf(o.z, 0.f);
      o.w = fmaxf(o.w, 0.f);
    }
    *(float4*)&C[row * Nn + n0 + (tx << 2)] = o;
  }
}

template <bool XVIEW, bool RELU>
__global__ __launch_bounds__(256) void gemm_tile(
    const float* __restrict__ A, const float* __restrict__ Bsrc,
    const float* __restrict__ bias, float* __restrict__ Cout, int K) {
  __shared__ float As[16][68];
  __shared__ float Bsh[16][68];
  const int tid = threadIdx.x;
  const int tx = tid & 15, ty = tid >> 4;
  const int rowBase = blockIdx.y * 64;
  const int colBase = blockIdx.x * 64;
  const int bb = colBase >> 8, n0 = colBase & 255;
  const int boff = XVIEW ? (bb * 393216 + n0) : colBase;
  const int la_row = tid >> 2, la_kq = (tid & 3) << 2;
  const int lb_k = tid >> 4, lb_c = (tid & 15) << 2;
  float acc[4][4];
#pragma unroll
  for (int r = 0; r < 4; ++r)
#pragma unroll
    for (int c = 0; c < 4; ++c) acc[r][c] = 0.f;
  for (int k0 = 0; k0 < K; k0 += 16) {
    const float4 av = *(const float4*)&A[(rowBase + la_row) * K + k0 + la_kq];
    float4 bv;
    if (XVIEW)
      bv = *(const float4*)&Bsrc[boff + (k0 + lb_k) * 256 + lb_c];
    else
      bv = *(const float4*)&Bsrc[(k0 + lb_k) * BNT + boff + lb_c];
    As[la_kq + 0][la_row] = av.x;
    As[la_kq + 1][la_row] = av.y;
    As[la_kq + 2][la_row] = av.z;
    As[la_kq + 3][la_row] = av.w;
    *(float4*)&Bsh[lb_k][lb_c] = bv;
    __syncthreads();
#pragma unroll
    for (int kk = 0; kk < 16; ++kk) {
      const float4 a4 = *(const float4*)&As[kk][ty << 2];
      const float4 b4 = *(const float4*)&Bsh[kk][tx << 2];
      acc[0][0] = fmaf(a4.x, b4.x, acc[0][0]);
      acc[0][1] = fmaf(a4.x, b4.y, acc[0][1]);
      acc[0][2] = fmaf(a4.x, b4.z, acc[0][2]);
      acc[0][3] = fmaf(a4.x, b4.w, acc[0][3]);
      acc[1][0] = fmaf(a4.y, b4.x, acc[1][0]);
      acc[1][1] = fmaf(a4.y, b4.y, acc[1][1]);
      acc[1][2] = fmaf(a4.y, b4.z, acc[1][2]);
      acc[1][3] = fmaf(a4.y, b4.w, acc[1][3]);
      acc[2][0] = fmaf(a4.z, b4.x, acc[2][0]);
      acc[2][1] = fmaf(a4.z, b4.y, acc[2][1]);
      acc[2][2] = fmaf(a4.z, b4.z, acc[2][2]);
      acc[2][3] = fmaf(a4.z, b4.w, acc[2][3]);
      acc[3][0] = fmaf(a4.w, b4.x, acc[3][0]);
      acc[3][1] = fmaf(a4.w, b4.y, acc[3][1]);
      acc[3][2] = fmaf(a4.w, b4.z, acc[3][2]);
      acc[3][3] = fmaf(a4.w, b4.w, acc[3][3]);
    }
    __syncthreads();
  }
#pragma unroll
  for (int r = 0; r < 4; ++r) {
    const int row = rowBase + (ty << 2) + r;
    const float bsv = bias[row];
    float4 o;
    o.x = acc[r][0] + bsv;
    o.y = acc[r][1] + bsv;
    o.z = acc[r][2] + bsv;
    o.w = acc[r][3] + bsv;
    if (RELU) {
      o.x = fmaxf(o.x, 0.f);
      o.y = fmaxf(o.y, 0.f);
      o.z = fmaxf(o.z, 0.f);
      o.w = fmaxf(o.w, 0.f);
    }
    *(float4*)&Cout[row * BNT + colBase + (tx << 2)] = o;
  }
}

__global__ __launch_bounds__(256) void sinkhorn_kernel(
    const float* __restrict__ S, const float* __restrict__ dustp,
    float* __restrict__ P) {
  const int b = blockIdx.x, tid = threadIdx.x;
  const int lane = tid & 63, wave = tid >> 6;
  __shared__ float Ms[65][256];
  __shared__ float u[65];
  __shared__ float v[256];
  const float dust = dustp[0];
  for (int idx = tid; idx < 16384; idx += 256) {
    const int m = idx >> 8, n = idx & 255;
    Ms[m][n] = S[m * BNT + b * 256 + n];
  }
  Ms[64][tid] = dust;
  v[tid] = 0.f;
  if (tid < 65) u[tid] = 0.f;
  const float norm = -logf(320.f);
  const float la_dust = norm + logf(192.f);
  __syncthreads();
  for (int it = 0; it < 3; ++it) {
    for (int i = wave; i < 65; i += 4) {
      const float x0 = Ms[i][lane] + v[lane];
      const float x1 = Ms[i][lane + 64] + v[lane + 64];
      const float x2 = Ms[i][lane + 128] + v[lane + 128];
      const float x3 = Ms[i][lane + 192] + v[lane + 192];
      float mm = fmaxf(fmaxf(x0, x1), fmaxf(x2, x3));
#pragma unroll
      for (int off = 32; off; off >>= 1) mm = fmaxf(mm, __shfl_xor(mm, off));
      float s = expf(x0 - mm) + expf(x1 - mm) + expf(x2 - mm) + expf(x3 - mm);
#pragma unroll
      for (int off = 32; off; off >>= 1) s += __shfl_xor(s, off);
      if (lane == 0) u[i] = (i == 64 ? la_dust : norm) - (logf(s) + mm);
    }
    __syncthreads();
    {
      const int n = tid;
      float mm = -1e30f;
      for (int i = 0; i < 65; ++i) mm = fmaxf(mm, Ms[i][n] + u[i]);
      float s = 0.f;
      for (int i = 0; i < 65; ++i) s += expf(Ms[i][n] + u[i] - mm);
      v[n] = norm - (logf(s) + mm);
    }
    __syncthreads();
  }
  for (int idx = tid; idx < 16384; idx += 256) {
    const int m = idx >> 8, n = idx & 255;
    P[b * 16384 + idx] = expf(Ms[m][n] + u[m] + v[n] - norm);
  }
}

__device__ __forceinline__ int ps_idx(int m, int n) {
  return m * 256 + ((((n >> 2) ^ (m & 7)) << 2) | (n & 3));
}
__global__ __launch_bounds__(256) void vlad_kernel(const float* __restrict__ F,
                                                   const float* __restrict__ P,
                                                   float* __restrict__ VL) {
  const int b = blockIdx.x, half = blockIdx.y;
  const int tid = threadIdx.x;
  const int m = tid & 63, lg = tid >> 6;
  __shared__ float ps[64 * 256];
  for (int idx = tid; idx < 16384; idx += 256) {
    const int mm = idx >> 8, n = idx & 255;
    ps[ps_idx(mm, n)] = P[b * 16384 + idx];
  }
  __syncthreads();
  float acc[16];
#pragma unroll
  for (int i = 0; i < 16; ++i) acc[i] = 0.f;
  for (int i = 0; i < 16; ++i) {
    const int ll = half * 64 + lg + 4 * i;
    const float* frow = &F[(size_t)ll * BNT + b * 256];
    float a = 0.f;
#pragma unroll 8
    for (int nq = 0; nq < 64; ++nq) {
      const float4 f4 = *(const float4*)&frow[nq << 2];
      const float4 p4 = *(const float4*)&ps[m * 256 + ((nq ^ (m & 7)) << 2)];
      a = fmaf(f4.x, p4.x, a);
      a = fmaf(f4.y, p4.y, a);
      a = fmaf(f4.z, p4.z, a);
      a = fmaf(f4.w, p4.w, a);
    }
    acc[i] = a;
  }
#pragma unroll
  for (int i = 0; i < 16; ++i) {
    const int ll = half * 64 + lg + 4 * i;
    VL[b * 8192 + ll * 64 + m] = acc[i];
  }
}

extern "C" void kernel_launch(void* const* d_in, const int* in_sizes, int n_in,
                              void* d_out, int out_size, void* d_ws,
                              size_t ws_size, hipStream_t stream) {
  const float* x = (const float*)d_in[0];
  const float* t = (const float*)d_in[1];
  const float* Wt1 = (const float*)d_in[2];
  const float* bt1 = (const float*)d_in[3];
  const float* Wt2 = (const float*)d_in[4];
  const float* bt2 = (const float*)d_in[5];
  const float* Wc1 = (const float*)d_in[6];
  const float* bc1 = (const float*)d_in[7];
  const float* Wc2 = (const float*)d_in[8];
  const float* bc2 = (const float*)d_in[9];
  const float* Ws1 = (const float*)d_in[10];
  const float* bs1 = (const float*)d_in[11];
  const float* Ws2 = (const float*)d_in[12];
  const float* bs2 = (const float*)d_in[13];
  const float* dust = (const float*)d_in[14];
  float* out = (float*)d_out;

  if (ws_size >= 97714176ull) {
    char* base = (char*)d_ws;
    ushort* Tb = (ushort*)base;
    ushort* Wt1b = (ushort*)(base + 196608);
    ushort* Wt2b = (ushort*)(base + 1769472);
    float* Pt = (float*)(base + 2031616);
    ushort* Hb = (ushort*)(base + 2555904);
    ushort* XT = (ushort*)base;
    ushort* Pb = (ushort*)base;
    float* VL = (float*)(base + 4194304);
    ushort* Fb = (ushort*)(base + 8388608);
    ushort* HT = (ushort*)(base + 50331648);
    float* C2 = (float*)(base + 83886080);
    ushort* A1 = (ushort*)(base + 83886080);
    ushort* Wc1b = A1;
    ushort* Ws1b = (ushort*)(base + 85458944);
    ushort* A2 = (ushort*)(base + 96468992);
    float* b2 = (float*)(base + 96993280);
    float* TK = (float*)(base + 96994304);
    float* b1 = (float*)(base + 97059840);
    float* Sb = C2 + (size_t)128 * BNT;

    prep_all<<<2788, 256, 0, stream>>>(t, Wt1, Wt2, Wc1, Ws1, bc1, bs1, Wc2,
                                       Ws2, bc2, bs2, Tb, Wt1b, Wt2b, Wc1b,
                                       Ws1b, b1, A2, b2);
    token1_mfma<<<dim3(8, 4), 256, 0, stream>>>(Tb, Wt1b, Pt);
    token1_reduce<<<64, 256, 0, stream>>>(Pt, bt1, Hb);
    token2_mfma<<<4, 256, 0, stream>>>(Hb, Wt2b, bt2, TK);
    transpose_x_bf16<<<dim3(24, 64), 256, 0, stream>>>(x, XT);
    gemm1_8ph<<<256, 512, 0, stream>>>(A1, XT, b1, HT);
    gemm2_mfma<<<256, 256, 0, stream>>>(A2, HT, b2, C2, Fb);
    sinkhorn_lin<<<64, 256, 0, stream>>>(Sb, dust, Pb);
    vlad_mfma<<<64, 256, 0, stream>>>(Fb, Pb, VL);
    finalize_kernel<<<64, 256, 0, stream>>>(TK, VL, out);
  } else {
    float* ws = (float*)d_ws;
    float* H = ws;
    float* F = H + 512 * BNT;
    float* Sb = F + 128 * BNT;
    float* P = Sb + 64 * BNT;
    float* VL = P + 64 * BNT;
    float* TK = VL + 64 * 8192;
    float* Hh = P;

    gemm_tt<true><<<dim3(8, 1), 256, 0, stream>>>(t, Wt1, bt1, Hh, 1536, 512);
    gemm_tt<false><<<dim3(4, 1), 256, 0, stream>>>(Hh, Wt2, bt2, TK, 512, 256);
    gemm_tile<true, true><<<dim3(256, 8), 256, 0, stream>>>(Wc1, x, bc1, H, 1536);
    gemm_tile<false, false><<<dim3(256, 2), 256, 0, stream>>>(Wc2, H, bc2, F, 512);
    gemm_tile<true, true><<<dim3(256, 8), 256, 0, stream>>>(Ws1, x, bs1, H, 1536);
    gemm_tile<false, false><<<dim3(256, 1), 256, 0, stream>>>(Ws2, H, bs2, Sb, 512);
    sinkhorn_kernel<<<64, 256, 0, stream>>>(Sb, dust, P);
    vlad_kernel<<<dim3(64, 2), 256, 0, stream>>>(F, P, VL);
    finalize_kernel<<<64, 256, 0, stream>>>(TK, VL, out);
  }
}

// Round 11
// 166.129 us; speedup vs baseline: 1.4002x; 1.0187x over previous
//
#include <hip/hip_runtime.h>
#include <math.h>

// SALAD head. B=64, C=1536, N=256, HID=512, L=128, M=64, G=256. BNT = B*N.
#define BNT 16384

using f32x4 = __attribute__((ext_vector_type(4))) float;
using s16x8 = __attribute__((ext_vector_type(8))) short;

__device__ __forceinline__ unsigned short f32_to_bf16_rne(float f) {
  unsigned int u = __float_as_uint(f);
  u += 0x7FFFu + ((u >> 16) & 1u);
  return (unsigned short)(u >> 16);
}
__device__ __forceinline__ unsigned pack_bf16x2(float a, float b) {
  return (unsigned)f32_to_bf16_rne(a) | ((unsigned)f32_to_bf16_rne(b) << 16);
}

__device__ __forceinline__ void gload_lds16(const ushort* g, ushort* lds) {
  __builtin_amdgcn_global_load_lds(
      (const __attribute__((address_space(1))) unsigned int*)g,
      (__attribute__((address_space(3))) unsigned int*)lds, 16, 0, 0);
}

// ---- fused prep: bf16 converts of t,Wt1,Wt2,Wc1,Ws1 + b1 stack + A2 stack --
__global__ __launch_bounds__(256) void prep_all(
    const float* __restrict__ t, const float* __restrict__ Wt1,
    const float* __restrict__ Wt2, const float* __restrict__ Wc1,
    const float* __restrict__ Ws1, const float* __restrict__ bc1,
    const float* __restrict__ bs1, const float* __restrict__ Wc2,
    const float* __restrict__ Ws2, const float* __restrict__ bc2,
    const float* __restrict__ bs2, ushort* __restrict__ Tb,
    ushort* __restrict__ Wt1b, ushort* __restrict__ Wt2b,
    ushort* __restrict__ Wc1b, ushort* __restrict__ Ws1b,
    float* __restrict__ b1, ushort* __restrict__ A2, float* __restrict__ b2) {
  const int bid = blockIdx.x, tid = threadIdx.x;
  const float* src = nullptr;
  ushort* dst = nullptr;
  int i = 0;
  if (bid < 96) {
    src = t; dst = Tb; i = bid * 256 + tid;
  } else if (bid < 864) {
    src = Wt1; dst = Wt1b; i = (bid - 96) * 256 + tid;
  } else if (bid < 992) {
    src = Wt2; dst = Wt2b; i = (bid - 864) * 256 + tid;
  } else if (bid < 1760) {
    src = Wc1; dst = Wc1b; i = (bid - 992) * 256 + tid;
  } else if (bid < 2528) {
    src = Ws1; dst = Ws1b; i = (bid - 1760) * 256 + tid;
  } else if (bid < 2532) {
    const int j = (bid - 2528) * 256 + tid;
    b1[j] = j < 512 ? bc1[j] : bs1[j - 512];
    return;
  } else {
    const int r = bid - 2532;
    const int c = tid * 4;
    float v[4] = {0.f, 0.f, 0.f, 0.f};
    if (r < 128) {
      if (c < 512) {
#pragma unroll
        for (int j = 0; j < 4; ++j) v[j] = Wc2[r * 512 + c + j];
      }
    } else if (r < 192) {
      if (c >= 512) {
#pragma unroll
        for (int j = 0; j < 4; ++j) v[j] = Ws2[(r - 128) * 512 + (c - 512) + j];
      }
    }
    uint2 o;
    o.x = pack_bf16x2(v[0], v[1]);
    o.y = pack_bf16x2(v[2], v[3]);
    *(uint2*)(A2 + r * 1024 + c) = o;
    if (tid == 0) b2[r] = r < 128 ? bc2[r] : (r < 192 ? bs2[r - 128] : 0.f);
    return;
  }
  const float4 v = ((const float4*)src)[i];
  uint2 o;
  o.x = pack_bf16x2(v.x, v.y);
  o.y = pack_bf16x2(v.z, v.w);
  ((uint2*)dst)[i] = o;
}

// ---- token layer 1 (MFMA, no LDS, split-K) ---------------------------------
__global__ __launch_bounds__(256) void token1_mfma(
    const ushort* __restrict__ Tb, const ushort* __restrict__ Wt1b,
    float* __restrict__ Pt) {
  const int ct = blockIdx.x, kc = blockIdx.y;
  const int tid = threadIdx.x, l = tid & 63, wv = tid >> 6;
  const int lr = l & 15, ko = l >> 4;
  const int col = ct * 64 + wv * 16 + lr;
  f32x4 acc[4];
#pragma unroll
  for (int r = 0; r < 4; ++r) acc[r] = (f32x4){0.f, 0.f, 0.f, 0.f};
  const int k0 = kc * 384;
#pragma unroll 4
  for (int ks = 0; ks < 12; ++ks) {
    const int k = k0 + ks * 32 + ko * 8;
    const s16x8 bf = *(const s16x8*)(Wt1b + (size_t)col * 1536 + k);
#pragma unroll
    for (int rf = 0; rf < 4; ++rf) {
      const s16x8 af = *(const s16x8*)(Tb + (size_t)(rf * 16 + lr) * 1536 + k);
      acc[rf] =
          __builtin_amdgcn_mfma_f32_16x16x32_bf16(af, bf, acc[rf], 0, 0, 0);
    }
  }
#pragma unroll
  for (int rf = 0; rf < 4; ++rf)
#pragma unroll
    for (int j = 0; j < 4; ++j) {
      const int row = rf * 16 + ko * 4 + j;
      Pt[((kc * 64 + row) << 9) + col] = acc[rf][j];
    }
}

// ---- token layer-1 reduce --------------------------------------------------
__global__ __launch_bounds__(256) void token1_reduce(
    const float* __restrict__ Pt, const float* __restrict__ bt1,
    ushort* __restrict__ Hb) {
  const int i = blockIdx.x * 256 + threadIdx.x;
  const int row = i >> 8, c2 = (i & 255) * 2;
  float v0 = bt1[c2], v1 = bt1[c2 + 1];
#pragma unroll
  for (int kc = 0; kc < 4; ++kc) {
    v0 += Pt[((kc * 64 + row) << 9) + c2];
    v1 += Pt[((kc * 64 + row) << 9) + c2 + 1];
  }
  v0 = fmaxf(v0, 0.f);
  v1 = fmaxf(v1, 0.f);
  ((unsigned*)Hb)[i] = pack_bf16x2(v0, v1);
}

// ---- token layer 2 (MFMA, no LDS) ------------------------------------------
__global__ __launch_bounds__(256) void token2_mfma(
    const ushort* __restrict__ Hb, const ushort* __restrict__ Wt2b,
    const float* __restrict__ bt2, float* __restrict__ TK) {
  const int ct = blockIdx.x;
  const int tid = threadIdx.x, l = tid & 63, wv = tid >> 6;
  const int lr = l & 15, ko = l >> 4;
  const int col = ct * 64 + wv * 16 + lr;
  f32x4 acc[4];
#pragma unroll
  for (int r = 0; r < 4; ++r) acc[r] = (f32x4){0.f, 0.f, 0.f, 0.f};
#pragma unroll 4
  for (int ks = 0; ks < 16; ++ks) {
    const int k = ks * 32 + ko * 8;
    const s16x8 bf = *(const s16x8*)(Wt2b + (size_t)col * 512 + k);
#pragma unroll
    for (int rf = 0; rf < 4; ++rf) {
      const s16x8 af = *(const s16x8*)(Hb + (size_t)(rf * 16 + lr) * 512 + k);
      acc[rf] =
          __builtin_amdgcn_mfma_f32_16x16x32_bf16(af, bf, acc[rf], 0, 0, 0);
    }
  }
  const float bb = bt2[col];
#pragma unroll
  for (int rf = 0; rf < 4; ++rf)
#pragma unroll
    for (int j = 0; j < 4; ++j)
      TK[(rf * 16 + ko * 4 + j) * 256 + col] = acc[rf][j] + bb;
}

// ------- x [64][1536][256] fp32 -> XT [16384][1536] bf16 (transpose) --------
__global__ __launch_bounds__(256) void transpose_x_bf16(
    const float* __restrict__ x, ushort* __restrict__ XT) {
  __shared__ ushort lds[16384];
  const int cc = blockIdx.x * 64, b = blockIdx.y;
  const int t = threadIdx.x;
  const float* xb = x + b * 393216 + cc * 256;
#pragma unroll
  for (int i = 0; i < 16; ++i) {
    const int c0 = i * 4;
    const float v0 = xb[(c0 + 0) * 256 + t];
    const float v1 = xb[(c0 + 1) * 256 + t];
    const float v2 = xb[(c0 + 2) * 256 + t];
    const float v3 = xb[(c0 + 3) * 256 + t];
    uint2 o;
    o.x = pack_bf16x2(v0, v1);
    o.y = pack_bf16x2(v2, v3);
    const int g = c0 >> 3;
    const int waddr = t * 128 + (((g ^ (t & 7)) << 4) | ((c0 & 7) << 1));
    *(uint2*)((char*)lds + waddr) = o;
  }
  __syncthreads();
#pragma unroll
  for (int r = 0; r < 8; ++r) {
    const int j = r * 32 + (t >> 3), q = t & 7;
    const uint4 o =
        *(const uint4*)((const char*)lds + j * 128 + ((q ^ (j & 7)) << 4));
    *(uint4*)(XT + (size_t)(b * 256 + j) * 1536 + cc + q * 8) = o;
  }
}

// ---- layer-1 GEMM: 256x256, BK=64, loose-window schedule -------------------
// Same tile/LDS/swizzle as the 8-phase version, but ONE barrier + ONE
// vmcnt(0) per K-tile window (hazard audit: in-window reads hit parity p,
// stages write parity ~p — disjoint; LDS->MFMA hazards are per-wave lgkm,
// compiler-managed). Waves free-run within a window so one wave's ds_reads
// overlap another's MFMAs (m114 mechanism). setprio dropped (m190: null-to-
// negative without lockstep phases).
__global__ __launch_bounds__(512) void gemm1_win(
    const ushort* __restrict__ A1, const ushort* __restrict__ Bt,
    const float* __restrict__ b1, ushort* __restrict__ HT) {
  __shared__ ushort lds[65536];  // A: [0,32768) 4 slots; B: [32768,65536)
  const int tid = threadIdx.x, l = tid & 63, w = tid >> 6;
  const int bid = blockIdx.x;
  const int newid = (bid & 7) * 32 + (bid >> 3);  // XCD-bijective (256%8==0)
  const int m0 = (newid & 3) * 256, n0 = (newid >> 2) * 256;
  const int wr = w >> 2, wc = w & 3;  // 2x4 wave grid
  const int lr = l & 15, kq = l >> 4;
  const int permK8 = (kq ^ ((lr >> 1) & 3)) * 8;  // ushort offset in row
  const int aRow = wr * 128 + lr;                 // + mi*16
  const int bRow = wc * 64 + lr;                  // + ni*16

  f32x4 acc[8][4];
#pragma unroll
  for (int mi = 0; mi < 8; ++mi)
#pragma unroll
    for (int ni = 0; ni < 4; ++ni) acc[mi][ni] = (f32x4){0.f, 0.f, 0.f, 0.f};

  const int srow = tid >> 2, ssp = tid & 3;
  const int skq = ssp ^ ((srow >> 1) & 3);
  const ushort* sA0 = A1 + (size_t)(m0 + srow) * 1536 + skq * 8;
  const ushort* sA1 = A1 + (size_t)(m0 + srow + 128) * 1536 + skq * 8;
  const ushort* sB0 = Bt + (size_t)(n0 + srow) * 1536 + skq * 8;
  const ushort* sB1 = Bt + (size_t)(n0 + srow + 128) * 1536 + skq * 8;
  const int wofs = w * 512;

#define STG_A(tau, kh)                                              \
  do {                                                              \
    ushort* d = &lds[((((tau)&1) * 2 + (kh)) * 8192) + wofs];       \
    gload_lds16(sA0 + (tau)*64 + (kh)*32, d);                       \
    gload_lds16(sA1 + (tau)*64 + (kh)*32, d + 4096);                \
  } while (0)
#define STG_B(tau, kh)                                              \
  do {                                                              \
    ushort* d = &lds[32768 + ((((tau)&1) * 2 + (kh)) * 8192) + wofs]; \
    gload_lds16(sB0 + (tau)*64 + (kh)*32, d);                       \
    gload_lds16(sB1 + (tau)*64 + (kh)*32, d + 4096);                \
  } while (0)

  // prologue: K-tile 0 fully staged
  STG_A(0, 0);
  STG_B(0, 0);
  STG_A(0, 1);
  STG_B(0, 1);
  asm volatile("s_waitcnt vmcnt(0)" ::: "memory");
  __builtin_amdgcn_s_barrier();

  for (int sg = 0; sg < 24; ++sg) {
    const int rho = sg & 1;
    const int As0 = (rho * 2 + 0) * 8192, As1 = (rho * 2 + 1) * 8192;
    const int Bs0 = 32768 + As0, Bs1 = 32768 + As1;
    const bool st = (sg + 1) < 24;
    s16x8 af[4], bfv[4];

    // ---- quarter 1: kh0, mi 0-3 (+ stage A half0 of next tile)
#pragma unroll
    for (int i = 0; i < 4; ++i)
      af[i] = *(const s16x8*)&lds[As0 + (aRow + i * 16) * 32 + permK8];
#pragma unroll
    for (int ni = 0; ni < 4; ++ni)
      bfv[ni] = *(const s16x8*)&lds[Bs0 + (bRow + ni * 16) * 32 + permK8];
    if (st) STG_A(sg + 1, 0);
#pragma unroll
    for (int i = 0; i < 4; ++i)
#pragma unroll
      for (int ni = 0; ni < 4; ++ni)
        acc[i][ni] = __builtin_amdgcn_mfma_f32_16x16x32_bf16(af[i], bfv[ni],
                                                             acc[i][ni], 0, 0, 0);

    // ---- quarter 2: kh0, mi 4-7 (+ stage B half0)
#pragma unroll
    for (int i = 0; i < 4; ++i)
      af[i] = *(const s16x8*)&lds[As0 + (aRow + 64 + i * 16) * 32 + permK8];
    if (st) STG_B(sg + 1, 0);
#pragma unroll
    for (int i = 0; i < 4; ++i)
#pragma unroll
      for (int ni = 0; ni < 4; ++ni)
        acc[4 + i][ni] = __builtin_amdgcn_mfma_f32_16x16x32_bf16(
            af[i], bfv[ni], acc[4 + i][ni], 0, 0, 0);

    // ---- quarter 3: kh1, mi 0-3 (+ stage A half1)
#pragma unroll
    for (int i = 0; i < 4; ++i)
      af[i] = *(const s16x8*)&lds[As1 + (aRow + i * 16) * 32 + permK8];
#pragma unroll
    for (int ni = 0; ni < 4; ++ni)
      bfv[ni] = *(const s16x8*)&lds[Bs1 + (bRow + ni * 16) * 32 + permK8];
    if (st) STG_A(sg + 1, 1);
#pragma unroll
    for (int i = 0; i < 4; ++i)
#pragma unroll
      for (int ni = 0; ni < 4; ++ni)
        acc[i][ni] = __builtin_amdgcn_mfma_f32_16x16x32_bf16(af[i], bfv[ni],
                                                             acc[i][ni], 0, 0, 0);

    // ---- quarter 4: kh1, mi 4-7 (+ stage B half1)
#pragma unroll
    for (int i = 0; i < 4; ++i)
      af[i] = *(const s16x8*)&lds[As1 + (aRow + 64 + i * 16) * 32 + permK8];
    if (st) STG_B(sg + 1, 1);
#pragma unroll
    for (int i = 0; i < 4; ++i)
#pragma unroll
      for (int ni = 0; ni < 4; ++ni)
        acc[4 + i][ni] = __builtin_amdgcn_mfma_f32_16x16x32_bf16(
            af[i], bfv[ni], acc[4 + i][ni], 0, 0, 0);

    // ---- window boundary: own-wave drain of next-tile stages, then barrier
    if (st) asm volatile("s_waitcnt vmcnt(0)" ::: "memory");
    __builtin_amdgcn_s_barrier();
  }
#undef STG_A
#undef STG_B

  // epilogue: h = m0+wr*128+mi*16+kq*4+j, token col = n0+wc*64+ni*16+lr
#pragma unroll
  for (int mi = 0; mi < 8; ++mi) {
    const int rbase = m0 + wr * 128 + mi * 16 + kq * 4;
    float b4[4];
#pragma unroll
    for (int j = 0; j < 4; ++j) b4[j] = b1[rbase + j];
#pragma unroll
    for (int ni = 0; ni < 4; ++ni) {
      const int col = n0 + wc * 64 + ni * 16 + lr;
      const float v0 = fmaxf(acc[mi][ni][0] + b4[0], 0.f);
      const float v1 = fmaxf(acc[mi][ni][1] + b4[1], 0.f);
      const float v2 = fmaxf(acc[mi][ni][2] + b4[2], 0.f);
      const float v3 = fmaxf(acc[mi][ni][3] + b4[3], 0.f);
      uint2 o;
      o.x = pack_bf16x2(v0, v1);
      o.y = pack_bf16x2(v2, v3);
      *(uint2*)(HT + (size_t)col * 1024 + rbase) = o;
    }
  }
}

// ---- layer-2 MFMA GEMM, 2-phase dbuf, BM=96 (balanced m-tiles 0..95/96..191)
__global__ __launch_bounds__(256) void gemm2_mfma96(
    const ushort* __restrict__ A2, const ushort* __restrict__ HT,
    const float* __restrict__ b2, float* __restrict__ C2,
    ushort* __restrict__ Fb) {
  constexpr int K = 1024;
  __shared__ ushort As[2 * 3072];  // 96 rows x 32 k, 2 bufs
  __shared__ ushort Bs[2 * 4096];  // 128 rows x 32 k, 2 bufs
  const int tid = threadIdx.x;
  const int l = tid & 63, w = tid >> 6;
  const int bid = blockIdx.x;
  const int newid = (bid & 7) * 32 + (bid >> 3);
  const int m0 = (newid & 1) * 96, n0 = (newid >> 1) * 128;
  const int wr = w >> 1, wc = w & 1;
  const int lr = l & 15, kq = l >> 4;

  f32x4 acc[3][4];
#pragma unroll
  for (int mi = 0; mi < 3; ++mi)
#pragma unroll
    for (int ni = 0; ni < 4; ++ni) acc[mi][ni] = (f32x4){0.f, 0.f, 0.f, 0.f};

  // staging: granule g -> row g>>2, k-oct g&3. A: 384 granules (96 rows);
  // thread t stages gA=t (rows 0..63) and, if t<128, gA=t+256 (rows 64..95).
  // B: 512 granules; thread stages gB=t and gB=t+256.
  const int srow = tid >> 2;
  const int q8 = (tid & 3) * 8;
  const bool secondA = tid < 128;  // waves 0,1 (wave-uniform)
  const ushort* sA0 = A2 + (size_t)(m0 + srow) * K + q8;
  const ushort* sA1 = A2 + (size_t)(m0 + srow + 64) * K + q8;
  const ushort* sB0 = HT + (size_t)(n0 + srow) * K + q8;
  const ushort* sB1 = HT + (size_t)(n0 + srow + 64) * K + q8;
  const int wofs = w * 512;  // wave-linear granule window (ushorts)

#define STAGE2(k0v, buf)                                            \
  do {                                                              \
    gload_lds16(sA0 + (k0v), As + (buf)*3072 + wofs);               \
    if (secondA) gload_lds16(sA1 + (k0v), As + (buf)*3072 + 2048 + wofs); \
    gload_lds16(sB0 + (k0v), Bs + (buf)*4096 + wofs);               \
    gload_lds16(sB1 + (k0v), Bs + (buf)*4096 + 2048 + wofs);        \
  } while (0)

  STAGE2(0, 0);
  __syncthreads();

  int cur = 0;
  for (int k0 = 0; k0 < K; k0 += 32) {
    const int nxt = cur ^ 1;
    if (k0 + 32 < K) STAGE2(k0 + 32, nxt);
    const ushort* Ab = As + cur * 3072;
    const ushort* Bb = Bs + cur * 4096;
    s16x8 af[3], bfr[4];
#pragma unroll
    for (int mi = 0; mi < 3; ++mi)
      af[mi] = *(const s16x8*)(Ab + (wr * 48 + mi * 16 + lr) * 32 + kq * 8);
#pragma unroll
    for (int ni = 0; ni < 4; ++ni)
      bfr[ni] = *(const s16x8*)(Bb + (wc * 64 + ni * 16 + lr) * 32 + kq * 8);
#pragma unroll
    for (int mi = 0; mi < 3; ++mi)
#pragma unroll
      for (int ni = 0; ni < 4; ++ni)
        acc[mi][ni] = __builtin_amdgcn_mfma_f32_16x16x32_bf16(
            af[mi], bfr[ni], acc[mi][ni], 0, 0, 0);
    __syncthreads();
    cur = nxt;
  }
#undef STAGE2

#pragma unroll
  for (int mi = 0; mi < 3; ++mi) {
    const int rbase = m0 + wr * 48 + mi * 16 + kq * 4;  // < 192 always
    float b4[4];
#pragma unroll
    for (int j = 0; j < 4; ++j) b4[j] = b2[rbase + j];
    if (rbase < 128) {
#pragma unroll
      for (int ni = 0; ni < 4; ++ni) {
        const int col = n0 + wc * 64 + ni * 16 + lr;
#pragma unroll
        for (int j = 0; j < 4; ++j)
          Fb[(size_t)(rbase + j) * BNT + col] =
              f32_to_bf16_rne(acc[mi][ni][j] + b4[j]);
      }
    } else {
#pragma unroll
      for (int ni = 0; ni < 4; ++ni) {
        const int col = n0 + wc * 64 + ni * 16 + lr;
        float* cr = C2 + (size_t)rbase * BNT + col;
#pragma unroll
        for (int j = 0; j < 4; ++j) cr[(size_t)j * BNT] = acc[mi][ni][j] + b4[j];
      }
    }
  }
}

// ---- Sinkhorn, LINEAR domain (mathematically == log-domain ref) ------------
__global__ __launch_bounds__(256) void sinkhorn_lin(
    const float* __restrict__ S, const float* __restrict__ dustp,
    ushort* __restrict__ Pb) {
  const int b = blockIdx.x, tid = threadIdx.x;
  const int lane = tid & 63, wave = tid >> 6;
  __shared__ float E[65][256];
  __shared__ float U[65];
  __shared__ float V[256];
  for (int idx = tid; idx < 16384; idx += 256) {
    const int m = idx >> 8, n = idx & 255;
    E[m][n] = expf(S[m * BNT + b * 256 + n]);
  }
  E[64][tid] = expf(dustp[0]);
  V[tid] = 1.f;
  const float Ai = 1.f / 320.f;
  const float Adust = 192.f / 320.f;
  const float Bn = 1.f / 320.f;
  __syncthreads();
  for (int it = 0; it < 3; ++it) {
    for (int i = wave; i < 65; i += 4) {
      float s = E[i][lane] * V[lane];
      s = fmaf(E[i][lane + 64], V[lane + 64], s);
      s = fmaf(E[i][lane + 128], V[lane + 128], s);
      s = fmaf(E[i][lane + 192], V[lane + 192], s);
#pragma unroll
      for (int off = 32; off; off >>= 1) s += __shfl_xor(s, off);
      if (lane == 0) U[i] = (i == 64 ? Adust : Ai) / s;
    }
    __syncthreads();
    {
      const int n = tid;
      float s = 0.f;
#pragma unroll 13
      for (int i = 0; i < 65; ++i) s = fmaf(E[i][n], U[i], s);
      V[n] = Bn / s;
    }
    __syncthreads();
  }
  for (int idx = tid; idx < 16384; idx += 256) {
    const int m = idx >> 8, n = idx & 255;
    Pb[b * 16384 + idx] = f32_to_bf16_rne(E[m][n] * U[m] * V[n] * 320.f);
  }
}

// ---- VLAD via MFMA, direct from global -------------------------------------
__global__ __launch_bounds__(256) void vlad_mfma(const ushort* __restrict__ Fb,
                                                 const ushort* __restrict__ Pb,
                                                 float* __restrict__ VL) {
  const int b = blockIdx.x;
  const int tid = threadIdx.x, l = tid & 63, w = tid >> 6;
  const int lr = l & 15, ko = l >> 4;
  f32x4 acc[2][4];
#pragma unroll
  for (int li = 0; li < 2; ++li)
#pragma unroll
    for (int ni = 0; ni < 4; ++ni) acc[li][ni] = (f32x4){0.f, 0.f, 0.f, 0.f};
  const ushort* Fbase = Fb + b * 256;
  const ushort* Pbase = Pb + b * 16384;
#pragma unroll
  for (int ks = 0; ks < 8; ++ks) {
    const int k = ks * 32 + ko * 8;
    s16x8 bfr[4];
#pragma unroll
    for (int ni = 0; ni < 4; ++ni)
      bfr[ni] = *(const s16x8*)(Pbase + (ni * 16 + lr) * 256 + k);
#pragma unroll
    for (int li = 0; li < 2; ++li) {
      const s16x8 af =
          *(const s16x8*)(Fbase + (size_t)(w * 32 + li * 16 + lr) * BNT + k);
#pragma unroll
      for (int ni = 0; ni < 4; ++ni)
        acc[li][ni] = __builtin_amdgcn_mfma_f32_16x16x32_bf16(
            af, bfr[ni], acc[li][ni], 0, 0, 0);
    }
  }
#pragma unroll
  for (int li = 0; li < 2; ++li)
#pragma unroll
    for (int ni = 0; ni < 4; ++ni)
#pragma unroll
      for (int j = 0; j < 4; ++j) {
        const int ll = w * 32 + li * 16 + ko * 4 + j;
        const int m = ni * 16 + lr;
        VL[b * 8192 + ll * 64 + m] = acc[li][ni][j];
      }
}

// ---------------- finalize ---------------------------------------------------
__global__ __launch_bounds__(256) void finalize_kernel(
    const float* __restrict__ TK, const float* __restrict__ VL,
    float* __restrict__ out) {
  const int b = blockIdx.x, tid = threadIdx.x;
  const int lane = tid & 63, wave = tid >> 6;
  __shared__ float sred[4];
  __shared__ float ssm_part[4][64];
  __shared__ float invm_s[64];
  __shared__ float totals[1];
  const float* vl = &VL[b * 8192];
  float accv = 0.f;
  for (int k = 0; k < 32; ++k) {
    const float xv = vl[tid + 256 * k];
    accv = fmaf(xv, xv, accv);
  }
  ssm_part[wave][lane] = accv;
  const float tv = TK[b * 256 + tid];
  float ss = tv * tv;
#pragma unroll
  for (int off = 32; off; off >>= 1) ss += __shfl_down(ss, off);
  if (lane == 0) sred[wave] = ss;
  __syncthreads();
  const float sstok = sred[0] + sred[1] + sred[2] + sred[3];
  const float invtok = 1.f / fmaxf(sqrtf(sstok), 1e-12f);
  float tpart = 0.f;
  if (wave == 0) {
    const float s4 = ssm_part[0][tid] + ssm_part[1][tid] + ssm_part[2][tid] +
                     ssm_part[3][tid];
    const float inv = 1.f / fmaxf(sqrtf(s4), 1e-12f);
    invm_s[tid] = inv;
    tpart = s4 * inv * inv;
#pragma unroll
    for (int off = 32; off; off >>= 1) tpart += __shfl_down(tpart, off);
    if (lane == 0) totals[0] = tpart;
  }
  __syncthreads();
  const float total = totals[0] + sstok * invtok * invtok;
  const float invT = 1.f / fmaxf(sqrtf(total), 1e-12f);
  float* ob = &out[b * 8448];
  ob[tid] = tv * invtok * invT;
  for (int k = 0; k < 32; ++k) {
    const int idx = tid + 256 * k;
    ob[256 + idx] = vl[idx] * invm_s[idx & 63] * invT;
  }
}

// ================= fp32 fallback path kernels ===============================
template <bool RELU>
__global__ __launch_bounds__(256) void gemm_tt(
    const float* __restrict__ A, const float* __restrict__ Bw,
    const float* __restrict__ bias, float* __restrict__ C, int K, int Nn) {
  __shared__ float As[16][68];
  __shared__ float Bs[16][68];
  const int tid = threadIdx.x;
  const int tx = tid & 15, ty = tid >> 4;
  const int n0 = blockIdx.x * 64;
  const int lrow = tid >> 2, lkq = (tid & 3) << 2;
  float acc[4][4];
#pragma unroll
  for (int r = 0; r < 4; ++r)
#pragma unroll
    for (int c = 0; c < 4; ++c) acc[r][c] = 0.f;
  for (int k0 = 0; k0 < K; k0 += 16) {
    const float4 av = *(const float4*)&A[lrow * K + k0 + lkq];
    const float4 bv = *(const float4*)&Bw[(n0 + lrow) * K + k0 + lkq];
    As[lkq + 0][lrow] = av.x;
    As[lkq + 1][lrow] = av.y;
    As[lkq + 2][lrow] = av.z;
    As[lkq + 3][lrow] = av.w;
    Bs[lkq + 0][lrow] = bv.x;
    Bs[lkq + 1][lrow] = bv.y;
    Bs[lkq + 2][lrow] = bv.z;
    Bs[lkq + 3][lrow] = bv.w;
    __syncthreads();
#pragma unroll
    for (int kk = 0; kk < 16; ++kk) {
      const float4 a4 = *(const float4*)&As[kk][ty << 2];
      const float4 b4 = *(const float4*)&Bs[kk][tx << 2];
      acc[0][0] = fmaf(a4.x, b4.x, acc[0][0]);
      acc[0][1] = fmaf(a4.x, b4.y, acc[0][1]);
      acc[0][2] = fmaf(a4.x, b4.z, acc[0][2]);
      acc[0][3] = fmaf(a4.x, b4.w, acc[0][3]);
      acc[1][0] = fmaf(a4.y, b4.x, acc[1][0]);
      acc[1][1] = fmaf(a4.y, b4.y, acc[1][1]);
      acc[1][2] = fmaf(a4.y, b4.z, acc[1][2]);
      acc[1][3] = fmaf(a4.y, b4.w, acc[1][3]);
      acc[2][0] = fmaf(a4.z, b4.x, acc[2][0]);
      acc[2][1] = fmaf(a4.z, b4.y, acc[2][1]);
      acc[2][2] = fmaf(a4.z, b4.z, acc[2][2]);
      acc[2][3] = fmaf(a4.z, b4.w, acc[2][3]);
      acc[3][0] = fmaf(a4.w, b4.x, acc[3][0]);
      acc[3][1] = fmaf(a4.w, b4.y, acc[3][1]);
      acc[3][2] = fmaf(a4.w, b4.z, acc[3][2]);
      acc[3][3] = fmaf(a4.w, b4.w, acc[3][3]);
    }
    __syncthreads();
  }
#pragma unroll
  for (int r = 0; r < 4; ++r) {
    const int row = (ty << 2) + r;
    float4 o;
    o.x = acc[r][0] + bias[n0 + (tx << 2) + 0];
    o.y = acc[r][1] + bias[n0 + (tx << 2) + 1];
    o.z = acc[r][2] + bias[n0 + (tx << 2) + 2];
    o.w = acc[r][3] + bias[n0 + (tx << 2) + 3];
    if (RELU) {
      o.x = fmaxf(o.x, 0.f);
      o.y = fmaxf(o.y, 0.f);
      o.z = fmaxf(o.z, 0.f);
      o.w = fmaxf(o.w, 0.f);
    }
    *(float4*)&C[row * Nn + n0 + (tx << 2)] = o;
  }
}

template <bool XVIEW, bool RELU>
__global__ __launch_bounds__(256) void gemm_tile(
    const float* __restrict__ A, const float* __restrict__ Bsrc,
    const float* __restrict__ bias, float* __restrict__ Cout, int K) {
  __shared__ float As[16][68];
  __shared__ float Bsh[16][68];
  const int tid = threadIdx.x;
  const int tx = tid & 15, ty = tid >> 4;
  const int rowBase = blockIdx.y * 64;
  const int colBase = blockIdx.x * 64;
  const int bb = colBase >> 8, n0 = colBase & 255;
  const int boff = XVIEW ? (bb * 393216 + n0) : colBase;
  const int la_row = tid >> 2, la_kq = (tid & 3) << 2;
  const int lb_k = tid >> 4, lb_c = (tid & 15) << 2;
  float acc[4][4];
#pragma unroll
  for (int r = 0; r < 4; ++r)
#pragma unroll
    for (int c = 0; c < 4; ++c) acc[r][c] = 0.f;
  for (int k0 = 0; k0 < K; k0 += 16) {
    const float4 av = *(const float4*)&A[(rowBase + la_row) * K + k0 + la_kq];
    float4 bv;
    if (XVIEW)
      bv = *(const float4*)&Bsrc[boff + (k0 + lb_k) * 256 + lb_c];
    else
      bv = *(const float4*)&Bsrc[(k0 + lb_k) * BNT + boff + lb_c];
    As[la_kq + 0][la_row] = av.x;
    As[la_kq + 1][la_row] = av.y;
    As[la_kq + 2][la_row] = av.z;
    As[la_kq + 3][la_row] = av.w;
    *(float4*)&Bsh[lb_k][lb_c] = bv;
    __syncthreads();
#pragma unroll
    for (int kk = 0; kk < 16; ++kk) {
      const float4 a4 = *(const float4*)&As[kk][ty << 2];
      const float4 b4 = *(const float4*)&Bsh[kk][tx << 2];
      acc[0][0] = fmaf(a4.x, b4.x, acc[0][0]);
      acc[0][1] = fmaf(a4.x, b4.y, acc[0][1]);
      acc[0][2] = fmaf(a4.x, b4.z, acc[0][2]);
      acc[0][3] = fmaf(a4.x, b4.w, acc[0][3]);
      acc[1][0] = fmaf(a4.y, b4.x, acc[1][0]);
      acc[1][1] = fmaf(a4.y, b4.y, acc[1][1]);
      acc[1][2] = fmaf(a4.y, b4.z, acc[1][2]);
      acc[1][3] = fmaf(a4.y, b4.w, acc[1][3]);
      acc[2][0] = fmaf(a4.z, b4.x, acc[2][0]);
      acc[2][1] = fmaf(a4.z, b4.y, acc[2][1]);
      acc[2][2] = fmaf(a4.z, b4.z, acc[2][2]);
      acc[2][3] = fmaf(a4.z, b4.w, acc[2][3]);
      acc[3][0] = fmaf(a4.w, b4.x, acc[3][0]);
      acc[3][1] = fmaf(a4.w, b4.y, acc[3][1]);
      acc[3][2] = fmaf(a4.w, b4.z, acc[3][2]);
      acc[3][3] = fmaf(a4.w, b4.w, acc[3][3]);
    }
    __syncthreads();
  }
#pragma unroll
  for (int r = 0; r < 4; ++r) {
    const int row = rowBase + (ty << 2) + r;
    const float bsv = bias[row];
    float4 o;
    o.x = acc[r][0] + bsv;
    o.y = acc[r][1] + bsv;
    o.z = acc[r][2] + bsv;
    o.w = acc[r][3] + bsv;
    if (RELU) {
      o.x = fmaxf(o.x, 0.f);
      o.y = fmaxf(o.y, 0.f);
      o.z = fmaxf(o.z, 0.f);
      o.w = fmaxf(o.w, 0.f);
    }
    *(float4*)&Cout[row * BNT + colBase + (tx << 2)] = o;
  }
}

__global__ __launch_bounds__(256) void sinkhorn_kernel(
    const float* __restrict__ S, const float* __restrict__ dustp,
    float* __restrict__ P) {
  const int b = blockIdx.x, tid = threadIdx.x;
  const int lane = tid & 63, wave = tid >> 6;
  __shared__ float Ms[65][256];
  __shared__ float u[65];
  __shared__ float v[256];
  const float dust = dustp[0];
  for (int idx = tid; idx < 16384; idx += 256) {
    const int m = idx >> 8, n = idx & 255;
    Ms[m][n] = S[m * BNT + b * 256 + n];
  }
  Ms[64][tid] = dust;
  v[tid] = 0.f;
  if (tid < 65) u[tid] = 0.f;
  const float norm = -logf(320.f);
  const float la_dust = norm + logf(192.f);
  __syncthreads();
  for (int it = 0; it < 3; ++it) {
    for (int i = wave; i < 65; i += 4) {
      const float x0 = Ms[i][lane] + v[lane];
      const float x1 = Ms[i][lane + 64] + v[lane + 64];
      const float x2 = Ms[i][lane + 128] + v[lane + 128];
      const float x3 = Ms[i][lane + 192] + v[lane + 192];
      float mm = fmaxf(fmaxf(x0, x1), fmaxf(x2, x3));
#pragma unroll
      for (int off = 32; off; off >>= 1) mm = fmaxf(mm, __shfl_xor(mm, off));
      float s = expf(x0 - mm) + expf(x1 - mm) + expf(x2 - mm) + expf(x3 - mm);
#pragma unroll
      for (int off = 32; off; off >>= 1) s += __shfl_xor(s, off);
      if (lane == 0) u[i] = (i == 64 ? la_dust : norm) - (logf(s) + mm);
    }
    __syncthreads();
    {
      const int n = tid;
      float mm = -1e30f;
      for (int i = 0; i < 65; ++i) mm = fmaxf(mm, Ms[i][n] + u[i]);
      float s = 0.f;
      for (int i = 0; i < 65; ++i) s += expf(Ms[i][n] + u[i] - mm);
      v[n] = norm - (logf(s) + mm);
    }
    __syncthreads();
  }
  for (int idx = tid; idx < 16384; idx += 256) {
    const int m = idx >> 8, n = idx & 255;
    P[b * 16384 + idx] = expf(Ms[m][n] + u[m] + v[n] - norm);
  }
}

__device__ __forceinline__ int ps_idx(int m, int n) {
  return m * 256 + ((((n >> 2) ^ (m & 7)) << 2) | (n & 3));
}
__global__ __launch_bounds__(256) void vlad_kernel(const float* __restrict__ F,
                                                   const float* __restrict__ P,
                                                   float* __restrict__ VL) {
  const int b = blockIdx.x, half = blockIdx.y;
  const int tid = threadIdx.x;
  const int m = tid & 63, lg = tid >> 6;
  __shared__ float ps[64 * 256];
  for (int idx = tid; idx < 16384; idx += 256) {
    const int mm = idx >> 8, n = idx & 255;
    ps[ps_idx(mm, n)] = P[b * 16384 + idx];
  }
  __syncthreads();
  float acc[16];
#pragma unroll
  for (int i = 0; i < 16; ++i) acc[i] = 0.f;
  for (int i = 0; i < 16; ++i) {
    const int ll = half * 64 + lg + 4 * i;
    const float* frow = &F[(size_t)ll * BNT + b * 256];
    float a = 0.f;
#pragma unroll 8
    for (int nq = 0; nq < 64; ++nq) {
      const float4 f4 = *(const float4*)&frow[nq << 2];
      const float4 p4 = *(const float4*)&ps[m * 256 + ((nq ^ (m & 7)) << 2)];
      a = fmaf(f4.x, p4.x, a);
      a = fmaf(f4.y, p4.y, a);
      a = fmaf(f4.z, p4.z, a);
      a = fmaf(f4.w, p4.w, a);
    }
    acc[i] = a;
  }
#pragma unroll
  for (int i = 0; i < 16; ++i) {
    const int ll = half * 64 + lg + 4 * i;
    VL[b * 8192 + ll * 64 + m] = acc[i];
  }
}

extern "C" void kernel_launch(void* const* d_in, const int* in_sizes, int n_in,
                              void* d_out, int out_size, void* d_ws,
                              size_t ws_size, hipStream_t stream) {
  const float* x = (const float*)d_in[0];
  const float* t = (const float*)d_in[1];
  const float* Wt1 = (const float*)d_in[2];
  const float* bt1 = (const float*)d_in[3];
  const float* Wt2 = (const float*)d_in[4];
  const float* bt2 = (const float*)d_in[5];
  const float* Wc1 = (const float*)d_in[6];
  const float* bc1 = (const float*)d_in[7];
  const float* Wc2 = (const float*)d_in[8];
  const float* bc2 = (const float*)d_in[9];
  const float* Ws1 = (const float*)d_in[10];
  const float* bs1 = (const float*)d_in[11];
  const float* Ws2 = (const float*)d_in[12];
  const float* bs2 = (const float*)d_in[13];
  const float* dust = (const float*)d_in[14];
  float* out = (float*)d_out;

  if (ws_size >= 97714176ull) {
    char* base = (char*)d_ws;
    ushort* Tb = (ushort*)base;
    ushort* Wt1b = (ushort*)(base + 196608);
    ushort* Wt2b = (ushort*)(base + 1769472);
    float* Pt = (float*)(base + 2031616);
    ushort* Hb = (ushort*)(base + 2555904);
    ushort* XT = (ushort*)base;
    ushort* Pb = (ushort*)base;
    float* VL = (float*)(base + 4194304);
    ushort* Fb = (ushort*)(base + 8388608);
    ushort* HT = (ushort*)(base + 50331648);
    float* C2 = (float*)(base + 83886080);
    ushort* A1 = (ushort*)(base + 83886080);
    ushort* Wc1b = A1;
    ushort* Ws1b = (ushort*)(base + 85458944);
    ushort* A2 = (ushort*)(base + 96468992);
    float* b2 = (float*)(base + 96993280);
    float* TK = (float*)(base + 96994304);
    float* b1 = (float*)(base + 97059840);
    float* Sb = C2 + (size_t)128 * BNT;

    prep_all<<<2788, 256, 0, stream>>>(t, Wt1, Wt2, Wc1, Ws1, bc1, bs1, Wc2,
                                       Ws2, bc2, bs2, Tb, Wt1b, Wt2b, Wc1b,
                                       Ws1b, b1, A2, b2);
    token1_mfma<<<dim3(8, 4), 256, 0, stream>>>(Tb, Wt1b, Pt);
    token1_reduce<<<64, 256, 0, stream>>>(Pt, bt1, Hb);
    token2_mfma<<<4, 256, 0, stream>>>(Hb, Wt2b, bt2, TK);
    transpose_x_bf16<<<dim3(24, 64), 256, 0, stream>>>(x, XT);
    gemm1_win<<<256, 512, 0, stream>>>(A1, XT, b1, HT);
    gemm2_mfma96<<<256, 256, 0, stream>>>(A2, HT, b2, C2, Fb);
    sinkhorn_lin<<<64, 256, 0, stream>>>(Sb, dust, Pb);
    vlad_mfma<<<64, 256, 0, stream>>>(Fb, Pb, VL);
    finalize_kernel<<<64, 256, 0, stream>>>(TK, VL, out);
  } else {
    float* ws = (float*)d_ws;
    float* H = ws;
    float* F = H + 512 * BNT;
    float* Sb = F + 128 * BNT;
    float* P = Sb + 64 * BNT;
    float* VL = P + 64 * BNT;
    float* TK = VL + 64 * 8192;
    float* Hh = P;

    gemm_tt<true><<<dim3(8, 1), 256, 0, stream>>>(t, Wt1, bt1, Hh, 1536, 512);
    gemm_tt<false><<<dim3(4, 1), 256, 0, stream>>>(Hh, Wt2, bt2, TK, 512, 256);
    gemm_tile<true, true><<<dim3(256, 8), 256, 0, stream>>>(Wc1, x, bc1, H, 1536);
    gemm_tile<false, false><<<dim3(256, 2), 256, 0, stream>>>(Wc2, H, bc2, F, 512);
    gemm_tile<true, true><<<dim3(256, 8), 256, 0, stream>>>(Ws1, x, bs1, H, 1536);
    gemm_tile<false, false><<<dim3(256, 1), 256, 0, stream>>>(Ws2, H, bs2, Sb, 512);
    sinkhorn_kernel<<<64, 256, 0, stream>>>(Sb, dust, P);
    vlad_kernel<<<dim3(64, 2), 256, 0, stream>>>(F, P, VL);
    finalize_kernel<<<64, 256, 0, stream>>>(TK, VL, out);
  }
}

// Round 13
// 159.196 us; speedup vs baseline: 1.4612x; 1.0436x over previous
//
#include <hip/hip_runtime.h>
#include <math.h>

// SALAD head. B=64, C=1536, N=256, HID=512, L=128, M=64, G=256. BNT = B*N.
#define BNT 16384

using f32x4 = __attribute__((ext_vector_type(4))) float;
using s16x8 = __attribute__((ext_vector_type(8))) short;

__device__ __forceinline__ unsigned short f32_to_bf16_rne(float f) {
  unsigned int u = __float_as_uint(f);
  u += 0x7FFFu + ((u >> 16) & 1u);
  return (unsigned short)(u >> 16);
}
__device__ __forceinline__ unsigned pack_bf16x2(float a, float b) {
  return (unsigned)f32_to_bf16_rne(a) | ((unsigned)f32_to_bf16_rne(b) << 16);
}

__device__ __forceinline__ void gload_lds16(const ushort* g, ushort* lds) {
  __builtin_amdgcn_global_load_lds(
      (const __attribute__((address_space(1))) unsigned int*)g,
      (__attribute__((address_space(3))) unsigned int*)lds, 16, 0, 0);
}

// ---- fused prep: bf16 converts of t,Wt1,Wt2,Wc1,Ws1 + b1 stack + A2 stack --
__global__ __launch_bounds__(256) void prep_all(
    const float* __restrict__ t, const float* __restrict__ Wt1,
    const float* __restrict__ Wt2, const float* __restrict__ Wc1,
    const float* __restrict__ Ws1, const float* __restrict__ bc1,
    const float* __restrict__ bs1, const float* __restrict__ Wc2,
    const float* __restrict__ Ws2, const float* __restrict__ bc2,
    const float* __restrict__ bs2, ushort* __restrict__ Tb,
    ushort* __restrict__ Wt1b, ushort* __restrict__ Wt2b,
    ushort* __restrict__ Wc1b, ushort* __restrict__ Ws1b,
    float* __restrict__ b1, ushort* __restrict__ A2, float* __restrict__ b2) {
  const int bid = blockIdx.x, tid = threadIdx.x;
  const float* src = nullptr;
  ushort* dst = nullptr;
  int i = 0;
  if (bid < 96) {
    src = t; dst = Tb; i = bid * 256 + tid;
  } else if (bid < 864) {
    src = Wt1; dst = Wt1b; i = (bid - 96) * 256 + tid;
  } else if (bid < 992) {
    src = Wt2; dst = Wt2b; i = (bid - 864) * 256 + tid;
  } else if (bid < 1760) {
    src = Wc1; dst = Wc1b; i = (bid - 992) * 256 + tid;
  } else if (bid < 2528) {
    src = Ws1; dst = Ws1b; i = (bid - 1760) * 256 + tid;
  } else if (bid < 2532) {
    const int j = (bid - 2528) * 256 + tid;
    b1[j] = j < 512 ? bc1[j] : bs1[j - 512];
    return;
  } else {
    const int r = bid - 2532;
    const int c = tid * 4;
    float v[4] = {0.f, 0.f, 0.f, 0.f};
    if (r < 128) {
      if (c < 512) {
#pragma unroll
        for (int j = 0; j < 4; ++j) v[j] = Wc2[r * 512 + c + j];
      }
    } else if (r < 192) {
      if (c >= 512) {
#pragma unroll
        for (int j = 0; j < 4; ++j) v[j] = Ws2[(r - 128) * 512 + (c - 512) + j];
      }
    }
    uint2 o;
    o.x = pack_bf16x2(v[0], v[1]);
    o.y = pack_bf16x2(v[2], v[3]);
    *(uint2*)(A2 + r * 1024 + c) = o;
    if (tid == 0) b2[r] = r < 128 ? bc2[r] : (r < 192 ? bs2[r - 128] : 0.f);
    return;
  }
  const float4 v = ((const float4*)src)[i];
  uint2 o;
  o.x = pack_bf16x2(v.x, v.y);
  o.y = pack_bf16x2(v.z, v.w);
  ((uint2*)dst)[i] = o;
}

// ---- token layer 1 (MFMA, no LDS, split-K) ---------------------------------
__global__ __launch_bounds__(256) void token1_mfma(
    const ushort* __restrict__ Tb, const ushort* __restrict__ Wt1b,
    float* __restrict__ Pt) {
  const int ct = blockIdx.x, kc = blockIdx.y;
  const int tid = threadIdx.x, l = tid & 63, wv = tid >> 6;
  const int lr = l & 15, ko = l >> 4;
  const int col = ct * 64 + wv * 16 + lr;
  f32x4 acc[4];
#pragma unroll
  for (int r = 0; r < 4; ++r) acc[r] = (f32x4){0.f, 0.f, 0.f, 0.f};
  const int k0 = kc * 384;
#pragma unroll 4
  for (int ks = 0; ks < 12; ++ks) {
    const int k = k0 + ks * 32 + ko * 8;
    const s16x8 bf = *(const s16x8*)(Wt1b + (size_t)col * 1536 + k);
#pragma unroll
    for (int rf = 0; rf < 4; ++rf) {
      const s16x8 af = *(const s16x8*)(Tb + (size_t)(rf * 16 + lr) * 1536 + k);
      acc[rf] =
          __builtin_amdgcn_mfma_f32_16x16x32_bf16(af, bf, acc[rf], 0, 0, 0);
    }
  }
#pragma unroll
  for (int rf = 0; rf < 4; ++rf)
#pragma unroll
    for (int j = 0; j < 4; ++j) {
      const int row = rf * 16 + ko * 4 + j;
      Pt[((kc * 64 + row) << 9) + col] = acc[rf][j];
    }
}

// ---- token layer-1 reduce --------------------------------------------------
__global__ __launch_bounds__(256) void token1_reduce(
    const float* __restrict__ Pt, const float* __restrict__ bt1,
    ushort* __restrict__ Hb) {
  const int i = blockIdx.x * 256 + threadIdx.x;
  const int row = i >> 8, c2 = (i & 255) * 2;
  float v0 = bt1[c2], v1 = bt1[c2 + 1];
#pragma unroll
  for (int kc = 0; kc < 4; ++kc) {
    v0 += Pt[((kc * 64 + row) << 9) + c2];
    v1 += Pt[((kc * 64 + row) << 9) + c2 + 1];
  }
  v0 = fmaxf(v0, 0.f);
  v1 = fmaxf(v1, 0.f);
  ((unsigned*)Hb)[i] = pack_bf16x2(v0, v1);
}

// ---- token layer 2 (MFMA, no LDS) ------------------------------------------
__global__ __launch_bounds__(256) void token2_mfma(
    const ushort* __restrict__ Hb, const ushort* __restrict__ Wt2b,
    const float* __restrict__ bt2, float* __restrict__ TK) {
  const int ct = blockIdx.x;
  const int tid = threadIdx.x, l = tid & 63, wv = tid >> 6;
  const int lr = l & 15, ko = l >> 4;
  const int col = ct * 64 + wv * 16 + lr;
  f32x4 acc[4];
#pragma unroll
  for (int r = 0; r < 4; ++r) acc[r] = (f32x4){0.f, 0.f, 0.f, 0.f};
#pragma unroll 4
  for (int ks = 0; ks < 16; ++ks) {
    const int k = ks * 32 + ko * 8;
    const s16x8 bf = *(const s16x8*)(Wt2b + (size_t)col * 512 + k);
#pragma unroll
    for (int rf = 0; rf < 4; ++rf) {
      const s16x8 af = *(const s16x8*)(Hb + (size_t)(rf * 16 + lr) * 512 + k);
      acc[rf] =
          __builtin_amdgcn_mfma_f32_16x16x32_bf16(af, bf, acc[rf], 0, 0, 0);
    }
  }
  const float bb = bt2[col];
#pragma unroll
  for (int rf = 0; rf < 4; ++rf)
#pragma unroll
    for (int j = 0; j < 4; ++j)
      TK[(rf * 16 + ko * 4 + j) * 256 + col] = acc[rf][j] + bb;
}

// ------- x [64][1536][256] fp32 -> XT [16384][1536] bf16 (transpose) --------
__global__ __launch_bounds__(256) void transpose_x_bf16(
    const float* __restrict__ x, ushort* __restrict__ XT) {
  __shared__ ushort lds[16384];
  const int cc = blockIdx.x * 64, b = blockIdx.y;
  const int t = threadIdx.x;
  const float* xb = x + b * 393216 + cc * 256;
#pragma unroll
  for (int i = 0; i < 16; ++i) {
    const int c0 = i * 4;
    const float v0 = xb[(c0 + 0) * 256 + t];
    const float v1 = xb[(c0 + 1) * 256 + t];
    const float v2 = xb[(c0 + 2) * 256 + t];
    const float v3 = xb[(c0 + 3) * 256 + t];
    uint2 o;
    o.x = pack_bf16x2(v0, v1);
    o.y = pack_bf16x2(v2, v3);
    const int g = c0 >> 3;
    const int waddr = t * 128 + (((g ^ (t & 7)) << 4) | ((c0 & 7) << 1));
    *(uint2*)((char*)lds + waddr) = o;
  }
  __syncthreads();
#pragma unroll
  for (int r = 0; r < 8; ++r) {
    const int j = r * 32 + (t >> 3), q = t & 7;
    const uint4 o =
        *(const uint4*)((const char*)lds + j * 128 + ((q ^ (j & 7)) << 4));
    *(uint4*)(XT + (size_t)(b * 256 + j) * 1536 + cc + q * 8) = o;
  }
}

// ---- layer-1 GEMM: 256x256, BK=64, 8-phase schedule (T2+T3+T4+T5) ----------
// (r10 verbatim — best measured variant: 805 TF, 0 bank conflicts)
__global__ __launch_bounds__(512) void gemm1_8ph(
    const ushort* __restrict__ A1, const ushort* __restrict__ Bt,
    const float* __restrict__ b1, ushort* __restrict__ HT) {
  __shared__ ushort lds[65536];  // A: [0,32768) 4 slots; B: [32768,65536)
  const int tid = threadIdx.x, l = tid & 63, w = tid >> 6;
  const int bid = blockIdx.x;
  const int newid = (bid & 7) * 32 + (bid >> 3);  // XCD-bijective (256%8==0)
  const int m0 = (newid & 3) * 256, n0 = (newid >> 2) * 256;
  const int wr = w >> 2, wc = w & 3;  // 2x4 wave grid
  const int lr = l & 15, kq = l >> 4;
  const int permK8 = (kq ^ ((lr >> 1) & 3)) * 8;  // ushort offset in row
  const int aRow = wr * 128 + lr;                 // + mi*16
  const int bRow = wc * 64 + lr;                  // + ni*16

  f32x4 acc[8][4];
#pragma unroll
  for (int mi = 0; mi < 8; ++mi)
#pragma unroll
    for (int ni = 0; ni < 4; ++ni) acc[mi][ni] = (f32x4){0.f, 0.f, 0.f, 0.f};

  const int srow = tid >> 2, ssp = tid & 3;
  const int skq = ssp ^ ((srow >> 1) & 3);
  const ushort* sA0 = A1 + (size_t)(m0 + srow) * 1536 + skq * 8;
  const ushort* sA1 = A1 + (size_t)(m0 + srow + 128) * 1536 + skq * 8;
  const ushort* sB0 = Bt + (size_t)(n0 + srow) * 1536 + skq * 8;
  const ushort* sB1 = Bt + (size_t)(n0 + srow + 128) * 1536 + skq * 8;
  const int wofs = w * 512;

#define STG_A(tau, kh)                                              \
  do {                                                              \
    ushort* d = &lds[((((tau)&1) * 2 + (kh)) * 8192) + wofs];       \
    gload_lds16(sA0 + (tau)*64 + (kh)*32, d);                       \
    gload_lds16(sA1 + (tau)*64 + (kh)*32, d + 4096);                \
  } while (0)
#define STG_B(tau, kh)                                              \
  do {                                                              \
    ushort* d = &lds[32768 + ((((tau)&1) * 2 + (kh)) * 8192) + wofs]; \
    gload_lds16(sB0 + (tau)*64 + (kh)*32, d);                       \
    gload_lds16(sB1 + (tau)*64 + (kh)*32, d + 4096);                \
  } while (0)

  STG_A(0, 0);
  STG_B(0, 0);
  STG_A(0, 1);
  STG_B(0, 1);
  asm volatile("s_waitcnt vmcnt(0)" ::: "memory");
  __builtin_amdgcn_s_barrier();

  for (int sg = 0; sg < 24; ++sg) {
    const int rho = sg & 1;
    const int As0 = (rho * 2 + 0) * 8192, As1 = (rho * 2 + 1) * 8192;
    const int Bs0 = 32768 + As0, Bs1 = 32768 + As1;
    const bool st = (sg + 1) < 24;
    s16x8 af[4], bfv[4];

    // ---- P1: kh0, mi 0-3
#pragma unroll
    for (int i = 0; i < 4; ++i)
      af[i] = *(const s16x8*)&lds[As0 + (aRow + i * 16) * 32 + permK8];
#pragma unroll
    for (int ni = 0; ni < 4; ++ni)
      bfv[ni] = *(const s16x8*)&lds[Bs0 + (bRow + ni * 16) * 32 + permK8];
    if (st) STG_A(sg + 1, 0);
    __builtin_amdgcn_s_barrier();
    __builtin_amdgcn_s_setprio(1);
#pragma unroll
    for (int i = 0; i < 4; ++i)
#pragma unroll
      for (int ni = 0; ni < 4; ++ni)
        acc[i][ni] = __builtin_amdgcn_mfma_f32_16x16x32_bf16(af[i], bfv[ni],
                                                             acc[i][ni], 0, 0, 0);
    __builtin_amdgcn_s_setprio(0);
    __builtin_amdgcn_s_barrier();

    // ---- P2: kh0, mi 4-7
#pragma unroll
    for (int i = 0; i < 4; ++i)
      af[i] = *(const s16x8*)&lds[As0 + (aRow + 64 + i * 16) * 32 + permK8];
    if (st) STG_B(sg + 1, 0);
    if (sg < 23)
      asm volatile("s_waitcnt vmcnt(4)" ::: "memory");
    else
      asm volatile("s_waitcnt vmcnt(0)" ::: "memory");
    __builtin_amdgcn_s_barrier();
    __builtin_amdgcn_s_setprio(1);
#pragma unroll
    for (int i = 0; i < 4; ++i)
#pragma unroll
      for (int ni = 0; ni < 4; ++ni)
        acc[4 + i][ni] = __builtin_amdgcn_mfma_f32_16x16x32_bf16(
            af[i], bfv[ni], acc[4 + i][ni], 0, 0, 0);
    __builtin_amdgcn_s_setprio(0);
    __builtin_amdgcn_s_barrier();

    // ---- P3: kh1, mi 0-3
#pragma unroll
    for (int i = 0; i < 4; ++i)
      af[i] = *(const s16x8*)&lds[As1 + (aRow + i * 16) * 32 + permK8];
#pragma unroll
    for (int ni = 0; ni < 4; ++ni)
      bfv[ni] = *(const s16x8*)&lds[Bs1 + (bRow + ni * 16) * 32 + permK8];
    if (st) STG_A(sg + 1, 1);
    __builtin_amdgcn_s_barrier();
    __builtin_amdgcn_s_setprio(1);
#pragma unroll
    for (int i = 0; i < 4; ++i)
#pragma unroll
      for (int ni = 0; ni < 4; ++ni)
        acc[i][ni] = __builtin_amdgcn_mfma_f32_16x16x32_bf16(af[i], bfv[ni],
                                                             acc[i][ni], 0, 0, 0);
    __builtin_amdgcn_s_setprio(0);
    __builtin_amdgcn_s_barrier();

    // ---- P4: kh1, mi 4-7
#pragma unroll
    for (int i = 0; i < 4; ++i)
      af[i] = *(const s16x8*)&lds[As1 + (aRow + 64 + i * 16) * 32 + permK8];
    if (st) STG_B(sg + 1, 1);
    asm volatile("s_waitcnt vmcnt(4)" ::: "memory");
    __builtin_amdgcn_s_barrier();
    __builtin_amdgcn_s_setprio(1);
#pragma unroll
    for (int i = 0; i < 4; ++i)
#pragma unroll
      for (int ni = 0; ni < 4; ++ni)
        acc[4 + i][ni] = __builtin_amdgcn_mfma_f32_16x16x32_bf16(
            af[i], bfv[ni], acc[4 + i][ni], 0, 0, 0);
    __builtin_amdgcn_s_setprio(0);
    __builtin_amdgcn_s_barrier();
  }
#undef STG_A
#undef STG_B

#pragma unroll
  for (int mi = 0; mi < 8; ++mi) {
    const int rbase = m0 + wr * 128 + mi * 16 + kq * 4;
    float b4[4];
#pragma unroll
    for (int j = 0; j < 4; ++j) b4[j] = b1[rbase + j];
#pragma unroll
    for (int ni = 0; ni < 4; ++ni) {
      const int col = n0 + wc * 64 + ni * 16 + lr;
      const float v0 = fmaxf(acc[mi][ni][0] + b4[0], 0.f);
      const float v1 = fmaxf(acc[mi][ni][1] + b4[1], 0.f);
      const float v2 = fmaxf(acc[mi][ni][2] + b4[2], 0.f);
      const float v3 = fmaxf(acc[mi][ni][3] + b4[3], 0.f);
      uint2 o;
      o.x = pack_bf16x2(v0, v1);
      o.y = pack_bf16x2(v2, v3);
      *(uint2*)(HT + (size_t)col * 1024 + rbase) = o;
    }
  }
}

// ---- layer-2 MFMA GEMM, 2-phase dbuf, BM=96 (balanced m-tiles) -------------
__global__ __launch_bounds__(256) void gemm2_mfma96(
    const ushort* __restrict__ A2, const ushort* __restrict__ HT,
    const float* __restrict__ b2, float* __restrict__ C2,
    ushort* __restrict__ Fb) {
  constexpr int K = 1024;
  __shared__ ushort As[2 * 3072];
  __shared__ ushort Bs[2 * 4096];
  const int tid = threadIdx.x;
  const int l = tid & 63, w = tid >> 6;
  const int bid = blockIdx.x;
  const int newid = (bid & 7) * 32 + (bid >> 3);
  const int m0 = (newid & 1) * 96, n0 = (newid >> 1) * 128;
  const int wr = w >> 1, wc = w & 1;
  const int lr = l & 15, kq = l >> 4;

  f32x4 acc[3][4];
#pragma unroll
  for (int mi = 0; mi < 3; ++mi)
#pragma unroll
    for (int ni = 0; ni < 4; ++ni) acc[mi][ni] = (f32x4){0.f, 0.f, 0.f, 0.f};

  const int srow = tid >> 2;
  const int q8 = (tid & 3) * 8;
  const bool secondA = tid < 128;
  const ushort* sA0 = A2 + (size_t)(m0 + srow) * K + q8;
  const ushort* sA1 = A2 + (size_t)(m0 + srow + 64) * K + q8;
  const ushort* sB0 = HT + (size_t)(n0 + srow) * K + q8;
  const ushort* sB1 = HT + (size_t)(n0 + srow + 64) * K + q8;
  const int wofs = w * 512;

#define STAGE2(k0v, buf)                                            \
  do {                                                              \
    gload_lds16(sA0 + (k0v), As + (buf)*3072 + wofs);               \
    if (secondA) gload_lds16(sA1 + (k0v), As + (buf)*3072 + 2048 + wofs); \
    gload_lds16(sB0 + (k0v), Bs + (buf)*4096 + wofs);               \
    gload_lds16(sB1 + (k0v), Bs + (buf)*4096 + 2048 + wofs);        \
  } while (0)

  STAGE2(0, 0);
  __syncthreads();

  int cur = 0;
  for (int k0 = 0; k0 < K; k0 += 32) {
    const int nxt = cur ^ 1;
    if (k0 + 32 < K) STAGE2(k0 + 32, nxt);
    const ushort* Ab = As + cur * 3072;
    const ushort* Bb = Bs + cur * 4096;
    s16x8 af[3], bfr[4];
#pragma unroll
    for (int mi = 0; mi < 3; ++mi)
      af[mi] = *(const s16x8*)(Ab + (wr * 48 + mi * 16 + lr) * 32 + kq * 8);
#pragma unroll
    for (int ni = 0; ni < 4; ++ni)
      bfr[ni] = *(const s16x8*)(Bb + (wc * 64 + ni * 16 + lr) * 32 + kq * 8);
#pragma unroll
    for (int mi = 0; mi < 3; ++mi)
#pragma unroll
      for (int ni = 0; ni < 4; ++ni)
        acc[mi][ni] = __builtin_amdgcn_mfma_f32_16x16x32_bf16(
            af[mi], bfr[ni], acc[mi][ni], 0, 0, 0);
    __syncthreads();
    cur = nxt;
  }
#undef STAGE2

#pragma unroll
  for (int mi = 0; mi < 3; ++mi) {
    const int rbase = m0 + wr * 48 + mi * 16 + kq * 4;
    float b4[4];
#pragma unroll
    for (int j = 0; j < 4; ++j) b4[j] = b2[rbase + j];
    if (rbase < 128) {
#pragma unroll
      for (int ni = 0; ni < 4; ++ni) {
        const int col = n0 + wc * 64 + ni * 16 + lr;
#pragma unroll
        for (int j = 0; j < 4; ++j)
          Fb[(size_t)(rbase + j) * BNT + col] =
              f32_to_bf16_rne(acc[mi][ni][j] + b4[j]);
      }
    } else {
#pragma unroll
      for (int ni = 0; ni < 4; ++ni) {
        const int col = n0 + wc * 64 + ni * 16 + lr;
        float* cr = C2 + (size_t)rbase * BNT + col;
#pragma unroll
        for (int j = 0; j < 4; ++j) cr[(size_t)j * BNT] = acc[mi][ni][j] + b4[j];
      }
    }
  }
}

// ---- fused post: Sinkhorn-linear -> P(LDS,bf16,swz) -> VLAD MFMA -> finalize
// LDS map (disjoint; FIXED r12's U/V overlap):
//   E   [0, 66560)        65x256 f32   (reused as VLs [0,32768) + scratch)
//   U   [66560, 66880)    65 f32 (padded)
//   V   [66880, 67904)    256 f32
//   Pl  [67904, 100672)   64x256 bf16, granule-XOR swizzled
__global__ __launch_bounds__(256) void post_kernel(
    const float* __restrict__ S, const float* __restrict__ dustp,
    const ushort* __restrict__ Fb, const float* __restrict__ TK,
    float* __restrict__ out) {
  __shared__ char smem[100672];
  float(*E)[256] = (float(*)[256])smem;
  float* U = (float*)(smem + 66560);
  float* V = (float*)(smem + 66880);
  ushort* Pl = (ushort*)(smem + 67904);
  float* VLs = (float*)smem;                   // [8192], reuses dead E
  float* sred = (float*)(smem + 32768);
  float* ssm = (float*)(smem + 32784);         // [4][64]
  float* invm_s = (float*)(smem + 33808);      // [64]
  float* totals = (float*)(smem + 34064);      // [1]

  const int b = blockIdx.x, tid = threadIdx.x;
  const int lane = tid & 63, wave = tid >> 6;

  // ---- stage 1: linear Sinkhorn (identical math to sinkhorn_lin) ----
  for (int idx = tid; idx < 16384; idx += 256) {
    const int m = idx >> 8, n = idx & 255;
    E[m][n] = expf(S[m * BNT + b * 256 + n]);
  }
  E[64][tid] = expf(dustp[0]);
  V[tid] = 1.f;
  const float Ai = 1.f / 320.f;
  const float Adust = 192.f / 320.f;
  const float Bn = 1.f / 320.f;
  __syncthreads();
  for (int it = 0; it < 3; ++it) {
    for (int i = wave; i < 65; i += 4) {
      float s = E[i][lane] * V[lane];
      s = fmaf(E[i][lane + 64], V[lane + 64], s);
      s = fmaf(E[i][lane + 128], V[lane + 128], s);
      s = fmaf(E[i][lane + 192], V[lane + 192], s);
#pragma unroll
      for (int off = 32; off; off >>= 1) s += __shfl_xor(s, off);
      if (lane == 0) U[i] = (i == 64 ? Adust : Ai) / s;
    }
    __syncthreads();
    {
      const int n = tid;
      float s = 0.f;
#pragma unroll 13
      for (int i = 0; i < 65; ++i) s = fmaf(E[i][n], U[i], s);
      V[n] = Bn / s;
    }
    __syncthreads();
  }
  // ---- stage 2: P -> LDS bf16, granule-XOR swizzle (16B granules) ----
  // P value uses EXACT sinkhorn_lin order: ((E*U)*V)*320.
#pragma unroll
  for (int j = 0; j < 8; ++j) {
    const int gg = tid + j * 256;       // 2048 granules
    const int row = gg >> 5, gr = gg & 31;
    const float um = U[row];
    const int n0g = gr * 8;
    float p[8];
#pragma unroll
    for (int e = 0; e < 8; ++e)
      p[e] = E[row][n0g + e] * um * V[n0g + e] * 320.f;
    uint4 o;
    o.x = pack_bf16x2(p[0], p[1]);
    o.y = pack_bf16x2(p[2], p[3]);
    o.z = pack_bf16x2(p[4], p[5]);
    o.w = pack_bf16x2(p[6], p[7]);
    *(uint4*)(Pl + row * 256 + ((gr ^ (row & 7)) << 3)) = o;
  }
  __syncthreads();
  // ---- stage 3: VLAD MFMA (F from global, P from LDS) ----
  const int l = lane, w = wave;
  const int lr = l & 15, ko = l >> 4;
  f32x4 acc[2][4];
#pragma unroll
  for (int li = 0; li < 2; ++li)
#pragma unroll
    for (int ni = 0; ni < 4; ++ni) acc[li][ni] = (f32x4){0.f, 0.f, 0.f, 0.f};
  const ushort* Fbase = Fb + b * 256;
#pragma unroll
  for (int ks = 0; ks < 8; ++ks) {
    s16x8 bfr[4];
#pragma unroll
    for (int ni = 0; ni < 4; ++ni) {
      const int row = ni * 16 + lr;
      const int gk = ks * 4 + ko;
      bfr[ni] = *(const s16x8*)(Pl + row * 256 + ((gk ^ (row & 7)) << 3));
    }
    const int k = ks * 32 + ko * 8;
#pragma unroll
    for (int li = 0; li < 2; ++li) {
      const s16x8 af =
          *(const s16x8*)(Fbase + (size_t)(w * 32 + li * 16 + lr) * BNT + k);
#pragma unroll
      for (int ni = 0; ni < 4; ++ni)
        acc[li][ni] = __builtin_amdgcn_mfma_f32_16x16x32_bf16(
            af, bfr[ni], acc[li][ni], 0, 0, 0);
    }
  }
#pragma unroll
  for (int li = 0; li < 2; ++li)
#pragma unroll
    for (int ni = 0; ni < 4; ++ni)
#pragma unroll
      for (int j = 0; j < 4; ++j) {
        const int ll = w * 32 + li * 16 + ko * 4 + j;
        const int m = ni * 16 + lr;
        VLs[ll * 64 + m] = acc[li][ni][j];
      }
  __syncthreads();
  // ---- stage 4: finalize (identical math) ----
  float accv = 0.f;
  for (int k = 0; k < 32; ++k) {
    const float xv = VLs[tid + 256 * k];
    accv = fmaf(xv, xv, accv);
  }
  ssm[wave * 64 + lane] = accv;
  const float tv = TK[b * 256 + tid];
  float ss = tv * tv;
#pragma unroll
  for (int off = 32; off; off >>= 1) ss += __shfl_down(ss, off);
  if (lane == 0) sred[wave] = ss;
  __syncthreads();
  const float sstok = sred[0] + sred[1] + sred[2] + sred[3];
  const float invtok = 1.f / fmaxf(sqrtf(sstok), 1e-12f);
  float tpart = 0.f;
  if (wave == 0) {
    const float s4 =
        ssm[tid] + ssm[64 + tid] + ssm[128 + tid] + ssm[192 + tid];
    const float inv = 1.f / fmaxf(sqrtf(s4), 1e-12f);
    invm_s[tid] = inv;
    tpart = s4 * inv * inv;
#pragma unroll
    for (int off = 32; off; off >>= 1) tpart += __shfl_down(tpart, off);
    if (lane == 0) totals[0] = tpart;
  }
  __syncthreads();
  const float total = totals[0] + sstok * invtok * invtok;
  const float invT = 1.f / fmaxf(sqrtf(total), 1e-12f);
  float* ob = &out[b * 8448];
  ob[tid] = tv * invtok * invT;
  for (int k = 0; k < 32; ++k) {
    const int idx = tid + 256 * k;
    ob[256 + idx] = VLs[idx] * invm_s[idx & 63] * invT;
  }
}

// ---------------- finalize (fallback path) -----------------------------------
__global__ __launch_bounds__(256) void finalize_kernel(
    const float* __restrict__ TK, const float* __restrict__ VL,
    float* __restrict__ out) {
  const int b = blockIdx.x, tid = threadIdx.x;
  const int lane = tid & 63, wave = tid >> 6;
  __shared__ float sred[4];
  __shared__ float ssm_part[4][64];
  __shared__ float invm_s[64];
  __shared__ float totals[1];
  const float* vl = &VL[b * 8192];
  float accv = 0.f;
  for (int k = 0; k < 32; ++k) {
    const float xv = vl[tid + 256 * k];
    accv = fmaf(xv, xv, accv);
  }
  ssm_part[wave][lane] = accv;
  const float tv = TK[b * 256 + tid];
  float ss = tv * tv;
#pragma unroll
  for (int off = 32; off; off >>= 1) ss += __shfl_down(ss, off);
  if (lane == 0) sred[wave] = ss;
  __syncthreads();
  const float sstok = sred[0] + sred[1] + sred[2] + sred[3];
  const float invtok = 1.f / fmaxf(sqrtf(sstok), 1e-12f);
  float tpart = 0.f;
  if (wave == 0) {
    const float s4 = ssm_part[0][tid] + ssm_part[1][tid] + ssm_part[2][tid] +
                     ssm_part[3][tid];
    const float inv = 1.f / fmaxf(sqrtf(s4), 1e-12f);
    invm_s[tid] = inv;
    tpart = s4 * inv * inv;
#pragma unroll
    for (int off = 32; off; off >>= 1) tpart += __shfl_down(tpart, off);
    if (lane == 0) totals[0] = tpart;
  }
  __syncthreads();
  const float total = totals[0] + sstok * invtok * invtok;
  const float invT = 1.f / fmaxf(sqrtf(total), 1e-12f);
  float* ob = &out[b * 8448];
  ob[tid] = tv * invtok * invT;
  for (int k = 0; k < 32; ++k) {
    const int idx = tid + 256 * k;
    ob[256 + idx] = vl[idx] * invm_s[idx & 63] * invT;
  }
}

// ================= fp32 fallback path kernels ===============================
template <bool RELU>
__global__ __launch_bounds__(256) void gemm_tt(
    const float* __restrict__ A, const float* __restrict__ Bw,
    const float* __restrict__ bias, float* __restrict__ C, int K, int Nn) {
  __shared__ float As[16][68];
  __shared__ float Bs[16][68];
  const int tid = threadIdx.x;
  const int tx = tid & 15, ty = tid >> 4;
  const int n0 = blockIdx.x * 64;
  const int lrow = tid >> 2, lkq = (tid & 3) << 2;
  float acc[4][4];
#pragma unroll
  for (int r = 0; r < 4; ++r)
#pragma unroll
    for (int c = 0; c < 4; ++c) acc[r][c] = 0.f;
  for (int k0 = 0; k0 < K; k0 += 16) {
    const float4 av = *(const float4*)&A[lrow * K + k0 + lkq];
    const float4 bv = *(const float4*)&Bw[(n0 + lrow) * K + k0 + lkq];
    As[lkq + 0][lrow] = av.x;
    As[lkq + 1][lrow] = av.y;
    As[lkq + 2][lrow] = av.z;
    As[lkq + 3][lrow] = av.w;
    Bs[lkq + 0][lrow] = bv.x;
    Bs[lkq + 1][lrow] = bv.y;
    Bs[lkq + 2][lrow] = bv.z;
    Bs[lkq + 3][lrow] = bv.w;
    __syncthreads();
#pragma unroll
    for (int kk = 0; kk < 16; ++kk) {
      const float4 a4 = *(const float4*)&As[kk][ty << 2];
      const float4 b4 = *(const float4*)&Bs[kk][tx << 2];
      acc[0][0] = fmaf(a4.x, b4.x, acc[0][0]);
      acc[0][1] = fmaf(a4.x, b4.y, acc[0][1]);
      acc[0][2] = fmaf(a4.x, b4.z, acc[0][2]);
      acc[0][3] = fmaf(a4.x, b4.w, acc[0][3]);
      acc[1][0] = fmaf(a4.y, b4.x, acc[1][0]);
      acc[1][1] = fmaf(a4.y, b4.y, acc[1][1]);
      acc[1][2] = fmaf(a4.y, b4.z, acc[1][2]);
      acc[1][3] = fmaf(a4.y, b4.w, acc[1][3]);
      acc[2][0] = fmaf(a4.z, b4.x, acc[2][0]);
      acc[2][1] = fmaf(a4.z, b4.y, acc[2][1]);
      acc[2][2] = fmaf(a4.z, b4.z, acc[2][2]);
      acc[2][3] = fmaf(a4.z, b4.w, acc[2][3]);
      acc[3][0] = fmaf(a4.w, b4.x, acc[3][0]);
      acc[3][1] = fmaf(a4.w, b4.y, acc[3][1]);
      acc[3][2] = fmaf(a4.w, b4.z, acc[3][2]);
      acc[3][3] = fmaf(a4.w, b4.w, acc[3][3]);
    }
    __syncthreads();
  }
#pragma unroll
  for (int r = 0; r < 4; ++r) {
    const int row = (ty << 2) + r;
    float4 o;
    o.x = acc[r][0] + bias[n0 + (tx << 2) + 0];
    o.y = acc[r][1] + bias[n0 + (tx << 2) + 1];
    o.z = acc[r][2] + bias[n0 + (tx << 2) + 2];
    o.w = acc[r][3] + bias[n0 + (tx << 2) + 3];
    if (RELU) {
      o.x = fmaxf(o.x, 0.f);
      o.y = fmaxf(o.y, 0.f);
      o.z = fmaxf(o.z, 0.f);
      o.w = fmaxf(o.w, 0.f);
    }
    *(float4*)&C[row * Nn + n0 + (tx << 2)] = o;
  }
}

template <bool XVIEW, bool RELU>
__global__ __launch_bounds__(256) void gemm_tile(
    const float* __restrict__ A, const float* __restrict__ Bsrc,
    const float* __restrict__ bias, float* __restrict__ Cout, int K) {
  __shared__ float As[16][68];
  __shared__ float Bsh[16][68];
  const int tid = threadIdx.x;
  const int tx = tid & 15, ty = tid >> 4;
  const int rowBase = blockIdx.y * 64;
  const int colBase = blockIdx.x * 64;
  const int bb = colBase >> 8, n0 = colBase & 255;
  const int boff = XVIEW ? (bb * 393216 + n0) : colBase;
  const int la_row = tid >> 2, la_kq = (tid & 3) << 2;
  const int lb_k = tid >> 4, lb_c = (tid & 15) << 2;
  float acc[4][4];
#pragma unroll
  for (int r = 0; r < 4; ++r)
#pragma unroll
    for (int c = 0; c < 4; ++c) acc[r][c] = 0.f;
  for (int k0 = 0; k0 < K; k0 += 16) {
    const float4 av = *(const float4*)&A[(rowBase + la_row) * K + k0 + la_kq];
    float4 bv;
    if (XVIEW)
      bv = *(const float4*)&Bsrc[boff + (k0 + lb_k) * 256 + lb_c];
    else
      bv = *(const float4*)&Bsrc[(k0 + lb_k) * BNT + boff + lb_c];
    As[la_kq + 0][la_row] = av.x;
    As[la_kq + 1][la_row] = av.y;
    As[la_kq + 2][la_row] = av.z;
    As[la_kq + 3][la_row] = av.w;
    *(float4*)&Bsh[lb_k][lb_c] = bv;
    __syncthreads();
#pragma unroll
    for (int kk = 0; kk < 16; ++kk) {
      const float4 a4 = *(const float4*)&As[kk][ty << 2];
      const float4 b4 = *(const float4*)&Bsh[kk][tx << 2];
      acc[0][0] = fmaf(a4.x, b4.x, acc[0][0]);
      acc[0][1] = fmaf(a4.x, b4.y, acc[0][1]);
      acc[0][2] = fmaf(a4.x, b4.z, acc[0][2]);
      acc[0][3] = fmaf(a4.x, b4.w, acc[0][3]);
      acc[1][0] = fmaf(a4.y, b4.x, acc[1][0]);
      acc[1][1] = fmaf(a4.y, b4.y, acc[1][1]);
      acc[1][2] = fmaf(a4.y, b4.z, acc[1][2]);
      acc[1][3] = fmaf(a4.y, b4.w, acc[1][3]);
      acc[2][0] = fmaf(a4.z, b4.x, acc[2][0]);
      acc[2][1] = fmaf(a4.z, b4.y, acc[2][1]);
      acc[2][2] = fmaf(a4.z, b4.z, acc[2][2]);
      acc[2][3] = fmaf(a4.z, b4.w, acc[2][3]);
      acc[3][0] = fmaf(a4.w, b4.x, acc[3][0]);
      acc[3][1] = fmaf(a4.w, b4.y, acc[3][1]);
      acc[3][2] = fmaf(a4.w, b4.z, acc[3][2]);
      acc[3][3] = fmaf(a4.w, b4.w, acc[3][3]);
    }
    __syncthreads();
  }
#pragma unroll
  for (int r = 0; r < 4; ++r) {
    const int row = rowBase + (ty << 2) + r;
    const float bsv = bias[row];
    float4 o;
    o.x = acc[r][0] + bsv;
    o.y = acc[r][1] + bsv;
    o.z = acc[r][2] + bsv;
    o.w = acc[r][3] + bsv;
    if (RELU) {
      o.x = fmaxf(o.x, 0.f);
      o.y = fmaxf(o.y, 0.f);
      o.z = fmaxf(o.z, 0.f);
      o.w = fmaxf(o.w, 0.f);
    }
    *(float4*)&Cout[row * BNT + colBase + (tx << 2)] = o;
  }
}

__global__ __launch_bounds__(256) void sinkhorn_kernel(
    const float* __restrict__ S, const float* __restrict__ dustp,
    float* __restrict__ P) {
  const int b = blockIdx.x, tid = threadIdx.x;
  const int lane = tid & 63, wave = tid >> 6;
  __shared__ float Ms[65][256];
  __shared__ float u[65];
  __shared__ float v[256];
  const float dust = dustp[0];
  for (int idx = tid; idx < 16384; idx += 256) {
    const int m = idx >> 8, n = idx & 255;
    Ms[m][n] = S[m * BNT + b * 256 + n];
  }
  Ms[64][tid] = dust;
  v[tid] = 0.f;
  if (tid < 65) u[tid] = 0.f;
  const float norm = -logf(320.f);
  const float la_dust = norm + logf(192.f);
  __syncthreads();
  for (int it = 0; it < 3; ++it) {
    for (int i = wave; i < 65; i += 4) {
      const float x0 = Ms[i][lane] + v[lane];
      const float x1 = Ms[i][lane + 64] + v[lane + 64];
      const float x2 = Ms[i][lane + 128] + v[lane + 128];
      const float x3 = Ms[i][lane + 192] + v[lane + 192];
      float mm = fmaxf(fmaxf(x0, x1), fmaxf(x2, x3));
#pragma unroll
      for (int off = 32; off; off >>= 1) mm = fmaxf(mm, __shfl_xor(mm, off));
      float s = expf(x0 - mm) + expf(x1 - mm) + expf(x2 - mm) + expf(x3 - mm);
#pragma unroll
      for (int off = 32; off; off >>= 1) s += __shfl_xor(s, off);
      if (lane == 0) u[i] = (i == 64 ? la_dust : norm) - (logf(s) + mm);
    }
    __syncthreads();
    {
      const int n = tid;
      float mm = -1e30f;
      for (int i = 0; i < 65; ++i) mm = fmaxf(mm, Ms[i][n] + u[i]);
      float s = 0.f;
      for (int i = 0; i < 65; ++i) s += expf(Ms[i][n] + u[i] - mm);
      v[n] = norm - (logf(s) + mm);
    }
    __syncthreads();
  }
  for (int idx = tid; idx < 16384; idx += 256) {
    const int m = idx >> 8, n = idx & 255;
    P[b * 16384 + idx] = expf(Ms[m][n] + u[m] + v[n] - norm);
  }
}

__device__ __forceinline__ int ps_idx(int m, int n) {
  return m * 256 + ((((n >> 2) ^ (m & 7)) << 2) | (n & 3));
}
__global__ __launch_bounds__(256) void vlad_kernel(const float* __restrict__ F,
                                                   const float* __restrict__ P,
                                                   float* __restrict__ VL) {
  const int b = blockIdx.x, half = blockIdx.y;
  const int tid = threadIdx.x;
  const int m = tid & 63, lg = tid >> 6;
  __shared__ float ps[64 * 256];
  for (int idx = tid; idx < 16384; idx += 256) {
    const int mm = idx >> 8, n = idx & 255;
    ps[ps_idx(mm, n)] = P[b * 16384 + idx];
  }
  __syncthreads();
  float acc[16];
#pragma unroll
  for (int i = 0; i < 16; ++i) acc[i] = 0.f;
  for (int i = 0; i < 16; ++i) {
    const int ll = half * 64 + lg + 4 * i;
    const float* frow = &F[(size_t)ll * BNT + b * 256];
    float a = 0.f;
#pragma unroll 8
    for (int nq = 0; nq < 64; ++nq) {
      const float4 f4 = *(const float4*)&frow[nq << 2];
      const float4 p4 = *(const float4*)&ps[m * 256 + ((nq ^ (m & 7)) << 2)];
      a = fmaf(f4.x, p4.x, a);
      a = fmaf(f4.y, p4.y, a);
      a = fmaf(f4.z, p4.z, a);
      a = fmaf(f4.w, p4.w, a);
    }
    acc[i] = a;
  }
#pragma unroll
  for (int i = 0; i < 16; ++i) {
    const int ll = half * 64 + lg + 4 * i;
    VL[b * 8192 + ll * 64 + m] = acc[i];
  }
}

extern "C" void kernel_launch(void* const* d_in, const int* in_sizes, int n_in,
                              void* d_out, int out_size, void* d_ws,
                              size_t ws_size, hipStream_t stream) {
  const float* x = (const float*)d_in[0];
  const float* t = (const float*)d_in[1];
  const float* Wt1 = (const float*)d_in[2];
  const float* bt1 = (const float*)d_in[3];
  const float* Wt2 = (const float*)d_in[4];
  const float* bt2 = (const float*)d_in[5];
  const float* Wc1 = (const float*)d_in[6];
  const float* bc1 = (const float*)d_in[7];
  const float* Wc2 = (const float*)d_in[8];
  const float* bc2 = (const float*)d_in[9];
  const float* Ws1 = (const float*)d_in[10];
  const float* bs1 = (const float*)d_in[11];
  const float* Ws2 = (const float*)d_in[12];
  const float* bs2 = (const float*)d_in[13];
  const float* dust = (const float*)d_in[14];
  float* out = (float*)d_out;

  if (ws_size >= 97714176ull) {
    char* base = (char*)d_ws;
    ushort* Tb = (ushort*)base;
    ushort* Wt1b = (ushort*)(base + 196608);
    ushort* Wt2b = (ushort*)(base + 1769472);
    float* Pt = (float*)(base + 2031616);
    ushort* Hb = (ushort*)(base + 2555904);
    ushort* XT = (ushort*)base;
    ushort* Fb = (ushort*)(base + 8388608);
    ushort* HT = (ushort*)(base + 50331648);
    float* C2 = (float*)(base + 83886080);
    ushort* A1 = (ushort*)(base + 83886080);
    ushort* Wc1b = A1;
    ushort* Ws1b = (ushort*)(base + 85458944);
    ushort* A2 = (ushort*)(base + 96468992);
    float* b2 = (float*)(base + 96993280);
    float* TK = (float*)(base + 96994304);
    float* b1 = (float*)(base + 97059840);
    float* Sb = C2 + (size_t)128 * BNT;

    prep_all<<<2788, 256, 0, stream>>>(t, Wt1, Wt2, Wc1, Ws1, bc1, bs1, Wc2,
                                       Ws2, bc2, bs2, Tb, Wt1b, Wt2b, Wc1b,
                                       Ws1b, b1, A2, b2);
    token1_mfma<<<dim3(8, 4), 256, 0, stream>>>(Tb, Wt1b, Pt);
    token1_reduce<<<64, 256, 0, stream>>>(Pt, bt1, Hb);
    token2_mfma<<<4, 256, 0, stream>>>(Hb, Wt2b, bt2, TK);
    transpose_x_bf16<<<dim3(24, 64), 256, 0, stream>>>(x, XT);
    gemm1_8ph<<<256, 512, 0, stream>>>(A1, XT, b1, HT);
    gemm2_mfma96<<<256, 256, 0, stream>>>(A2, HT, b2, C2, Fb);
    post_kernel<<<64, 256, 0, stream>>>(Sb, dust, Fb, TK, out);
  } else {
    float* ws = (float*)d_ws;
    float* H = ws;
    float* F = H + 512 * BNT;
    float* Sb = F + 128 * BNT;
    float* P = Sb + 64 * BNT;
    float* VL = P + 64 * BNT;
    float* TK = VL + 64 * 8192;
    float* Hh = P;

    gemm_tt<true><<<dim3(8, 1), 256, 0, stream>>>(t, Wt1, bt1, Hh, 1536, 512);
    gemm_tt<false><<<dim3(4, 1), 256, 0, stream>>>(Hh, Wt2, bt2, TK, 512, 256);
    gemm_tile<true, true><<<dim3(256, 8), 256, 0, stream>>>(Wc1, x, bc1, H, 1536);
    gemm_tile<false, false><<<dim3(256, 2), 256, 0, stream>>>(Wc2, H, bc2, F, 512);
    gemm_tile<true, true><<<dim3(256, 8), 256, 0, stream>>>(Ws1, x, bs1, H, 1536);
    gemm_tile<false, false><<<dim3(256, 1), 256, 0, stream>>>(Ws2, H, bs2, Sb, 512);
    sinkhorn_kernel<<<64, 256, 0, stream>>>(Sb, dust, P);
    vlad_kernel<<<dim3(64, 2), 256, 0, stream>>>(F, P, VL);
    finalize_kernel<<<64, 256, 0, stream>>>(TK, VL, out);
  }
}

// Round 14
// 151.958 us; speedup vs baseline: 1.5308x; 1.0476x over previous
//
#include <hip/hip_runtime.h>
#include <math.h>

// SALAD head. B=64, C=1536, N=256, HID=512, L=128, M=64, G=256. BNT = B*N.
#define BNT 16384

using f32x4 = __attribute__((ext_vector_type(4))) float;
using s16x8 = __attribute__((ext_vector_type(8))) short;

__device__ __forceinline__ unsigned short f32_to_bf16_rne(float f) {
  unsigned int u = __float_as_uint(f);
  u += 0x7FFFu + ((u >> 16) & 1u);
  return (unsigned short)(u >> 16);
}
__device__ __forceinline__ unsigned pack_bf16x2(float a, float b) {
  return (unsigned)f32_to_bf16_rne(a) | ((unsigned)f32_to_bf16_rne(b) << 16);
}

__device__ __forceinline__ void gload_lds16(const ushort* g, ushort* lds) {
  __builtin_amdgcn_global_load_lds(
      (const __attribute__((address_space(1))) unsigned int*)g,
      (__attribute__((address_space(3))) unsigned int*)lds, 16, 0, 0);
}

// ---- fused prep: bf16 converts + b1/A2 stacking + x-transpose --------------
// blocks [0,2788): prep paths; [2788,4324): transpose of x into XT.
__global__ __launch_bounds__(256) void prep_all2(
    const float* __restrict__ t, const float* __restrict__ Wt1,
    const float* __restrict__ Wt2, const float* __restrict__ Wc1,
    const float* __restrict__ Ws1, const float* __restrict__ bc1,
    const float* __restrict__ bs1, const float* __restrict__ Wc2,
    const float* __restrict__ Ws2, const float* __restrict__ bc2,
    const float* __restrict__ bs2, const float* __restrict__ x,
    ushort* __restrict__ Tb, ushort* __restrict__ Wt1b,
    ushort* __restrict__ Wt2b, ushort* __restrict__ Wc1b,
    ushort* __restrict__ Ws1b, float* __restrict__ b1,
    ushort* __restrict__ A2, float* __restrict__ b2,
    ushort* __restrict__ XT) {
  __shared__ ushort lds[16384];
  const int bid = blockIdx.x, tid = threadIdx.x;
  if (bid >= 2788) {
    // ---- transpose x [64][1536][256] f32 -> XT [16384][1536] bf16 ----
    const int tb = bid - 2788;
    const int b = tb / 24, cc = (tb % 24) * 64;
    const int tt = tid;
    const float* xb = x + b * 393216 + cc * 256;
#pragma unroll
    for (int i = 0; i < 16; ++i) {
      const int c0 = i * 4;
      const float v0 = xb[(c0 + 0) * 256 + tt];
      const float v1 = xb[(c0 + 1) * 256 + tt];
      const float v2 = xb[(c0 + 2) * 256 + tt];
      const float v3 = xb[(c0 + 3) * 256 + tt];
      uint2 o;
      o.x = pack_bf16x2(v0, v1);
      o.y = pack_bf16x2(v2, v3);
      const int g = c0 >> 3;
      const int waddr = tt * 128 + (((g ^ (tt & 7)) << 4) | ((c0 & 7) << 1));
      *(uint2*)((char*)lds + waddr) = o;
    }
    __syncthreads();
#pragma unroll
    for (int r = 0; r < 8; ++r) {
      const int j = r * 32 + (tt >> 3), q = tt & 7;
      const uint4 o =
          *(const uint4*)((const char*)lds + j * 128 + ((q ^ (j & 7)) << 4));
      *(uint4*)(XT + (size_t)(b * 256 + j) * 1536 + cc + q * 8) = o;
    }
    return;
  }
  const float* src = nullptr;
  ushort* dst = nullptr;
  int i = 0;
  if (bid < 96) {
    src = t; dst = Tb; i = bid * 256 + tid;
  } else if (bid < 864) {
    src = Wt1; dst = Wt1b; i = (bid - 96) * 256 + tid;
  } else if (bid < 992) {
    src = Wt2; dst = Wt2b; i = (bid - 864) * 256 + tid;
  } else if (bid < 1760) {
    src = Wc1; dst = Wc1b; i = (bid - 992) * 256 + tid;
  } else if (bid < 2528) {
    src = Ws1; dst = Ws1b; i = (bid - 1760) * 256 + tid;
  } else if (bid < 2532) {
    const int j = (bid - 2528) * 256 + tid;
    b1[j] = j < 512 ? bc1[j] : bs1[j - 512];
    return;
  } else {
    const int r = bid - 2532;
    const int c = tid * 4;
    float v[4] = {0.f, 0.f, 0.f, 0.f};
    if (r < 128) {
      if (c < 512) {
#pragma unroll
        for (int j = 0; j < 4; ++j) v[j] = Wc2[r * 512 + c + j];
      }
    } else if (r < 192) {
      if (c >= 512) {
#pragma unroll
        for (int j = 0; j < 4; ++j) v[j] = Ws2[(r - 128) * 512 + (c - 512) + j];
      }
    }
    uint2 o;
    o.x = pack_bf16x2(v[0], v[1]);
    o.y = pack_bf16x2(v[2], v[3]);
    *(uint2*)(A2 + r * 1024 + c) = o;
    if (tid == 0) b2[r] = r < 128 ? bc2[r] : (r < 192 ? bs2[r - 128] : 0.f);
    return;
  }
  const float4 v = ((const float4*)src)[i];
  uint2 o;
  o.x = pack_bf16x2(v.x, v.y);
  o.y = pack_bf16x2(v.z, v.w);
  ((uint2*)dst)[i] = o;
}

// ---- token layer 1 (MFMA, no LDS, split-K) ---------------------------------
__global__ __launch_bounds__(256) void token1_mfma(
    const ushort* __restrict__ Tb, const ushort* __restrict__ Wt1b,
    float* __restrict__ Pt) {
  const int ct = blockIdx.x, kc = blockIdx.y;
  const int tid = threadIdx.x, l = tid & 63, wv = tid >> 6;
  const int lr = l & 15, ko = l >> 4;
  const int col = ct * 64 + wv * 16 + lr;
  f32x4 acc[4];
#pragma unroll
  for (int r = 0; r < 4; ++r) acc[r] = (f32x4){0.f, 0.f, 0.f, 0.f};
  const int k0 = kc * 384;
#pragma unroll 4
  for (int ks = 0; ks < 12; ++ks) {
    const int k = k0 + ks * 32 + ko * 8;
    const s16x8 bf = *(const s16x8*)(Wt1b + (size_t)col * 1536 + k);
#pragma unroll
    for (int rf = 0; rf < 4; ++rf) {
      const s16x8 af = *(const s16x8*)(Tb + (size_t)(rf * 16 + lr) * 1536 + k);
      acc[rf] =
          __builtin_amdgcn_mfma_f32_16x16x32_bf16(af, bf, acc[rf], 0, 0, 0);
    }
  }
#pragma unroll
  for (int rf = 0; rf < 4; ++rf)
#pragma unroll
    for (int j = 0; j < 4; ++j) {
      const int row = rf * 16 + ko * 4 + j;
      Pt[((kc * 64 + row) << 9) + col] = acc[rf][j];
    }
}

// ---- token layer-1 reduce --------------------------------------------------
__global__ __launch_bounds__(256) void token1_reduce(
    const float* __restrict__ Pt, const float* __restrict__ bt1,
    ushort* __restrict__ Hb) {
  const int i = blockIdx.x * 256 + threadIdx.x;
  const int row = i >> 8, c2 = (i & 255) * 2;
  float v0 = bt1[c2], v1 = bt1[c2 + 1];
#pragma unroll
  for (int kc = 0; kc < 4; ++kc) {
    v0 += Pt[((kc * 64 + row) << 9) + c2];
    v1 += Pt[((kc * 64 + row) << 9) + c2 + 1];
  }
  v0 = fmaxf(v0, 0.f);
  v1 = fmaxf(v1, 0.f);
  ((unsigned*)Hb)[i] = pack_bf16x2(v0, v1);
}

// ---- token layer 2 (MFMA, no LDS) ------------------------------------------
__global__ __launch_bounds__(256) void token2_mfma(
    const ushort* __restrict__ Hb, const ushort* __restrict__ Wt2b,
    const float* __restrict__ bt2, float* __restrict__ TK) {
  const int ct = blockIdx.x;
  const int tid = threadIdx.x, l = tid & 63, wv = tid >> 6;
  const int lr = l & 15, ko = l >> 4;
  const int col = ct * 64 + wv * 16 + lr;
  f32x4 acc[4];
#pragma unroll
  for (int r = 0; r < 4; ++r) acc[r] = (f32x4){0.f, 0.f, 0.f, 0.f};
#pragma unroll 4
  for (int ks = 0; ks < 16; ++ks) {
    const int k = ks * 32 + ko * 8;
    const s16x8 bf = *(const s16x8*)(Wt2b + (size_t)col * 512 + k);
#pragma unroll
    for (int rf = 0; rf < 4; ++rf) {
      const s16x8 af = *(const s16x8*)(Hb + (size_t)(rf * 16 + lr) * 512 + k);
      acc[rf] =
          __builtin_amdgcn_mfma_f32_16x16x32_bf16(af, bf, acc[rf], 0, 0, 0);
    }
  }
  const float bb = bt2[col];
#pragma unroll
  for (int rf = 0; rf < 4; ++rf)
#pragma unroll
    for (int j = 0; j < 4; ++j)
      TK[(rf * 16 + ko * 4 + j) * 256 + col] = acc[rf][j] + bb;
}

// ---- layer-1 GEMM: 256x256, BK=64, 8-phase schedule (T2+T3+T4+T5) ----------
// (r10 verbatim — best measured variant: 805 TF, 0 bank conflicts)
__global__ __launch_bounds__(512) void gemm1_8ph(
    const ushort* __restrict__ A1, const ushort* __restrict__ Bt,
    const float* __restrict__ b1, ushort* __restrict__ HT) {
  __shared__ ushort lds[65536];  // A: [0,32768) 4 slots; B: [32768,65536)
  const int tid = threadIdx.x, l = tid & 63, w = tid >> 6;
  const int bid = blockIdx.x;
  const int newid = (bid & 7) * 32 + (bid >> 3);  // XCD-bijective (256%8==0)
  const int m0 = (newid & 3) * 256, n0 = (newid >> 2) * 256;
  const int wr = w >> 2, wc = w & 3;  // 2x4 wave grid
  const int lr = l & 15, kq = l >> 4;
  const int permK8 = (kq ^ ((lr >> 1) & 3)) * 8;  // ushort offset in row
  const int aRow = wr * 128 + lr;                 // + mi*16
  const int bRow = wc * 64 + lr;                  // + ni*16

  f32x4 acc[8][4];
#pragma unroll
  for (int mi = 0; mi < 8; ++mi)
#pragma unroll
    for (int ni = 0; ni < 4; ++ni) acc[mi][ni] = (f32x4){0.f, 0.f, 0.f, 0.f};

  const int srow = tid >> 2, ssp = tid & 3;
  const int skq = ssp ^ ((srow >> 1) & 3);
  const ushort* sA0 = A1 + (size_t)(m0 + srow) * 1536 + skq * 8;
  const ushort* sA1 = A1 + (size_t)(m0 + srow + 128) * 1536 + skq * 8;
  const ushort* sB0 = Bt + (size_t)(n0 + srow) * 1536 + skq * 8;
  const ushort* sB1 = Bt + (size_t)(n0 + srow + 128) * 1536 + skq * 8;
  const int wofs = w * 512;

#define STG_A(tau, kh)                                              \
  do {                                                              \
    ushort* d = &lds[((((tau)&1) * 2 + (kh)) * 8192) + wofs];       \
    gload_lds16(sA0 + (tau)*64 + (kh)*32, d);                       \
    gload_lds16(sA1 + (tau)*64 + (kh)*32, d + 4096);                \
  } while (0)
#define STG_B(tau, kh)                                              \
  do {                                                              \
    ushort* d = &lds[32768 + ((((tau)&1) * 2 + (kh)) * 8192) + wofs]; \
    gload_lds16(sB0 + (tau)*64 + (kh)*32, d);                       \
    gload_lds16(sB1 + (tau)*64 + (kh)*32, d + 4096);                \
  } while (0)

  STG_A(0, 0);
  STG_B(0, 0);
  STG_A(0, 1);
  STG_B(0, 1);
  asm volatile("s_waitcnt vmcnt(0)" ::: "memory");
  __builtin_amdgcn_s_barrier();

  for (int sg = 0; sg < 24; ++sg) {
    const int rho = sg & 1;
    const int As0 = (rho * 2 + 0) * 8192, As1 = (rho * 2 + 1) * 8192;
    const int Bs0 = 32768 + As0, Bs1 = 32768 + As1;
    const bool st = (sg + 1) < 24;
    s16x8 af[4], bfv[4];

    // ---- P1: kh0, mi 0-3
#pragma unroll
    for (int i = 0; i < 4; ++i)
      af[i] = *(const s16x8*)&lds[As0 + (aRow + i * 16) * 32 + permK8];
#pragma unroll
    for (int ni = 0; ni < 4; ++ni)
      bfv[ni] = *(const s16x8*)&lds[Bs0 + (bRow + ni * 16) * 32 + permK8];
    if (st) STG_A(sg + 1, 0);
    __builtin_amdgcn_s_barrier();
    __builtin_amdgcn_s_setprio(1);
#pragma unroll
    for (int i = 0; i < 4; ++i)
#pragma unroll
      for (int ni = 0; ni < 4; ++ni)
        acc[i][ni] = __builtin_amdgcn_mfma_f32_16x16x32_bf16(af[i], bfv[ni],
                                                             acc[i][ni], 0, 0, 0);
    __builtin_amdgcn_s_setprio(0);
    __builtin_amdgcn_s_barrier();

    // ---- P2: kh0, mi 4-7
#pragma unroll
    for (int i = 0; i < 4; ++i)
      af[i] = *(const s16x8*)&lds[As0 + (aRow + 64 + i * 16) * 32 + permK8];
    if (st) STG_B(sg + 1, 0);
    if (sg < 23)
      asm volatile("s_waitcnt vmcnt(4)" ::: "memory");
    else
      asm volatile("s_waitcnt vmcnt(0)" ::: "memory");
    __builtin_amdgcn_s_barrier();
    __builtin_amdgcn_s_setprio(1);
#pragma unroll
    for (int i = 0; i < 4; ++i)
#pragma unroll
      for (int ni = 0; ni < 4; ++ni)
        acc[4 + i][ni] = __builtin_amdgcn_mfma_f32_16x16x32_bf16(
            af[i], bfv[ni], acc[4 + i][ni], 0, 0, 0);
    __builtin_amdgcn_s_setprio(0);
    __builtin_amdgcn_s_barrier();

    // ---- P3: kh1, mi 0-3
#pragma unroll
    for (int i = 0; i < 4; ++i)
      af[i] = *(const s16x8*)&lds[As1 + (aRow + i * 16) * 32 + permK8];
#pragma unroll
    for (int ni = 0; ni < 4; ++ni)
      bfv[ni] = *(const s16x8*)&lds[Bs1 + (bRow + ni * 16) * 32 + permK8];
    if (st) STG_A(sg + 1, 1);
    __builtin_amdgcn_s_barrier();
    __builtin_amdgcn_s_setprio(1);
#pragma unroll
    for (int i = 0; i < 4; ++i)
#pragma unroll
      for (int ni = 0; ni < 4; ++ni)
        acc[i][ni] = __builtin_amdgcn_mfma_f32_16x16x32_bf16(af[i], bfv[ni],
                                                             acc[i][ni], 0, 0, 0);
    __builtin_amdgcn_s_setprio(0);
    __builtin_amdgcn_s_barrier();

    // ---- P4: kh1, mi 4-7
#pragma unroll
    for (int i = 0; i < 4; ++i)
      af[i] = *(const s16x8*)&lds[As1 + (aRow + 64 + i * 16) * 32 + permK8];
    if (st) STG_B(sg + 1, 1);
    asm volatile("s_waitcnt vmcnt(4)" ::: "memory");
    __builtin_amdgcn_s_barrier();
    __builtin_amdgcn_s_setprio(1);
#pragma unroll
    for (int i = 0; i < 4; ++i)
#pragma unroll
      for (int ni = 0; ni < 4; ++ni)
        acc[4 + i][ni] = __builtin_amdgcn_mfma_f32_16x16x32_bf16(
            af[i], bfv[ni], acc[4 + i][ni], 0, 0, 0);
    __builtin_amdgcn_s_setprio(0);
    __builtin_amdgcn_s_barrier();
  }
#undef STG_A
#undef STG_B

#pragma unroll
  for (int mi = 0; mi < 8; ++mi) {
    const int rbase = m0 + wr * 128 + mi * 16 + kq * 4;
    float b4[4];
#pragma unroll
    for (int j = 0; j < 4; ++j) b4[j] = b1[rbase + j];
#pragma unroll
    for (int ni = 0; ni < 4; ++ni) {
      const int col = n0 + wc * 64 + ni * 16 + lr;
      const float v0 = fmaxf(acc[mi][ni][0] + b4[0], 0.f);
      const float v1 = fmaxf(acc[mi][ni][1] + b4[1], 0.f);
      const float v2 = fmaxf(acc[mi][ni][2] + b4[2], 0.f);
      const float v3 = fmaxf(acc[mi][ni][3] + b4[3], 0.f);
      uint2 o;
      o.x = pack_bf16x2(v0, v1);
      o.y = pack_bf16x2(v2, v3);
      *(uint2*)(HT + (size_t)col * 1024 + rbase) = o;
    }
  }
}

// ---- layer-2 MFMA GEMM, 2-phase dbuf, BM=96, BK=64 (half the barriers) -----
// Same MFMA k-order as the BK=32 version (s=0 == old step k0, s=1 == k0+32)
// -> bit-identical accumulation. LDS 56 KB (grid-limited occupancy anyway).
__global__ __launch_bounds__(256) void gemm2_mfma64(
    const ushort* __restrict__ A2, const ushort* __restrict__ HT,
    const float* __restrict__ b2, float* __restrict__ C2,
    ushort* __restrict__ Fb) {
  constexpr int K = 1024;
  __shared__ ushort As[2 * 6144];  // [buf][sub(2)][96 rows][4 octs][8]
  __shared__ ushort Bs[2 * 8192];  // [buf][sub(2)][128 rows][4 octs][8]
  const int tid = threadIdx.x;
  const int l = tid & 63, w = tid >> 6;
  const int bid = blockIdx.x;
  const int newid = (bid & 7) * 32 + (bid >> 3);
  const int m0 = (newid & 1) * 96, n0 = (newid >> 1) * 128;
  const int wr = w >> 1, wc = w & 1;
  const int lr = l & 15, kq = l >> 4;

  f32x4 acc[3][4];
#pragma unroll
  for (int mi = 0; mi < 3; ++mi)
#pragma unroll
    for (int ni = 0; ni < 4; ++ni) acc[mi][ni] = (f32x4){0.f, 0.f, 0.f, 0.f};

  // staging granule maps (wave-linear dst; per-lane src):
  // A: g = tid + j*256 (j<3): q=g&3, r2=g>>2, sub=r2/96, r=r2-sub*96
  const ushort* srcA[3];
#pragma unroll
  for (int j = 0; j < 3; ++j) {
    const int g = tid + j * 256;
    const int q = g & 3, r2 = g >> 2;
    const int sub = r2 / 96, r = r2 - sub * 96;
    srcA[j] = A2 + (size_t)(m0 + r) * K + (sub * 4 + q) * 8;
  }
  // B: g = tid + j*256 (j<4): q=g&3, r2=g>>2, r=r2&127, sub=r2>>7
  const ushort* srcB[4];
#pragma unroll
  for (int j = 0; j < 4; ++j) {
    const int g = tid + j * 256;
    const int q = g & 3, r2 = g >> 2;
    const int r = r2 & 127, sub = r2 >> 7;
    srcB[j] = HT + (size_t)(n0 + r) * K + (sub * 4 + q) * 8;
  }
  const int wofs = w * 512;

#define STAGE2(k0v, buf)                                               \
  do {                                                                 \
    gload_lds16(srcA[0] + (k0v), As + (buf)*6144 + 0 * 2048 + wofs);   \
    gload_lds16(srcA[1] + (k0v), As + (buf)*6144 + 1 * 2048 + wofs);   \
    gload_lds16(srcA[2] + (k0v), As + (buf)*6144 + 2 * 2048 + wofs);   \
    gload_lds16(srcB[0] + (k0v), Bs + (buf)*8192 + 0 * 2048 + wofs);   \
    gload_lds16(srcB[1] + (k0v), Bs + (buf)*8192 + 1 * 2048 + wofs);   \
    gload_lds16(srcB[2] + (k0v), Bs + (buf)*8192 + 2 * 2048 + wofs);   \
    gload_lds16(srcB[3] + (k0v), Bs + (buf)*8192 + 3 * 2048 + wofs);   \
  } while (0)

  STAGE2(0, 0);
  __syncthreads();

  int cur = 0;
  for (int k0 = 0; k0 < K; k0 += 64) {
    const int nxt = cur ^ 1;
    if (k0 + 64 < K) STAGE2(k0 + 64, nxt);
    const ushort* Ab = As + cur * 6144;
    const ushort* Bb = Bs + cur * 8192;
#pragma unroll
    for (int s = 0; s < 2; ++s) {
      s16x8 af[3], bfr[4];
#pragma unroll
      for (int mi = 0; mi < 3; ++mi)
        af[mi] = *(const s16x8*)(Ab + (s * 96 + wr * 48 + mi * 16 + lr) * 32 +
                                 kq * 8);
#pragma unroll
      for (int ni = 0; ni < 4; ++ni)
        bfr[ni] = *(const s16x8*)(Bb + (s * 128 + wc * 64 + ni * 16 + lr) * 32 +
                                  kq * 8);
#pragma unroll
      for (int mi = 0; mi < 3; ++mi)
#pragma unroll
        for (int ni = 0; ni < 4; ++ni)
          acc[mi][ni] = __builtin_amdgcn_mfma_f32_16x16x32_bf16(
              af[mi], bfr[ni], acc[mi][ni], 0, 0, 0);
    }
    __syncthreads();
    cur = nxt;
  }
#undef STAGE2

#pragma unroll
  for (int mi = 0; mi < 3; ++mi) {
    const int rbase = m0 + wr * 48 + mi * 16 + kq * 4;
    float b4[4];
#pragma unroll
    for (int j = 0; j < 4; ++j) b4[j] = b2[rbase + j];
    if (rbase < 128) {
#pragma unroll
      for (int ni = 0; ni < 4; ++ni) {
        const int col = n0 + wc * 64 + ni * 16 + lr;
#pragma unroll
        for (int j = 0; j < 4; ++j)
          Fb[(size_t)(rbase + j) * BNT + col] =
              f32_to_bf16_rne(acc[mi][ni][j] + b4[j]);
      }
    } else {
#pragma unroll
      for (int ni = 0; ni < 4; ++ni) {
        const int col = n0 + wc * 64 + ni * 16 + lr;
        float* cr = C2 + (size_t)rbase * BNT + col;
#pragma unroll
        for (int j = 0; j < 4; ++j) cr[(size_t)j * BNT] = acc[mi][ni][j] + b4[j];
      }
    }
  }
}

// ---- fused post: Sinkhorn-linear -> P(LDS,bf16,swz) -> VLAD MFMA -> finalize
// LDS map (disjoint): E [0,66560) | U [66560,66880) | V [66880,67904) |
//   Pl [67904,100672). E reused as VLs + finalize scratch.
__global__ __launch_bounds__(256) void post_kernel(
    const float* __restrict__ S, const float* __restrict__ dustp,
    const ushort* __restrict__ Fb, const float* __restrict__ TK,
    float* __restrict__ out) {
  __shared__ char smem[100672];
  float(*E)[256] = (float(*)[256])smem;
  float* U = (float*)(smem + 66560);
  float* V = (float*)(smem + 66880);
  ushort* Pl = (ushort*)(smem + 67904);
  float* VLs = (float*)smem;
  float* sred = (float*)(smem + 32768);
  float* ssm = (float*)(smem + 32784);
  float* invm_s = (float*)(smem + 33808);
  float* totals = (float*)(smem + 34064);

  const int b = blockIdx.x, tid = threadIdx.x;
  const int lane = tid & 63, wave = tid >> 6;

  for (int idx = tid; idx < 16384; idx += 256) {
    const int m = idx >> 8, n = idx & 255;
    E[m][n] = expf(S[m * BNT + b * 256 + n]);
  }
  E[64][tid] = expf(dustp[0]);
  V[tid] = 1.f;
  const float Ai = 1.f / 320.f;
  const float Adust = 192.f / 320.f;
  const float Bn = 1.f / 320.f;
  __syncthreads();
  for (int it = 0; it < 3; ++it) {
    for (int i = wave; i < 65; i += 4) {
      float s = E[i][lane] * V[lane];
      s = fmaf(E[i][lane + 64], V[lane + 64], s);
      s = fmaf(E[i][lane + 128], V[lane + 128], s);
      s = fmaf(E[i][lane + 192], V[lane + 192], s);
#pragma unroll
      for (int off = 32; off; off >>= 1) s += __shfl_xor(s, off);
      if (lane == 0) U[i] = (i == 64 ? Adust : Ai) / s;
    }
    __syncthreads();
    {
      const int n = tid;
      float s = 0.f;
#pragma unroll 13
      for (int i = 0; i < 65; ++i) s = fmaf(E[i][n], U[i], s);
      V[n] = Bn / s;
    }
    __syncthreads();
  }
#pragma unroll
  for (int j = 0; j < 8; ++j) {
    const int gg = tid + j * 256;
    const int row = gg >> 5, gr = gg & 31;
    const float um = U[row];
    const int n0g = gr * 8;
    float p[8];
#pragma unroll
    for (int e = 0; e < 8; ++e)
      p[e] = E[row][n0g + e] * um * V[n0g + e] * 320.f;
    uint4 o;
    o.x = pack_bf16x2(p[0], p[1]);
    o.y = pack_bf16x2(p[2], p[3]);
    o.z = pack_bf16x2(p[4], p[5]);
    o.w = pack_bf16x2(p[6], p[7]);
    *(uint4*)(Pl + row * 256 + ((gr ^ (row & 7)) << 3)) = o;
  }
  __syncthreads();
  const int l = lane, w = wave;
  const int lr = l & 15, ko = l >> 4;
  f32x4 acc[2][4];
#pragma unroll
  for (int li = 0; li < 2; ++li)
#pragma unroll
    for (int ni = 0; ni < 4; ++ni) acc[li][ni] = (f32x4){0.f, 0.f, 0.f, 0.f};
  const ushort* Fbase = Fb + b * 256;
#pragma unroll
  for (int ks = 0; ks < 8; ++ks) {
    s16x8 bfr[4];
#pragma unroll
    for (int ni = 0; ni < 4; ++ni) {
      const int row = ni * 16 + lr;
      const int gk = ks * 4 + ko;
      bfr[ni] = *(const s16x8*)(Pl + row * 256 + ((gk ^ (row & 7)) << 3));
    }
    const int k = ks * 32 + ko * 8;
#pragma unroll
    for (int li = 0; li < 2; ++li) {
      const s16x8 af =
          *(const s16x8*)(Fbase + (size_t)(w * 32 + li * 16 + lr) * BNT + k);
#pragma unroll
      for (int ni = 0; ni < 4; ++ni)
        acc[li][ni] = __builtin_amdgcn_mfma_f32_16x16x32_bf16(
            af, bfr[ni], acc[li][ni], 0, 0, 0);
    }
  }
#pragma unroll
  for (int li = 0; li < 2; ++li)
#pragma unroll
    for (int ni = 0; ni < 4; ++ni)
#pragma unroll
      for (int j = 0; j < 4; ++j) {
        const int ll = w * 32 + li * 16 + ko * 4 + j;
        const int m = ni * 16 + lr;
        VLs[ll * 64 + m] = acc[li][ni][j];
      }
  __syncthreads();
  float accv = 0.f;
  for (int k = 0; k < 32; ++k) {
    const float xv = VLs[tid + 256 * k];
    accv = fmaf(xv, xv, accv);
  }
  ssm[wave * 64 + lane] = accv;
  const float tv = TK[b * 256 + tid];
  float ss = tv * tv;
#pragma unroll
  for (int off = 32; off; off >>= 1) ss += __shfl_down(ss, off);
  if (lane == 0) sred[wave] = ss;
  __syncthreads();
  const float sstok = sred[0] + sred[1] + sred[2] + sred[3];
  const float invtok = 1.f / fmaxf(sqrtf(sstok), 1e-12f);
  float tpart = 0.f;
  if (wave == 0) {
    const float s4 =
        ssm[tid] + ssm[64 + tid] + ssm[128 + tid] + ssm[192 + tid];
    const float inv = 1.f / fmaxf(sqrtf(s4), 1e-12f);
    invm_s[tid] = inv;
    tpart = s4 * inv * inv;
#pragma unroll
    for (int off = 32; off; off >>= 1) tpart += __shfl_down(tpart, off);
    if (lane == 0) totals[0] = tpart;
  }
  __syncthreads();
  const float total = totals[0] + sstok * invtok * invtok;
  const float invT = 1.f / fmaxf(sqrtf(total), 1e-12f);
  float* ob = &out[b * 8448];
  ob[tid] = tv * invtok * invT;
  for (int k = 0; k < 32; ++k) {
    const int idx = tid + 256 * k;
    ob[256 + idx] = VLs[idx] * invm_s[idx & 63] * invT;
  }
}

// ---------------- finalize (fallback path) -----------------------------------
__global__ __launch_bounds__(256) void finalize_kernel(
    const float* __restrict__ TK, const float* __restrict__ VL,
    float* __restrict__ out) {
  const int b = blockIdx.x, tid = threadIdx.x;
  const int lane = tid & 63, wave = tid >> 6;
  __shared__ float sred[4];
  __shared__ float ssm_part[4][64];
  __shared__ float invm_s[64];
  __shared__ float totals[1];
  const float* vl = &VL[b * 8192];
  float accv = 0.f;
  for (int k = 0; k < 32; ++k) {
    const float xv = vl[tid + 256 * k];
    accv = fmaf(xv, xv, accv);
  }
  ssm_part[wave][lane] = accv;
  const float tv = TK[b * 256 + tid];
  float ss = tv * tv;
#pragma unroll
  for (int off = 32; off; off >>= 1) ss += __shfl_down(ss, off);
  if (lane == 0) sred[wave] = ss;
  __syncthreads();
  const float sstok = sred[0] + sred[1] + sred[2] + sred[3];
  const float invtok = 1.f / fmaxf(sqrtf(sstok), 1e-12f);
  float tpart = 0.f;
  if (wave == 0) {
    const float s4 = ssm_part[0][tid] + ssm_part[1][tid] + ssm_part[2][tid] +
                     ssm_part[3][tid];
    const float inv = 1.f / fmaxf(sqrtf(s4), 1e-12f);
    invm_s[tid] = inv;
    tpart = s4 * inv * inv;
#pragma unroll
    for (int off = 32; off; off >>= 1) tpart += __shfl_down(tpart, off);
    if (lane == 0) totals[0] = tpart;
  }
  __syncthreads();
  const float total = totals[0] + sstok * invtok * invtok;
  const float invT = 1.f / fmaxf(sqrtf(total), 1e-12f);
  float* ob = &out[b * 8448];
  ob[tid] = tv * invtok * invT;
  for (int k = 0; k < 32; ++k) {
    const int idx = tid + 256 * k;
    ob[256 + idx] = vl[idx] * invm_s[idx & 63] * invT;
  }
}

// ================= fp32 fallback path kernels ===============================
template <bool RELU>
__global__ __launch_bounds__(256) void gemm_tt(
    const float* __restrict__ A, const float* __restrict__ Bw,
    const float* __restrict__ bias, float* __restrict__ C, int K, int Nn) {
  __shared__ float As[16][68];
  __shared__ float Bs[16][68];
  const int tid = threadIdx.x;
  const int tx = tid & 15, ty = tid >> 4;
  const int n0 = blockIdx.x * 64;
  const int lrow = tid >> 2, lkq = (tid & 3) << 2;
  float acc[4][4];
#pragma unroll
  for (int r = 0; r < 4; ++r)
#pragma unroll
    for (int c = 0; c < 4; ++c) acc[r][c] = 0.f;
  for (int k0 = 0; k0 < K; k0 += 16) {
    const float4 av = *(const float4*)&A[lrow * K + k0 + lkq];
    const float4 bv = *(const float4*)&Bw[(n0 + lrow) * K + k0 + lkq];
    As[lkq + 0][lrow] = av.x;
    As[lkq + 1][lrow] = av.y;
    As[lkq + 2][lrow] = av.z;
    As[lkq + 3][lrow] = av.w;
    Bs[lkq + 0][lrow] = bv.x;
    Bs[lkq + 1][lrow] = bv.y;
    Bs[lkq + 2][lrow] = bv.z;
    Bs[lkq + 3][lrow] = bv.w;
    __syncthreads();
#pragma unroll
    for (int kk = 0; kk < 16; ++kk) {
      const float4 a4 = *(const float4*)&As[kk][ty << 2];
      const float4 b4 = *(const float4*)&Bs[kk][tx << 2];
      acc[0][0] = fmaf(a4.x, b4.x, acc[0][0]);
      acc[0][1] = fmaf(a4.x, b4.y, acc[0][1]);
      acc[0][2] = fmaf(a4.x, b4.z, acc[0][2]);
      acc[0][3] = fmaf(a4.x, b4.w, acc[0][3]);
      acc[1][0] = fmaf(a4.y, b4.x, acc[1][0]);
      acc[1][1] = fmaf(a4.y, b4.y, acc[1][1]);
      acc[1][2] = fmaf(a4.y, b4.z, acc[1][2]);
      acc[1][3] = fmaf(a4.y, b4.w, acc[1][3]);
      acc[2][0] = fmaf(a4.z, b4.x, acc[2][0]);
      acc[2][1] = fmaf(a4.z, b4.y, acc[2][1]);
      acc[2][2] = fmaf(a4.z, b4.z, acc[2][2]);
      acc[2][3] = fmaf(a4.z, b4.w, acc[2][3]);
      acc[3][0] = fmaf(a4.w, b4.x, acc[3][0]);
      acc[3][1] = fmaf(a4.w, b4.y, acc[3][1]);
      acc[3][2] = fmaf(a4.w, b4.z, acc[3][2]);
      acc[3][3] = fmaf(a4.w, b4.w, acc[3][3]);
    }
    __syncthreads();
  }
#pragma unroll
  for (int r = 0; r < 4; ++r) {
    const int row = (ty << 2) + r;
    float4 o;
    o.x = acc[r][0] + bias[n0 + (tx << 2) + 0];
    o.y = acc[r][1] + bias[n0 + (tx << 2) + 1];
    o.z = acc[r][2] + bias[n0 + (tx << 2) + 2];
    o.w = acc[r][3] + bias[n0 + (tx << 2) + 3];
    if (RELU) {
      o.x = fmaxf(o.x, 0.f);
      o.y = fmaxf(o.y, 0.f);
      o.z = fmaxf(o.z, 0.f);
      o.w = fmaxf(o.w, 0.f);
    }
    *(float4*)&C[row * Nn + n0 + (tx << 2)] = o;
  }
}

template <bool XVIEW, bool RELU>
__global__ __launch_bounds__(256) void gemm_tile(
    const float* __restrict__ A, const float* __restrict__ Bsrc,
    const float* __restrict__ bias, float* __restrict__ Cout, int K) {
  __shared__ float As[16][68];
  __shared__ float Bsh[16][68];
  const int tid = threadIdx.x;
  const int tx = tid & 15, ty = tid >> 4;
  const int rowBase = blockIdx.y * 64;
  const int colBase = blockIdx.x * 64;
  const int bb = colBase >> 8, n0 = colBase & 255;
  const int boff = XVIEW ? (bb * 393216 + n0) : colBase;
  const int la_row = tid >> 2, la_kq = (tid & 3) << 2;
  const int lb_k = tid >> 4, lb_c = (tid & 15) << 2;
  float acc[4][4];
#pragma unroll
  for (int r = 0; r < 4; ++r)
#pragma unroll
    for (int c = 0; c < 4; ++c) acc[r][c] = 0.f;
  for (int k0 = 0; k0 < K; k0 += 16) {
    const float4 av = *(const float4*)&A[(rowBase + la_row) * K + k0 + la_kq];
    float4 bv;
    if (XVIEW)
      bv = *(const float4*)&Bsrc[boff + (k0 + lb_k) * 256 + lb_c];
    else
      bv = *(const float4*)&Bsrc[(k0 + lb_k) * BNT + boff + lb_c];
    As[la_kq + 0][la_row] = av.x;
    As[la_kq + 1][la_row] = av.y;
    As[la_kq + 2][la_row] = av.z;
    As[la_kq + 3][la_row] = av.w;
    *(float4*)&Bsh[lb_k][lb_c] = bv;
    __syncthreads();
#pragma unroll
    for (int kk = 0; kk < 16; ++kk) {
      const float4 a4 = *(const float4*)&As[kk][ty << 2];
      const float4 b4 = *(const float4*)&Bsh[kk][tx << 2];
      acc[0][0] = fmaf(a4.x, b4.x, acc[0][0]);
      acc[0][1] = fmaf(a4.x, b4.y, acc[0][1]);
      acc[0][2] = fmaf(a4.x, b4.z, acc[0][2]);
      acc[0][3] = fmaf(a4.x, b4.w, acc[0][3]);
      acc[1][0] = fmaf(a4.y, b4.x, acc[1][0]);
      acc[1][1] = fmaf(a4.y, b4.y, acc[1][1]);
      acc[1][2] = fmaf(a4.y, b4.z, acc[1][2]);
      acc[1][3] = fmaf(a4.y, b4.w, acc[1][3]);
      acc[2][0] = fmaf(a4.z, b4.x, acc[2][0]);
      acc[2][1] = fmaf(a4.z, b4.y, acc[2][1]);
      acc[2][2] = fmaf(a4.z, b4.z, acc[2][2]);
      acc[2][3] = fmaf(a4.z, b4.w, acc[2][3]);
      acc[3][0] = fmaf(a4.w, b4.x, acc[3][0]);
      acc[3][1] = fmaf(a4.w, b4.y, acc[3][1]);
      acc[3][2] = fmaf(a4.w, b4.z, acc[3][2]);
      acc[3][3] = fmaf(a4.w, b4.w, acc[3][3]);
    }
    __syncthreads();
  }
#pragma unroll
  for (int r = 0; r < 4; ++r) {
    const int row = rowBase + (ty << 2) + r;
    const float bsv = bias[row];
    float4 o;
    o.x = acc[r][0] + bsv;
    o.y = acc[r][1] + bsv;
    o.z = acc[r][2] + bsv;
    o.w = acc[r][3] + bsv;
    if (RELU) {
      o.x = fmaxf(o.x, 0.f);
      o.y = fmaxf(o.y, 0.f);
      o.z = fmaxf(o.z, 0.f);
      o.w = fmaxf(o.w, 0.f);
    }
    *(float4*)&Cout[row * BNT + colBase + (tx << 2)] = o;
  }
}

__global__ __launch_bounds__(256) void sinkhorn_kernel(
    const float* __restrict__ S, const float* __restrict__ dustp,
    float* __restrict__ P) {
  const int b = blockIdx.x, tid = threadIdx.x;
  const int lane = tid & 63, wave = tid >> 6;
  __shared__ float Ms[65][256];
  __shared__ float u[65];
  __shared__ float v[256];
  const float dust = dustp[0];
  for (int idx = tid; idx < 16384; idx += 256) {
    const int m = idx >> 8, n = idx & 255;
    Ms[m][n] = S[m * BNT + b * 256 + n];
  }
  Ms[64][tid] = dust;
  v[tid] = 0.f;
  if (tid < 65) u[tid] = 0.f;
  const float norm = -logf(320.f);
  const float la_dust = norm + logf(192.f);
  __syncthreads();
  for (int it = 0; it < 3; ++it) {
    for (int i = wave; i < 65; i += 4) {
      const float x0 = Ms[i][lane] + v[lane];
      const float x1 = Ms[i][lane + 64] + v[lane + 64];
      const float x2 = Ms[i][lane + 128] + v[lane + 128];
      const float x3 = Ms[i][lane + 192] + v[lane + 192];
      float mm = fmaxf(fmaxf(x0, x1), fmaxf(x2, x3));
#pragma unroll
      for (int off = 32; off; off >>= 1) mm = fmaxf(mm, __shfl_xor(mm, off));
      float s = expf(x0 - mm) + expf(x1 - mm) + expf(x2 - mm) + expf(x3 - mm);
#pragma unroll
      for (int off = 32; off; off >>= 1) s += __shfl_xor(s, off);
      if (lane == 0) u[i] = (i == 64 ? la_dust : norm) - (logf(s) + mm);
    }
    __syncthreads();
    {
      const int n = tid;
      float mm = -1e30f;
      for (int i = 0; i < 65; ++i) mm = fmaxf(mm, Ms[i][n] + u[i]);
      float s = 0.f;
      for (int i = 0; i < 65; ++i) s += expf(Ms[i][n] + u[i] - mm);
      v[n] = norm - (logf(s) + mm);
    }
    __syncthreads();
  }
  for (int idx = tid; idx < 16384; idx += 256) {
    const int m = idx >> 8, n = idx & 255;
    P[b * 16384 + idx] = expf(Ms[m][n] + u[m] + v[n] - norm);
  }
}

__device__ __forceinline__ int ps_idx(int m, int n) {
  return m * 256 + ((((n >> 2) ^ (m & 7)) << 2) | (n & 3));
}
__global__ __launch_bounds__(256) void vlad_kernel(const float* __restrict__ F,
                                                   const float* __restrict__ P,
                                                   float* __restrict__ VL) {
  const int b = blockIdx.x, half = blockIdx.y;
  const int tid = threadIdx.x;
  const int m = tid & 63, lg = tid >> 6;
  __shared__ float ps[64 * 256];
  for (int idx = tid; idx < 16384; idx += 256) {
    const int mm = idx >> 8, n = idx & 255;
    ps[ps_idx(mm, n)] = P[b * 16384 + idx];
  }
  __syncthreads();
  float acc[16];
#pragma unroll
  for (int i = 0; i < 16; ++i) acc[i] = 0.f;
  for (int i = 0; i < 16; ++i) {
    const int ll = half * 64 + lg + 4 * i;
    const float* frow = &F[(size_t)ll * BNT + b * 256];
    float a = 0.f;
#pragma unroll 8
    for (int nq = 0; nq < 64; ++nq) {
      const float4 f4 = *(const float4*)&frow[nq << 2];
      const float4 p4 = *(const float4*)&ps[m * 256 + ((nq ^ (m & 7)) << 2)];
      a = fmaf(f4.x, p4.x, a);
      a = fmaf(f4.y, p4.y, a);
      a = fmaf(f4.z, p4.z, a);
      a = fmaf(f4.w, p4.w, a);
    }
    acc[i] = a;
  }
#pragma unroll
  for (int i = 0; i < 16; ++i) {
    const int ll = half * 64 + lg + 4 * i;
    VL[b * 8192 + ll * 64 + m] = acc[i];
  }
}

extern "C" void kernel_launch(void* const* d_in, const int* in_sizes, int n_in,
                              void* d_out, int out_size, void* d_ws,
                              size_t ws_size, hipStream_t stream) {
  const float* x = (const float*)d_in[0];
  const float* t = (const float*)d_in[1];
  const float* Wt1 = (const float*)d_in[2];
  const float* bt1 = (const float*)d_in[3];
  const float* Wt2 = (const float*)d_in[4];
  const float* bt2 = (const float*)d_in[5];
  const float* Wc1 = (const float*)d_in[6];
  const float* bc1 = (const float*)d_in[7];
  const float* Wc2 = (const float*)d_in[8];
  const float* bc2 = (const float*)d_in[9];
  const float* Ws1 = (const float*)d_in[10];
  const float* bs1 = (const float*)d_in[11];
  const float* Ws2 = (const float*)d_in[12];
  const float* bs2 = (const float*)d_in[13];
  const float* dust = (const float*)d_in[14];
  float* out = (float*)d_out;

  if (ws_size >= 97714176ull) {
    // Layout: XT [0, 50331648) (written by prep_all2's transpose blocks).
    // Token scratch lives in the HT region (dead until gemm1, which runs
    // after token2): Tb@50331648, Wt1b@50528256, Wt2b@52101120,
    // Pt@52363264, Hb@52887552. HT (16384x1024 bf16) @50331648 is written
    // by gemm1 AFTER token path completes. C2/A1 overlay @83886080 as before.
    char* base = (char*)d_ws;
    ushort* XT = (ushort*)base;
    ushort* Tb = (ushort*)(base + 50331648);
    ushort* Wt1b = (ushort*)(base + 50528256);
    ushort* Wt2b = (ushort*)(base + 52101120);
    float* Pt = (float*)(base + 52363264);
    ushort* Hb = (ushort*)(base + 52887552);
    ushort* Fb = (ushort*)(base + 8388608);  // post-gemm1 overlay of XT region
    ushort* HT = (ushort*)(base + 50331648);
    float* C2 = (float*)(base + 83886080);
    ushort* A1 = (ushort*)(base + 83886080);
    ushort* Wc1b = A1;
    ushort* Ws1b = (ushort*)(base + 85458944);
    ushort* A2 = (ushort*)(base + 96468992);
    float* b2 = (float*)(base + 96993280);
    float* TK = (float*)(base + 96994304);
    float* b1 = (float*)(base + 97059840);
    float* Sb = C2 + (size_t)128 * BNT;

    prep_all2<<<4324, 256, 0, stream>>>(t, Wt1, Wt2, Wc1, Ws1, bc1, bs1, Wc2,
                                        Ws2, bc2, bs2, x, Tb, Wt1b, Wt2b, Wc1b,
                                        Ws1b, b1, A2, b2, XT);
    token1_mfma<<<dim3(8, 4), 256, 0, stream>>>(Tb, Wt1b, Pt);
    token1_reduce<<<64, 256, 0, stream>>>(Pt, bt1, Hb);
    token2_mfma<<<4, 256, 0, stream>>>(Hb, Wt2b, bt2, TK);
    gemm1_8ph<<<256, 512, 0, stream>>>(A1, XT, b1, HT);
    gemm2_mfma64<<<256, 256, 0, stream>>>(A2, HT, b2, C2, Fb);
    post_kernel<<<64, 256, 0, stream>>>(Sb, dust, Fb, TK, out);
  } else {
    float* ws = (float*)d_ws;
    float* H = ws;
    float* F = H + 512 * BNT;
    float* Sb = F + 128 * BNT;
    float* P = Sb + 64 * BNT;
    float* VL = P + 64 * BNT;
    float* TK = VL + 64 * 8192;
    float* Hh = P;

    gemm_tt<true><<<dim3(8, 1), 256, 0, stream>>>(t, Wt1, bt1, Hh, 1536, 512);
    gemm_tt<false><<<dim3(4, 1), 256, 0, stream>>>(Hh, Wt2, bt2, TK, 512, 256);
    gemm_tile<true, true><<<dim3(256, 8), 256, 0, stream>>>(Wc1, x, bc1, H, 1536);
    gemm_tile<false, false><<<dim3(256, 2), 256, 0, stream>>>(Wc2, H, bc2, F, 512);
    gemm_tile<true, true><<<dim3(256, 8), 256, 0, stream>>>(Ws1, x, bs1, H, 1536);
    gemm_tile<false, false><<<dim3(256, 1), 256, 0, stream>>>(Ws2, H, bs2, Sb, 512);
    sinkhorn_kernel<<<64, 256, 0, stream>>>(Sb, dust, P);
    vlad_kernel<<<dim3(64, 2), 256, 0, stream>>>(F, P, VL);
    finalize_kernel<<<64, 256, 0, stream>>>(TK, VL, out);
  }
}